// Round 1
// baseline (12084.810 us; speedup 1.0000x reference)
//
#include <hip/hip_runtime.h>
#include <math.h>

#define N_NODES 50000
#define N_EDGES 800000
#define NODE_IN 36
#define EDGE_IN 16
#define C_HID 128
#define C_OUT 64
#define BN_EPS 1e-5f

// ---- monotone float<->uint encoding for atomicMax on floats ----
__device__ __forceinline__ unsigned enc_f(float f) {
    unsigned u = __float_as_uint(f);
    return (u & 0x80000000u) ? ~u : (u | 0x80000000u);
}
__device__ __forceinline__ float dec_f(unsigned e) {
    return (e & 0x80000000u) ? __uint_as_float(e ^ 0x80000000u)
                             : __uint_as_float(~e);
}

// ---- build node features x = [node_emb[cat] | cont]  [N,36] ----
__global__ void k_node_feat(const int* __restrict__ xcat,
                            const float* __restrict__ xcont,
                            const float* __restrict__ node_emb,
                            float* __restrict__ x) {
    int idx = blockIdx.x * blockDim.x + threadIdx.x;
    if (idx >= N_NODES * NODE_IN) return;
    int i = idx / NODE_IN;
    int j = idx - i * NODE_IN;
    float v;
    if (j < 20) v = node_emb[xcat[i] * 20 + j];
    else        v = xcont[i * 16 + (j - 20)];
    x[idx] = v;
}

// ---- GINE layer 1, edge pass: agg1[dst] += relu(x[src] + ea@W + b) ----
__global__ void k_gine1_edge(const int* __restrict__ ei,
                             const int* __restrict__ ecat,
                             const float* __restrict__ econt,
                             const float* __restrict__ edge_emb,
                             const float* __restrict__ W,   // [16,36]
                             const float* __restrict__ b,   // [36]
                             const float* __restrict__ x,
                             float* __restrict__ agg) {
    __shared__ float sW[EDGE_IN * NODE_IN];
    __shared__ float sb[NODE_IN];
    __shared__ float semb[16];
    for (int t = threadIdx.x; t < EDGE_IN * NODE_IN; t += blockDim.x) sW[t] = W[t];
    if (threadIdx.x < NODE_IN) sb[threadIdx.x] = b[threadIdx.x];
    if (threadIdx.x < 16) semb[threadIdx.x] = edge_emb[threadIdx.x];
    __syncthreads();
    int e = blockIdx.x * blockDim.x + threadIdx.x;
    if (e >= N_EDGES) return;
    int s = ei[e], d = ei[N_EDGES + e];
    int c = ecat[e];
    float ea[16];
#pragma unroll
    for (int k = 0; k < 4; k++) ea[k] = semb[c * 4 + k];
#pragma unroll
    for (int k = 0; k < 12; k++) ea[4 + k] = econt[e * 12 + k];
    const float* xs = x + (size_t)s * NODE_IN;
    float* ad = agg + (size_t)d * NODE_IN;
#pragma unroll 4
    for (int j = 0; j < NODE_IN; j++) {
        float t = sb[j];
#pragma unroll
        for (int k = 0; k < 16; k++) t += ea[k] * sW[k * NODE_IN + j];
        float m = xs[j] + t;
        if (m > 0.f) atomicAdd(ad + j, m);   // relu: adding 0 is a no-op, skip
    }
}

// ---- GINE layer 1, node pass: h1 = bn(relu(((1+eps)x+agg)@W + b)) ----
__global__ void k_gine1_node(const float* __restrict__ x,
                             const float* __restrict__ agg,
                             const float* __restrict__ eps_p,
                             const float* __restrict__ W,   // [36,128]
                             const float* __restrict__ b,
                             const float* __restrict__ g,
                             const float* __restrict__ bb,
                             const float* __restrict__ m,
                             const float* __restrict__ v,
                             float* __restrict__ h) {
    __shared__ float z[2][NODE_IN];
    int node0 = blockIdx.x * 2;
    float eps = eps_p[0];
    int t = threadIdx.x;
    if (t < 2 * NODE_IN) {
        int n = t / NODE_IN, j = t - n * NODE_IN;
        int i = node0 + n;
        if (i < N_NODES)
            z[n][j] = (1.f + eps) * x[(size_t)i * NODE_IN + j] + agg[(size_t)i * NODE_IN + j];
    }
    __syncthreads();
    int n = t >> 7, c = t & 127;
    int i = node0 + n;
    if (i >= N_NODES) return;
    float acc = b[c];
#pragma unroll 4
    for (int j = 0; j < NODE_IN; j++) acc += z[n][j] * W[j * C_HID + c];
    acc = fmaxf(acc, 0.f);
    float sc = g[c] * rsqrtf(v[c] + BN_EPS);
    h[(size_t)i * C_HID + c] = (acc - m[c]) * sc + bb[c];
}

// ---- GINE layer 2, edge pass (F=128) ----
__global__ void k_gine2_edge(const int* __restrict__ ei,
                             const int* __restrict__ ecat,
                             const float* __restrict__ econt,
                             const float* __restrict__ edge_emb,
                             const float* __restrict__ W,   // [16,128]
                             const float* __restrict__ b,   // [128]
                             const float* __restrict__ h1,
                             float* __restrict__ agg) {
    __shared__ float sW[EDGE_IN * C_HID];
    __shared__ float sb[C_HID];
    __shared__ float semb[16];
    for (int t = threadIdx.x; t < EDGE_IN * C_HID; t += blockDim.x) sW[t] = W[t];
    if (threadIdx.x < C_HID) sb[threadIdx.x] = b[threadIdx.x];
    if (threadIdx.x < 16) semb[threadIdx.x] = edge_emb[threadIdx.x];
    __syncthreads();
    int e = blockIdx.x * blockDim.x + threadIdx.x;
    if (e >= N_EDGES) return;
    int s = ei[e], d = ei[N_EDGES + e];
    int c = ecat[e];
    float ea[16];
#pragma unroll
    for (int k = 0; k < 4; k++) ea[k] = semb[c * 4 + k];
#pragma unroll
    for (int k = 0; k < 12; k++) ea[4 + k] = econt[e * 12 + k];
    const float* hs = h1 + (size_t)s * C_HID;
    float* ad = agg + (size_t)d * C_HID;
#pragma unroll 2
    for (int j = 0; j < C_HID; j++) {
        float t = sb[j];
#pragma unroll
        for (int k = 0; k < 16; k++) t += ea[k] * sW[k * C_HID + j];
        float m = hs[j] + t;
        if (m > 0.f) atomicAdd(ad + j, m);
    }
}

// ---- GINE layer 2, node pass ----
__global__ void k_gine2_node(const float* __restrict__ h1,
                             const float* __restrict__ agg,
                             const float* __restrict__ eps_p,
                             const float* __restrict__ W,   // [128,128]
                             const float* __restrict__ b,
                             const float* __restrict__ g,
                             const float* __restrict__ bb,
                             const float* __restrict__ m,
                             const float* __restrict__ v,
                             float* __restrict__ h2) {
    __shared__ float z[2][C_HID];
    int node0 = blockIdx.x * 2;
    float eps = eps_p[0];
    int t = threadIdx.x;
    {
        int n = t >> 7, j = t & 127;
        int i = node0 + n;
        if (i < N_NODES)
            z[n][j] = (1.f + eps) * h1[(size_t)i * C_HID + j] + agg[(size_t)i * C_HID + j];
    }
    __syncthreads();
    int n = t >> 7, c = t & 127;
    int i = node0 + n;
    if (i >= N_NODES) return;
    float acc = b[c];
#pragma unroll 8
    for (int j = 0; j < C_HID; j++) acc += z[n][j] * W[j * C_HID + c];
    acc = fmaxf(acc, 0.f);
    float sc = g[c] * rsqrtf(v[c] + BN_EPS);
    h2[(size_t)i * C_HID + c] = (acc - m[c]) * sc + bb[c];
}

// ---- mean edge feature (sum; divide later) ----
__global__ void k_ea_sum(const int* __restrict__ ecat,
                         const float* __restrict__ econt,
                         const float* __restrict__ edge_emb,
                         float* __restrict__ ea_sum) {
    float p[16];
#pragma unroll
    for (int k = 0; k < 16; k++) p[k] = 0.f;
    for (int e = blockIdx.x * blockDim.x + threadIdx.x; e < N_EDGES;
         e += gridDim.x * blockDim.x) {
        int c = ecat[e];
#pragma unroll
        for (int k = 0; k < 4; k++) p[k] += edge_emb[c * 4 + k];
#pragma unroll
        for (int k = 0; k < 12; k++) p[4 + k] += econt[e * 12 + k];
    }
#pragma unroll
    for (int k = 0; k < 16; k++) {
        float v = p[k];
        for (int off = 32; off > 0; off >>= 1) v += __shfl_down(v, off);
        if ((threadIdx.x & 63) == 0) atomicAdd(ea_sum + k, v);
    }
}

// ---- self-loop edge transform: ee_loop = mean(ea) @ We  [128] ----
__global__ void k_loop_prep(const float* __restrict__ ea_sum,
                            const float* __restrict__ We,
                            float* __restrict__ ee_loop) {
    int c = threadIdx.x;
    float acc = 0.f;
#pragma unroll
    for (int k = 0; k < 16; k++)
        acc += (ea_sum[k] * (1.f / N_EDGES)) * We[k * C_HID + c];
    ee_loop[c] = acc;
}

// ---- GAT node pass: xl, xr, self-loop alpha, amax init ----
__global__ void k_gat0(const float* __restrict__ h2,
                       const float* __restrict__ Wl, const float* __restrict__ bl,
                       const float* __restrict__ Wr, const float* __restrict__ br,
                       const float* __restrict__ ee_loop,
                       const float* __restrict__ att,
                       float* __restrict__ xl, float* __restrict__ xr,
                       float* __restrict__ alpha_loop, unsigned* __restrict__ amax) {
    __shared__ float z[2][C_HID];
    int node0 = blockIdx.x * 2;
    int t = threadIdx.x;
    {
        int n = t >> 7, j = t & 127;
        int i = node0 + n;
        if (i < N_NODES) z[n][j] = h2[(size_t)i * C_HID + j];
    }
    __syncthreads();
    int n = t >> 7, c = t & 127;
    int i = node0 + n;
    if (i >= N_NODES) return;
    float al = bl[c], ar = br[c];
#pragma unroll 8
    for (int j = 0; j < C_HID; j++) {
        float zz = z[n][j];
        al += zz * Wl[j * C_HID + c];
        ar += zz * Wr[j * C_HID + c];
    }
    xl[(size_t)i * C_HID + c] = al;
    xr[(size_t)i * C_HID + c] = ar;
    float mm = al + ar + ee_loop[c];
    mm = (mm > 0.f) ? mm : 0.2f * mm;
    float v = mm * att[c];                       // att flat [2,64] == [128]
    for (int off = 32; off > 0; off >>= 1) v += __shfl_down(v, off);
    if ((t & 63) == 0) {                          // one head-group == one wave
        int h = (c >> 6);
        alpha_loop[i * 2 + h] = v;
        amax[i * 2 + h] = enc_f(v);
    }
}

// ---- GAT edge pass 1: alpha per edge + segment max ----
__global__ void k_gat1(const int* __restrict__ ei,
                       const int* __restrict__ ecat,
                       const float* __restrict__ econt,
                       const float* __restrict__ edge_emb,
                       const float* __restrict__ We,   // [16,128]
                       const float* __restrict__ att,
                       const float* __restrict__ xl, const float* __restrict__ xr,
                       float* __restrict__ alpha, unsigned* __restrict__ amax) {
    __shared__ float sW[EDGE_IN * C_HID];
    __shared__ float satt[C_HID];
    __shared__ float semb[16];
    for (int t = threadIdx.x; t < EDGE_IN * C_HID; t += blockDim.x) sW[t] = We[t];
    if (threadIdx.x < C_HID) satt[threadIdx.x] = att[threadIdx.x];
    if (threadIdx.x < 16) semb[threadIdx.x] = edge_emb[threadIdx.x];
    __syncthreads();
    int e = blockIdx.x * blockDim.x + threadIdx.x;
    if (e >= N_EDGES) return;
    int s = ei[e], d = ei[N_EDGES + e];
    int cc = ecat[e];
    float ea[16];
#pragma unroll
    for (int k = 0; k < 4; k++) ea[k] = semb[cc * 4 + k];
#pragma unroll
    for (int k = 0; k < 12; k++) ea[4 + k] = econt[e * 12 + k];
    const float* xls = xl + (size_t)s * C_HID;
    const float* xrd = xr + (size_t)d * C_HID;
    float a0 = 0.f, a1 = 0.f;
#pragma unroll 2
    for (int c = 0; c < C_HID; c++) {
        float ee = 0.f;
#pragma unroll
        for (int k = 0; k < 16; k++) ee += ea[k] * sW[k * C_HID + c];
        float m = xls[c] + xrd[c] + ee;
        m = (m > 0.f) ? m : 0.2f * m;
        float v = m * satt[c];
        if (c < 64) a0 += v; else a1 += v;
    }
    alpha[e * 2] = a0;
    alpha[e * 2 + 1] = a1;
    atomicMax(amax + d * 2, enc_f(a0));
    atomicMax(amax + d * 2 + 1, enc_f(a1));
}

// ---- GAT edge pass 2: exp + weighted aggregate ----
__global__ void k_gat2(const int* __restrict__ ei,
                       const float* __restrict__ alpha,
                       const unsigned* __restrict__ amax,
                       const float* __restrict__ xl,
                       float* __restrict__ den, float* __restrict__ num) {
    int e = blockIdx.x * blockDim.x + threadIdx.x;
    if (e >= N_EDGES) return;
    int s = ei[e], d = ei[N_EDGES + e];
    float e0 = __expf(alpha[e * 2]     - dec_f(amax[d * 2]));
    float e1 = __expf(alpha[e * 2 + 1] - dec_f(amax[d * 2 + 1]));
    atomicAdd(den + d * 2, e0);
    atomicAdd(den + d * 2 + 1, e1);
    const float* xls = xl + (size_t)s * C_HID;
    float* nd = num + (size_t)d * C_HID;
#pragma unroll 4
    for (int c = 0; c < 64; c++) atomicAdd(nd + c, e0 * xls[c]);
#pragma unroll 4
    for (int c = 64; c < C_HID; c++) atomicAdd(nd + c, e1 * xls[c]);
}

// ---- GAT finalize: add self-loop, divide, head-mean, bias ----
__global__ void k_gat3(const float* __restrict__ alpha_loop,
                       const unsigned* __restrict__ amax,
                       const float* __restrict__ den,
                       const float* __restrict__ num,
                       const float* __restrict__ xl,
                       const float* __restrict__ bias,
                       float* __restrict__ out) {
    int idx = blockIdx.x * blockDim.x + threadIdx.x;
    if (idx >= N_NODES * C_OUT) return;
    int i = idx >> 6, c = idx & 63;
    float e0 = __expf(alpha_loop[i * 2]     - dec_f(amax[i * 2]));
    float e1 = __expf(alpha_loop[i * 2 + 1] - dec_f(amax[i * 2 + 1]));
    float d0 = den[i * 2] + e0;
    float d1 = den[i * 2 + 1] + e1;
    float n0 = num[(size_t)i * C_HID + c]      + e0 * xl[(size_t)i * C_HID + c];
    float n1 = num[(size_t)i * C_HID + 64 + c] + e1 * xl[(size_t)i * C_HID + 64 + c];
    out[idx] = 0.5f * (n0 / d0 + n1 / d1) + bias[c];
}

extern "C" void kernel_launch(void* const* d_in, const int* in_sizes, int n_in,
                              void* d_out, int out_size, void* d_ws, size_t ws_size,
                              hipStream_t stream) {
    const int*   x_cat    = (const int*)d_in[0];
    const float* x_cont   = (const float*)d_in[1];
    const int*   e_cat    = (const int*)d_in[2];
    const float* e_cont   = (const float*)d_in[3];
    const int*   ei       = (const int*)d_in[4];
    const float* node_emb = (const float*)d_in[5];
    const float* edge_emb = (const float*)d_in[6];
    const float* eps1     = (const float*)d_in[7];
    const float* W1e      = (const float*)d_in[8];
    const float* b1e      = (const float*)d_in[9];
    const float* W1n      = (const float*)d_in[10];
    const float* b1n      = (const float*)d_in[11];
    const float* g1       = (const float*)d_in[12];
    const float* bb1      = (const float*)d_in[13];
    const float* m1       = (const float*)d_in[14];
    const float* v1       = (const float*)d_in[15];
    const float* eps2     = (const float*)d_in[16];
    const float* W2e      = (const float*)d_in[17];
    const float* b2e      = (const float*)d_in[18];
    const float* W2n      = (const float*)d_in[19];
    const float* b2n      = (const float*)d_in[20];
    const float* g2       = (const float*)d_in[21];
    const float* bb2      = (const float*)d_in[22];
    const float* m2       = (const float*)d_in[23];
    const float* v2       = (const float*)d_in[24];
    const float* Wl       = (const float*)d_in[25];
    const float* bl       = (const float*)d_in[26];
    const float* Wr       = (const float*)d_in[27];
    const float* br       = (const float*)d_in[28];
    const float* Weg      = (const float*)d_in[29];
    const float* att      = (const float*)d_in[30];
    const float* gbias    = (const float*)d_in[31];

    const size_t NF36 = (size_t)N_NODES * NODE_IN;   // 1.8M
    const size_t NF128 = (size_t)N_NODES * C_HID;    // 6.4M

    float* ws = (float*)d_ws;
    float* x          = ws;                         // N*36
    float* agg1       = x + NF36;                   // N*36 (reused as alpha: E*2 <= N*36)
    float* h1         = agg1 + NF36;                // N*128 (reused as xl)
    float* agg2       = h1 + NF128;                 // N*128 (reused as xr)
    float* h2         = agg2 + NF128;               // N*128 (reused as num)
    float* alpha_loop = h2 + NF128;                 // N*2
    unsigned* amax    = (unsigned*)(alpha_loop + 2 * N_NODES); // N*2
    float* den        = (float*)(amax + 2 * N_NODES);          // N*2
    float* ea_sum     = den + 2 * N_NODES;          // 16
    float* ee_loop    = ea_sum + 16;                // 128

    float* alpha = agg1;   // E*2 = 1.6M floats fits in N*36 = 1.8M
    float* xl    = h1;
    float* xr    = agg2;
    float* num   = h2;

    size_t need = (size_t)(ee_loop + C_HID - ws) * sizeof(float);
    if (ws_size < need) return;  // insufficient scratch; fail visibly

    // zero accumulators (ws is poisoned 0xAA before every launch)
    hipMemsetAsync(agg1, 0, NF36 * sizeof(float), stream);
    hipMemsetAsync(agg2, 0, NF128 * sizeof(float), stream);
    hipMemsetAsync(den, 0, 2 * N_NODES * sizeof(float), stream);
    hipMemsetAsync(ea_sum, 0, 16 * sizeof(float), stream);

    k_node_feat<<<(N_NODES * NODE_IN + 255) / 256, 256, 0, stream>>>(
        x_cat, x_cont, node_emb, x);
    k_gine1_edge<<<(N_EDGES + 255) / 256, 256, 0, stream>>>(
        ei, e_cat, e_cont, edge_emb, W1e, b1e, x, agg1);
    k_gine1_node<<<N_NODES / 2, 256, 0, stream>>>(
        x, agg1, eps1, W1n, b1n, g1, bb1, m1, v1, h1);
    k_gine2_edge<<<(N_EDGES + 255) / 256, 256, 0, stream>>>(
        ei, e_cat, e_cont, edge_emb, W2e, b2e, h1, agg2);
    k_gine2_node<<<N_NODES / 2, 256, 0, stream>>>(
        h1, agg2, eps2, W2n, b2n, g2, bb2, m2, v2, h2);
    k_ea_sum<<<256, 256, 0, stream>>>(e_cat, e_cont, edge_emb, ea_sum);
    k_loop_prep<<<1, C_HID, 0, stream>>>(ea_sum, Weg, ee_loop);
    k_gat0<<<N_NODES / 2, 256, 0, stream>>>(
        h2, Wl, bl, Wr, br, ee_loop, att, xl, xr, alpha_loop, amax);
    hipMemsetAsync(num, 0, NF128 * sizeof(float), stream);   // h2 dead now
    k_gat1<<<(N_EDGES + 255) / 256, 256, 0, stream>>>(
        ei, e_cat, e_cont, edge_emb, Weg, att, xl, xr, alpha, amax);
    k_gat2<<<(N_EDGES + 255) / 256, 256, 0, stream>>>(
        ei, alpha, amax, xl, den, num);
    k_gat3<<<(N_NODES * C_OUT + 255) / 256, 256, 0, stream>>>(
        alpha_loop, amax, den, num, xl, gbias, (float*)d_out);
}

// Round 2
// 1441.516 us; speedup vs baseline: 8.3834x; 8.3834x over previous
//
#include <hip/hip_runtime.h>
#include <math.h>

#define N_NODES 50000
#define N_EDGES 800000
#define NODE_IN 36
#define EDGE_IN 16
#define C_HID 128
#define C_OUT 64
#define BN_EPS 1e-5f
#define SCAN_T 1024
#define CHUNK ((N_NODES + SCAN_T - 1) / SCAN_T)   // 49

// ================= node features =================
__global__ void k_node_feat(const int* __restrict__ xcat,
                            const float* __restrict__ xcont,
                            const float* __restrict__ node_emb,
                            float* __restrict__ x) {
    int idx = blockIdx.x * blockDim.x + threadIdx.x;
    if (idx >= N_NODES * NODE_IN) return;
    int i = idx / NODE_IN;
    int j = idx - i * NODE_IN;
    float v;
    if (j < 20) v = node_emb[xcat[i] * 20 + j];
    else        v = xcont[i * 16 + (j - 20)];
    x[idx] = v;
}

// ================= CSR build =================
__global__ void k_deg(const int* __restrict__ ei, int* __restrict__ deg) {
    int e = blockIdx.x * blockDim.x + threadIdx.x;
    if (e >= N_EDGES) return;
    atomicAdd(deg + ei[N_EDGES + e], 1);
}

__global__ void k_scan(const int* __restrict__ deg, int* __restrict__ rowp,
                       int* __restrict__ cursor) {
    __shared__ int sums[SCAN_T];
    int t = threadIdx.x;
    int lo = t * CHUNK, hi = min(lo + CHUNK, N_NODES);
    int s = 0;
    for (int i = lo; i < hi; i++) s += deg[i];
    sums[t] = s;
    __syncthreads();
    for (int off = 1; off < SCAN_T; off <<= 1) {
        int v = 0;
        if (t >= off) v = sums[t - off];
        __syncthreads();
        if (t >= off) sums[t] += v;
        __syncthreads();
    }
    int run = sums[t] - s;      // exclusive prefix
    for (int i = lo; i < hi; i++) {
        rowp[i] = run;
        cursor[i] = run;
        run += deg[i];
    }
    if (t == SCAN_T - 1) rowp[N_NODES] = sums[SCAN_T - 1];
}

__global__ void k_fill(const int* __restrict__ ei, int* __restrict__ cursor,
                       int* __restrict__ csr_eid, int* __restrict__ csr_src) {
    int e = blockIdx.x * blockDim.x + threadIdx.x;
    if (e >= N_EDGES) return;
    int d = ei[N_EDGES + e];
    int pos = atomicAdd(cursor + d, 1);
    csr_eid[pos] = e;
    csr_src[pos] = ei[e];
}

// ================= GINE1 gather (F=36): agg[i] = sum relu(x[src]+lin_e(ea)) ===
__global__ void k_gine1_gather(const int* __restrict__ rowp,
                               const int* __restrict__ csr_eid,
                               const int* __restrict__ csr_src,
                               const int* __restrict__ ecat,
                               const float* __restrict__ econt,
                               const float* __restrict__ edge_emb,
                               const float* __restrict__ W,   // [16,36]
                               const float* __restrict__ b,   // [36]
                               const float* __restrict__ x,
                               float* __restrict__ agg) {
    __shared__ float sT[4 * NODE_IN];      // bias + cat part
    __shared__ float sW12[12 * NODE_IN];
    for (int t = threadIdx.x; t < 4 * NODE_IN; t += blockDim.x) {
        int q = t / NODE_IN, c = t - q * NODE_IN;
        float v = b[c];
#pragma unroll
        for (int k = 0; k < 4; k++) v += edge_emb[q * 4 + k] * W[k * NODE_IN + c];
        sT[t] = v;
    }
    for (int t = threadIdx.x; t < 12 * NODE_IN; t += blockDim.x)
        sW12[t] = W[4 * NODE_IN + t];
    __syncthreads();
    int i = blockIdx.x * 4 + (threadIdx.x >> 6);
    int lane = threadIdx.x & 63;
    if (i >= N_NODES) return;
    int beg = rowp[i], end = rowp[i + 1];
    float acc = 0.f;
    for (int p = beg; p < end; ++p) {
        int eid = csr_eid[p];
        int src = csr_src[p];
        int cat = ecat[eid];
        const float* ec = econt + (size_t)eid * 12;
        if (lane < NODE_IN) {
            float t = sT[cat * NODE_IN + lane];
#pragma unroll
            for (int k = 0; k < 12; k++) t += ec[k] * sW12[k * NODE_IN + lane];
            float m = x[(size_t)src * NODE_IN + lane] + t;
            acc += fmaxf(m, 0.f);
        }
    }
    if (lane < NODE_IN) agg[(size_t)i * NODE_IN + lane] = acc;
}

// ================= GINE1 node MLP + BN =================
__global__ void k_gine1_node(const float* __restrict__ x,
                             const float* __restrict__ agg,
                             const float* __restrict__ eps_p,
                             const float* __restrict__ W,   // [36,128]
                             const float* __restrict__ b,
                             const float* __restrict__ g,
                             const float* __restrict__ bb,
                             const float* __restrict__ m,
                             const float* __restrict__ v,
                             float* __restrict__ h) {
    __shared__ float z[2][NODE_IN];
    int node0 = blockIdx.x * 2;
    float eps = eps_p[0];
    int t = threadIdx.x;
    if (t < 2 * NODE_IN) {
        int n = t / NODE_IN, j = t - n * NODE_IN;
        int i = node0 + n;
        if (i < N_NODES)
            z[n][j] = (1.f + eps) * x[(size_t)i * NODE_IN + j] + agg[(size_t)i * NODE_IN + j];
    }
    __syncthreads();
    int n = t >> 7, c = t & 127;
    int i = node0 + n;
    if (i >= N_NODES) return;
    float acc = b[c];
#pragma unroll 4
    for (int j = 0; j < NODE_IN; j++) acc += z[n][j] * W[j * C_HID + c];
    acc = fmaxf(acc, 0.f);
    float sc = g[c] * rsqrtf(v[c] + BN_EPS);
    h[(size_t)i * C_HID + c] = (acc - m[c]) * sc + bb[c];
}

// ================= GINE2 gather (F=128) =================
__global__ void k_gine2_gather(const int* __restrict__ rowp,
                               const int* __restrict__ csr_eid,
                               const int* __restrict__ csr_src,
                               const int* __restrict__ ecat,
                               const float* __restrict__ econt,
                               const float* __restrict__ edge_emb,
                               const float* __restrict__ W,   // [16,128]
                               const float* __restrict__ b,   // [128]
                               const float* __restrict__ h1,
                               float* __restrict__ agg) {
    __shared__ float sT[4 * C_HID];
    __shared__ float sW12[12 * C_HID];
    for (int t = threadIdx.x; t < 4 * C_HID; t += blockDim.x) {
        int q = t >> 7, c = t & 127;
        float v = b[c];
#pragma unroll
        for (int k = 0; k < 4; k++) v += edge_emb[q * 4 + k] * W[k * C_HID + c];
        sT[t] = v;
    }
    for (int t = threadIdx.x; t < 12 * C_HID; t += blockDim.x)
        sW12[t] = W[4 * C_HID + t];
    __syncthreads();
    int i = blockIdx.x * 4 + (threadIdx.x >> 6);
    int lane = threadIdx.x & 63;
    if (i >= N_NODES) return;
    int c0 = lane, c1 = lane + 64;
    int beg = rowp[i], end = rowp[i + 1];
    float acc0 = 0.f, acc1 = 0.f;
    for (int p = beg; p < end; ++p) {
        int eid = csr_eid[p];
        int src = csr_src[p];
        int cat = ecat[eid];
        const float* ec = econt + (size_t)eid * 12;
        float t0 = sT[cat * C_HID + c0];
        float t1 = sT[cat * C_HID + c1];
#pragma unroll
        for (int k = 0; k < 12; k++) {
            float ev = ec[k];
            t0 += ev * sW12[k * C_HID + c0];
            t1 += ev * sW12[k * C_HID + c1];
        }
        const float* hs = h1 + (size_t)src * C_HID;
        acc0 += fmaxf(hs[c0] + t0, 0.f);
        acc1 += fmaxf(hs[c1] + t1, 0.f);
    }
    agg[(size_t)i * C_HID + c0] = acc0;
    agg[(size_t)i * C_HID + c1] = acc1;
}

// ================= GINE2 node MLP + BN =================
__global__ void k_gine2_node(const float* __restrict__ h1,
                             const float* __restrict__ agg,
                             const float* __restrict__ eps_p,
                             const float* __restrict__ W,   // [128,128]
                             const float* __restrict__ b,
                             const float* __restrict__ g,
                             const float* __restrict__ bb,
                             const float* __restrict__ m,
                             const float* __restrict__ v,
                             float* __restrict__ h2) {
    __shared__ float z[2][C_HID];
    int node0 = blockIdx.x * 2;
    float eps = eps_p[0];
    int t = threadIdx.x;
    {
        int n = t >> 7, j = t & 127;
        int i = node0 + n;
        if (i < N_NODES)
            z[n][j] = (1.f + eps) * h1[(size_t)i * C_HID + j] + agg[(size_t)i * C_HID + j];
    }
    __syncthreads();
    int n = t >> 7, c = t & 127;
    int i = node0 + n;
    if (i >= N_NODES) return;
    float acc = b[c];
#pragma unroll 8
    for (int j = 0; j < C_HID; j++) acc += z[n][j] * W[j * C_HID + c];
    acc = fmaxf(acc, 0.f);
    float sc = g[c] * rsqrtf(v[c] + BN_EPS);
    h2[(size_t)i * C_HID + c] = (acc - m[c]) * sc + bb[c];
}

// ================= mean edge feature =================
__global__ void k_ea_sum(const int* __restrict__ ecat,
                         const float* __restrict__ econt,
                         const float* __restrict__ edge_emb,
                         float* __restrict__ ea_sum) {
    float p[16];
#pragma unroll
    for (int k = 0; k < 16; k++) p[k] = 0.f;
    for (int e = blockIdx.x * blockDim.x + threadIdx.x; e < N_EDGES;
         e += gridDim.x * blockDim.x) {
        int c = ecat[e];
#pragma unroll
        for (int k = 0; k < 4; k++) p[k] += edge_emb[c * 4 + k];
#pragma unroll
        for (int k = 0; k < 12; k++) p[4 + k] += econt[e * 12 + k];
    }
#pragma unroll
    for (int k = 0; k < 16; k++) {
        float v = p[k];
        for (int off = 32; off > 0; off >>= 1) v += __shfl_down(v, off);
        if ((threadIdx.x & 63) == 0) atomicAdd(ea_sum + k, v);
    }
}

__global__ void k_loop_prep(const float* __restrict__ ea_sum,
                            const float* __restrict__ We,
                            float* __restrict__ ee_loop) {
    int c = threadIdx.x;
    float acc = 0.f;
#pragma unroll
    for (int k = 0; k < 16; k++)
        acc += (ea_sum[k] * (1.f / N_EDGES)) * We[k * C_HID + c];
    ee_loop[c] = acc;
}

// ================= GAT node transforms: xl, xr =================
__global__ void k_gat0(const float* __restrict__ h2,
                       const float* __restrict__ Wl, const float* __restrict__ bl,
                       const float* __restrict__ Wr, const float* __restrict__ br,
                       float* __restrict__ xl, float* __restrict__ xr) {
    __shared__ float z[2][C_HID];
    int node0 = blockIdx.x * 2;
    int t = threadIdx.x;
    {
        int n = t >> 7, j = t & 127;
        int i = node0 + n;
        if (i < N_NODES) z[n][j] = h2[(size_t)i * C_HID + j];
    }
    __syncthreads();
    int n = t >> 7, c = t & 127;
    int i = node0 + n;
    if (i >= N_NODES) return;
    float al = bl[c], ar = br[c];
#pragma unroll 8
    for (int j = 0; j < C_HID; j++) {
        float zz = z[n][j];
        al += zz * Wl[j * C_HID + c];
        ar += zz * Wr[j * C_HID + c];
    }
    xl[(size_t)i * C_HID + c] = al;
    xr[(size_t)i * C_HID + c] = ar;
}

// ========== GAT fused: online softmax + aggregate, one wave per node ==========
__global__ void k_gat_fused(const int* __restrict__ rowp,
                            const int* __restrict__ csr_eid,
                            const int* __restrict__ csr_src,
                            const int* __restrict__ ecat,
                            const float* __restrict__ econt,
                            const float* __restrict__ edge_emb,
                            const float* __restrict__ We,    // [16,128]
                            const float* __restrict__ att,   // [128]
                            const float* __restrict__ ee_loop,
                            const float* __restrict__ xl,
                            const float* __restrict__ xr,
                            const float* __restrict__ bias,  // [64]
                            float* __restrict__ out) {
    __shared__ float sT[4 * C_HID];     // cat part of ea@We (no bias)
    __shared__ float sW12[12 * C_HID];
    __shared__ float satt[C_HID];
    __shared__ float sloop[C_HID];
    for (int t = threadIdx.x; t < 4 * C_HID; t += blockDim.x) {
        int q = t >> 7, c = t & 127;
        float v = 0.f;
#pragma unroll
        for (int k = 0; k < 4; k++) v += edge_emb[q * 4 + k] * We[k * C_HID + c];
        sT[t] = v;
    }
    for (int t = threadIdx.x; t < 12 * C_HID; t += blockDim.x)
        sW12[t] = We[4 * C_HID + t];
    if (threadIdx.x < C_HID) {
        satt[threadIdx.x] = att[threadIdx.x];
        sloop[threadIdx.x] = ee_loop[threadIdx.x];
    }
    __syncthreads();
    int i = blockIdx.x * 4 + (threadIdx.x >> 6);
    int lane = threadIdx.x & 63;
    if (i >= N_NODES) return;
    int c0 = lane, c1 = lane + 64;

    float xr0 = xr[(size_t)i * C_HID + c0];
    float xr1 = xr[(size_t)i * C_HID + c1];
    float xld0 = xl[(size_t)i * C_HID + c0];
    float xld1 = xl[(size_t)i * C_HID + c1];

    // self-loop alpha
    float m0 = xld0 + xr0 + sloop[c0]; m0 = (m0 > 0.f) ? m0 : 0.2f * m0;
    float m1 = xld1 + xr1 + sloop[c1]; m1 = (m1 > 0.f) ? m1 : 0.2f * m1;
    float v0 = m0 * satt[c0];
    float v1 = m1 * satt[c1];
#pragma unroll
    for (int off = 32; off > 0; off >>= 1) {
        v0 += __shfl_xor(v0, off);
        v1 += __shfl_xor(v1, off);
    }
    float rm0 = v0, rm1 = v1;           // running max (init = self-loop alpha)
    float den0 = 1.f, den1 = 1.f;       // exp(self - self) = 1
    float acc0 = xld0, acc1 = xld1;     // 1 * xl[self]

    int beg = rowp[i], end = rowp[i + 1];
    for (int p = beg; p < end; ++p) {
        int eid = csr_eid[p];
        int src = csr_src[p];
        int cat = ecat[eid];
        const float* ec = econt + (size_t)eid * 12;
        float e0 = sT[cat * C_HID + c0];
        float e1 = sT[cat * C_HID + c1];
#pragma unroll
        for (int k = 0; k < 12; k++) {
            float ev = ec[k];
            e0 += ev * sW12[k * C_HID + c0];
            e1 += ev * sW12[k * C_HID + c1];
        }
        const float* xls = xl + (size_t)src * C_HID;
        float xs0 = xls[c0], xs1 = xls[c1];
        float mm0 = xs0 + xr0 + e0; mm0 = (mm0 > 0.f) ? mm0 : 0.2f * mm0;
        float mm1 = xs1 + xr1 + e1; mm1 = (mm1 > 0.f) ? mm1 : 0.2f * mm1;
        float a0 = mm0 * satt[c0];
        float a1 = mm1 * satt[c1];
#pragma unroll
        for (int off = 32; off > 0; off >>= 1) {
            a0 += __shfl_xor(a0, off);
            a1 += __shfl_xor(a1, off);
        }
        // online softmax update (branchless)
        float nm0 = fmaxf(rm0, a0);
        float so0 = __expf(rm0 - nm0);
        float sn0 = __expf(a0 - nm0);
        den0 = den0 * so0 + sn0;
        acc0 = acc0 * so0 + sn0 * xs0;
        rm0 = nm0;
        float nm1 = fmaxf(rm1, a1);
        float so1 = __expf(rm1 - nm1);
        float sn1 = __expf(a1 - nm1);
        den1 = den1 * so1 + sn1;
        acc1 = acc1 * so1 + sn1 * xs1;
        rm1 = nm1;
    }
    out[(size_t)i * C_OUT + lane] = 0.5f * (acc0 / den0 + acc1 / den1) + bias[lane];
}

extern "C" void kernel_launch(void* const* d_in, const int* in_sizes, int n_in,
                              void* d_out, int out_size, void* d_ws, size_t ws_size,
                              hipStream_t stream) {
    const int*   x_cat    = (const int*)d_in[0];
    const float* x_cont   = (const float*)d_in[1];
    const int*   e_cat    = (const int*)d_in[2];
    const float* e_cont   = (const float*)d_in[3];
    const int*   ei       = (const int*)d_in[4];
    const float* node_emb = (const float*)d_in[5];
    const float* edge_emb = (const float*)d_in[6];
    const float* eps1     = (const float*)d_in[7];
    const float* W1e      = (const float*)d_in[8];
    const float* b1e      = (const float*)d_in[9];
    const float* W1n      = (const float*)d_in[10];
    const float* b1n      = (const float*)d_in[11];
    const float* g1       = (const float*)d_in[12];
    const float* bb1      = (const float*)d_in[13];
    const float* m1       = (const float*)d_in[14];
    const float* v1       = (const float*)d_in[15];
    const float* eps2     = (const float*)d_in[16];
    const float* W2e      = (const float*)d_in[17];
    const float* b2e      = (const float*)d_in[18];
    const float* W2n      = (const float*)d_in[19];
    const float* b2n      = (const float*)d_in[20];
    const float* g2       = (const float*)d_in[21];
    const float* bb2      = (const float*)d_in[22];
    const float* m2       = (const float*)d_in[23];
    const float* v2       = (const float*)d_in[24];
    const float* Wl       = (const float*)d_in[25];
    const float* bl       = (const float*)d_in[26];
    const float* Wr       = (const float*)d_in[27];
    const float* br       = (const float*)d_in[28];
    const float* Weg      = (const float*)d_in[29];
    const float* att      = (const float*)d_in[30];
    const float* gbias    = (const float*)d_in[31];

    const size_t NF36  = (size_t)N_NODES * NODE_IN;
    const size_t NF128 = (size_t)N_NODES * C_HID;

    float* ws = (float*)d_ws;
    float* x      = ws;               // N*36
    float* f1     = x + NF36;         // N*128 : h1, then xl
    float* f2     = f1 + NF128;       // N*128 : h2
    float* f3     = f2 + NF128;       // N*128 : agg36 / agg128 / xr
    float* ea_sum  = f3 + NF128;      // 16
    float* ee_loop = ea_sum + 16;     // 128
    int* ipool   = (int*)(ee_loop + C_HID);
    int* deg     = ipool;                    // N
    int* cursor  = deg + N_NODES;            // N
    int* rowp    = cursor + N_NODES;         // N+1
    int* csr_eid = rowp + N_NODES + 1;       // E
    int* csr_src = csr_eid + N_EDGES;        // E

    float* h1 = f1;  float* xl = f1;
    float* h2 = f2;
    float* agg36 = f3; float* agg128 = f3; float* xr = f3;

    size_t need = (size_t)((char*)(csr_src + N_EDGES) - (char*)d_ws);
    if (ws_size < need) return;

    hipMemsetAsync(deg, 0, N_NODES * sizeof(int), stream);
    hipMemsetAsync(ea_sum, 0, 16 * sizeof(float), stream);

    const int EB = (N_EDGES + 255) / 256;
    const int NB4 = (N_NODES + 3) / 4;

    k_node_feat<<<(N_NODES * NODE_IN + 255) / 256, 256, 0, stream>>>(
        x_cat, x_cont, node_emb, x);
    k_deg<<<EB, 256, 0, stream>>>(ei, deg);
    k_scan<<<1, SCAN_T, 0, stream>>>(deg, rowp, cursor);
    k_fill<<<EB, 256, 0, stream>>>(ei, cursor, csr_eid, csr_src);

    k_gine1_gather<<<NB4, 256, 0, stream>>>(
        rowp, csr_eid, csr_src, e_cat, e_cont, edge_emb, W1e, b1e, x, agg36);
    k_gine1_node<<<N_NODES / 2, 256, 0, stream>>>(
        x, agg36, eps1, W1n, b1n, g1, bb1, m1, v1, h1);
    k_gine2_gather<<<NB4, 256, 0, stream>>>(
        rowp, csr_eid, csr_src, e_cat, e_cont, edge_emb, W2e, b2e, h1, agg128);
    k_gine2_node<<<N_NODES / 2, 256, 0, stream>>>(
        h1, agg128, eps2, W2n, b2n, g2, bb2, m2, v2, h2);

    k_ea_sum<<<256, 256, 0, stream>>>(e_cat, e_cont, edge_emb, ea_sum);
    k_loop_prep<<<1, C_HID, 0, stream>>>(ea_sum, Weg, ee_loop);

    k_gat0<<<N_NODES / 2, 256, 0, stream>>>(h2, Wl, bl, Wr, br, xl, xr);
    k_gat_fused<<<NB4, 256, 0, stream>>>(
        rowp, csr_eid, csr_src, e_cat, e_cont, edge_emb, Weg, att, ee_loop,
        xl, xr, gbias, (float*)d_out);
}

// Round 3
// 1248.984 us; speedup vs baseline: 9.6757x; 1.1542x over previous
//
#include <hip/hip_runtime.h>
#include <math.h>

#define N_NODES 50000
#define N_EDGES 800000
#define NODE_IN 36
#define EDGE_IN 16
#define C_HID 128
#define C_OUT 64
#define BN_EPS 1e-5f
#define SCAN_T 1024
#define CHUNK ((N_NODES + SCAN_T - 1) / SCAN_T)   // 49

__device__ __forceinline__ int rfl(int v) { return __builtin_amdgcn_readfirstlane(v); }

// select one of 4 per-lane register values by (wave-uniform) cat
__device__ __forceinline__ float sel4(int cat, float a, float b, float c, float d) {
    float r = (cat == 0) ? a : b;
    r = (cat == 2) ? c : r;
    r = (cat == 3) ? d : r;
    return r;
}

// ================= node features =================
__global__ void k_node_feat(const int* __restrict__ xcat,
                            const float* __restrict__ xcont,
                            const float* __restrict__ node_emb,
                            float* __restrict__ x) {
    int idx = blockIdx.x * blockDim.x + threadIdx.x;
    if (idx >= N_NODES * NODE_IN) return;
    int i = idx / NODE_IN;
    int j = idx - i * NODE_IN;
    float v;
    if (j < 20) v = node_emb[xcat[i] * 20 + j];
    else        v = xcont[i * 16 + (j - 20)];
    x[idx] = v;
}

// ================= CSR build =================
__global__ void k_deg(const int* __restrict__ ei, int* __restrict__ deg) {
    int e = blockIdx.x * blockDim.x + threadIdx.x;
    if (e >= N_EDGES) return;
    atomicAdd(deg + ei[N_EDGES + e], 1);
}

__global__ void k_scan(const int* __restrict__ deg, int* __restrict__ rowp,
                       int* __restrict__ cursor) {
    __shared__ int sums[SCAN_T];
    int t = threadIdx.x;
    int lo = t * CHUNK, hi = min(lo + CHUNK, N_NODES);
    int s = 0;
    for (int i = lo; i < hi; i++) s += deg[i];
    sums[t] = s;
    __syncthreads();
    for (int off = 1; off < SCAN_T; off <<= 1) {
        int v = 0;
        if (t >= off) v = sums[t - off];
        __syncthreads();
        if (t >= off) sums[t] += v;
        __syncthreads();
    }
    int run = sums[t] - s;      // exclusive prefix
    for (int i = lo; i < hi; i++) {
        rowp[i] = run;
        cursor[i] = run;
        run += deg[i];
    }
    if (t == SCAN_T - 1) rowp[N_NODES] = sums[SCAN_T - 1];
}

__global__ void k_fill(const int* __restrict__ ei, int* __restrict__ cursor,
                       int* __restrict__ csr_eid, int* __restrict__ csr_src) {
    int e = blockIdx.x * blockDim.x + threadIdx.x;
    if (e >= N_EDGES) return;
    int d = ei[N_EDGES + e];
    int pos = atomicAdd(cursor + d, 1);
    csr_eid[pos] = e;
    csr_src[pos] = ei[e];
}

// ======== GINE1 gather (F=36), scalar metadata + 4-edge batching ========
__global__ void k_gine1_gather(const int* __restrict__ rowp,
                               const int* __restrict__ csr_eid,
                               const int* __restrict__ csr_src,
                               const int* __restrict__ ecat,
                               const float* __restrict__ econt,
                               const float* __restrict__ edge_emb,
                               const float* __restrict__ W,   // [16,36]
                               const float* __restrict__ b,   // [36]
                               const float* __restrict__ x,
                               float* __restrict__ agg) {
    int i = blockIdx.x * 4 + (threadIdx.x >> 6);
    int lane = threadIdx.x & 63;
    if (i >= N_NODES) return;
    int c = (lane < NODE_IN) ? lane : (NODE_IN - 1);
    float w[12];
#pragma unroll
    for (int k = 0; k < 12; k++) w[k] = W[(4 + k) * NODE_IN + c];
    float tb[4];
#pragma unroll
    for (int q = 0; q < 4; q++) {
        float v = b[c];
#pragma unroll
        for (int k = 0; k < 4; k++) v += edge_emb[q * 4 + k] * W[k * NODE_IN + c];
        tb[q] = v;
    }
    int beg = rfl(rowp[i]), end = rfl(rowp[i + 1]);
    float acc = 0.f;
    int p = beg;
    for (; p + 4 <= end; p += 4) {
        int eid[4], src[4], cat[4];
        float4 A[4], B[4], C4[4];
        float xs[4];
#pragma unroll
        for (int bq = 0; bq < 4; bq++) {
            eid[bq] = rfl(csr_eid[p + bq]);
            src[bq] = rfl(csr_src[p + bq]);
            cat[bq] = rfl(ecat[eid[bq]]);
            const float4* ec4 = (const float4*)(econt + (size_t)eid[bq] * 12);
            A[bq] = ec4[0]; B[bq] = ec4[1]; C4[bq] = ec4[2];
            xs[bq] = x[(size_t)src[bq] * NODE_IN + c];
        }
#pragma unroll
        for (int bq = 0; bq < 4; bq++) {
            float t = sel4(cat[bq], tb[0], tb[1], tb[2], tb[3]);
            t += A[bq].x * w[0] + A[bq].y * w[1] + A[bq].z * w[2] + A[bq].w * w[3];
            t += B[bq].x * w[4] + B[bq].y * w[5] + B[bq].z * w[6] + B[bq].w * w[7];
            t += C4[bq].x * w[8] + C4[bq].y * w[9] + C4[bq].z * w[10] + C4[bq].w * w[11];
            acc += fmaxf(xs[bq] + t, 0.f);
        }
    }
    for (; p < end; ++p) {
        int eid = rfl(csr_eid[p]);
        int src = rfl(csr_src[p]);
        int cat = rfl(ecat[eid]);
        const float4* ec4 = (const float4*)(econt + (size_t)eid * 12);
        float4 A = ec4[0], B = ec4[1], C4 = ec4[2];
        float t = sel4(cat, tb[0], tb[1], tb[2], tb[3]);
        t += A.x * w[0] + A.y * w[1] + A.z * w[2] + A.w * w[3];
        t += B.x * w[4] + B.y * w[5] + B.z * w[6] + B.w * w[7];
        t += C4.x * w[8] + C4.y * w[9] + C4.z * w[10] + C4.w * w[11];
        acc += fmaxf(x[(size_t)src * NODE_IN + c] + t, 0.f);
    }
    if (lane < NODE_IN) agg[(size_t)i * NODE_IN + lane] = acc;
}

// ================= GINE1 node MLP + BN =================
__global__ void k_gine1_node(const float* __restrict__ x,
                             const float* __restrict__ agg,
                             const float* __restrict__ eps_p,
                             const float* __restrict__ W,   // [36,128]
                             const float* __restrict__ b,
                             const float* __restrict__ g,
                             const float* __restrict__ bb,
                             const float* __restrict__ m,
                             const float* __restrict__ v,
                             float* __restrict__ h) {
    __shared__ float z[2][NODE_IN];
    int node0 = blockIdx.x * 2;
    float eps = eps_p[0];
    int t = threadIdx.x;
    if (t < 2 * NODE_IN) {
        int n = t / NODE_IN, j = t - n * NODE_IN;
        int i = node0 + n;
        if (i < N_NODES)
            z[n][j] = (1.f + eps) * x[(size_t)i * NODE_IN + j] + agg[(size_t)i * NODE_IN + j];
    }
    __syncthreads();
    int n = t >> 7, c = t & 127;
    int i = node0 + n;
    if (i >= N_NODES) return;
    float acc = b[c];
#pragma unroll 4
    for (int j = 0; j < NODE_IN; j++) acc += z[n][j] * W[j * C_HID + c];
    acc = fmaxf(acc, 0.f);
    float sc = g[c] * rsqrtf(v[c] + BN_EPS);
    h[(size_t)i * C_HID + c] = (acc - m[c]) * sc + bb[c];
}

// ======== GINE2 gather (F=128), scalar metadata + 4-edge batching ========
__global__ void k_gine2_gather(const int* __restrict__ rowp,
                               const int* __restrict__ csr_eid,
                               const int* __restrict__ csr_src,
                               const int* __restrict__ ecat,
                               const float* __restrict__ econt,
                               const float* __restrict__ edge_emb,
                               const float* __restrict__ W,   // [16,128]
                               const float* __restrict__ b,   // [128]
                               const float* __restrict__ h1,
                               float* __restrict__ agg) {
    int i = blockIdx.x * 4 + (threadIdx.x >> 6);
    int lane = threadIdx.x & 63;
    if (i >= N_NODES) return;
    int c0 = lane, c1 = lane + 64;
    float w0[12], w1[12];
#pragma unroll
    for (int k = 0; k < 12; k++) {
        w0[k] = W[(4 + k) * C_HID + c0];
        w1[k] = W[(4 + k) * C_HID + c1];
    }
    float tb0[4], tb1[4];
#pragma unroll
    for (int q = 0; q < 4; q++) {
        float v0 = b[c0], v1 = b[c1];
#pragma unroll
        for (int k = 0; k < 4; k++) {
            float ev = edge_emb[q * 4 + k];
            v0 += ev * W[k * C_HID + c0];
            v1 += ev * W[k * C_HID + c1];
        }
        tb0[q] = v0; tb1[q] = v1;
    }
    int beg = rfl(rowp[i]), end = rfl(rowp[i + 1]);
    float acc0 = 0.f, acc1 = 0.f;
    int p = beg;
    for (; p + 4 <= end; p += 4) {
        int eid[4], src[4], cat[4];
        float4 A[4], B[4], C4[4];
        float xs0[4], xs1[4];
#pragma unroll
        for (int bq = 0; bq < 4; bq++) {
            eid[bq] = rfl(csr_eid[p + bq]);
            src[bq] = rfl(csr_src[p + bq]);
            cat[bq] = rfl(ecat[eid[bq]]);
            const float4* ec4 = (const float4*)(econt + (size_t)eid[bq] * 12);
            A[bq] = ec4[0]; B[bq] = ec4[1]; C4[bq] = ec4[2];
            const float* hs = h1 + (size_t)src[bq] * C_HID;
            xs0[bq] = hs[c0]; xs1[bq] = hs[c1];
        }
#pragma unroll
        for (int bq = 0; bq < 4; bq++) {
            float t0 = sel4(cat[bq], tb0[0], tb0[1], tb0[2], tb0[3]);
            float t1 = sel4(cat[bq], tb1[0], tb1[1], tb1[2], tb1[3]);
            t0 += A[bq].x * w0[0] + A[bq].y * w0[1] + A[bq].z * w0[2] + A[bq].w * w0[3];
            t1 += A[bq].x * w1[0] + A[bq].y * w1[1] + A[bq].z * w1[2] + A[bq].w * w1[3];
            t0 += B[bq].x * w0[4] + B[bq].y * w0[5] + B[bq].z * w0[6] + B[bq].w * w0[7];
            t1 += B[bq].x * w1[4] + B[bq].y * w1[5] + B[bq].z * w1[6] + B[bq].w * w1[7];
            t0 += C4[bq].x * w0[8] + C4[bq].y * w0[9] + C4[bq].z * w0[10] + C4[bq].w * w0[11];
            t1 += C4[bq].x * w1[8] + C4[bq].y * w1[9] + C4[bq].z * w1[10] + C4[bq].w * w1[11];
            acc0 += fmaxf(xs0[bq] + t0, 0.f);
            acc1 += fmaxf(xs1[bq] + t1, 0.f);
        }
    }
    for (; p < end; ++p) {
        int eid = rfl(csr_eid[p]);
        int src = rfl(csr_src[p]);
        int cat = rfl(ecat[eid]);
        const float4* ec4 = (const float4*)(econt + (size_t)eid * 12);
        float4 A = ec4[0], B = ec4[1], C4 = ec4[2];
        float t0 = sel4(cat, tb0[0], tb0[1], tb0[2], tb0[3]);
        float t1 = sel4(cat, tb1[0], tb1[1], tb1[2], tb1[3]);
        t0 += A.x * w0[0] + A.y * w0[1] + A.z * w0[2] + A.w * w0[3];
        t1 += A.x * w1[0] + A.y * w1[1] + A.z * w1[2] + A.w * w1[3];
        t0 += B.x * w0[4] + B.y * w0[5] + B.z * w0[6] + B.w * w0[7];
        t1 += B.x * w1[4] + B.y * w1[5] + B.z * w1[6] + B.w * w1[7];
        t0 += C4.x * w0[8] + C4.y * w0[9] + C4.z * w0[10] + C4.w * w0[11];
        t1 += C4.x * w1[8] + C4.y * w1[9] + C4.z * w1[10] + C4.w * w1[11];
        const float* hs = h1 + (size_t)src * C_HID;
        acc0 += fmaxf(hs[c0] + t0, 0.f);
        acc1 += fmaxf(hs[c1] + t1, 0.f);
    }
    agg[(size_t)i * C_HID + c0] = acc0;
    agg[(size_t)i * C_HID + c1] = acc1;
}

// ================= GINE2 node MLP + BN =================
__global__ void k_gine2_node(const float* __restrict__ h1,
                             const float* __restrict__ agg,
                             const float* __restrict__ eps_p,
                             const float* __restrict__ W,   // [128,128]
                             const float* __restrict__ b,
                             const float* __restrict__ g,
                             const float* __restrict__ bb,
                             const float* __restrict__ m,
                             const float* __restrict__ v,
                             float* __restrict__ h2) {
    __shared__ float z[2][C_HID];
    int node0 = blockIdx.x * 2;
    float eps = eps_p[0];
    int t = threadIdx.x;
    {
        int n = t >> 7, j = t & 127;
        int i = node0 + n;
        if (i < N_NODES)
            z[n][j] = (1.f + eps) * h1[(size_t)i * C_HID + j] + agg[(size_t)i * C_HID + j];
    }
    __syncthreads();
    int n = t >> 7, c = t & 127;
    int i = node0 + n;
    if (i >= N_NODES) return;
    float acc = b[c];
#pragma unroll 8
    for (int j = 0; j < C_HID; j++) acc += z[n][j] * W[j * C_HID + c];
    acc = fmaxf(acc, 0.f);
    float sc = g[c] * rsqrtf(v[c] + BN_EPS);
    h2[(size_t)i * C_HID + c] = (acc - m[c]) * sc + bb[c];
}

// ================= mean edge feature =================
__global__ void k_ea_sum(const int* __restrict__ ecat,
                         const float* __restrict__ econt,
                         const float* __restrict__ edge_emb,
                         float* __restrict__ ea_sum) {
    float p[16];
#pragma unroll
    for (int k = 0; k < 16; k++) p[k] = 0.f;
    for (int e = blockIdx.x * blockDim.x + threadIdx.x; e < N_EDGES;
         e += gridDim.x * blockDim.x) {
        int c = ecat[e];
#pragma unroll
        for (int k = 0; k < 4; k++) p[k] += edge_emb[c * 4 + k];
#pragma unroll
        for (int k = 0; k < 12; k++) p[4 + k] += econt[e * 12 + k];
    }
#pragma unroll
    for (int k = 0; k < 16; k++) {
        float v = p[k];
        for (int off = 32; off > 0; off >>= 1) v += __shfl_down(v, off);
        if ((threadIdx.x & 63) == 0) atomicAdd(ea_sum + k, v);
    }
}

__global__ void k_loop_prep(const float* __restrict__ ea_sum,
                            const float* __restrict__ We,
                            float* __restrict__ ee_loop) {
    int c = threadIdx.x;
    float acc = 0.f;
#pragma unroll
    for (int k = 0; k < 16; k++)
        acc += (ea_sum[k] * (1.f / N_EDGES)) * We[k * C_HID + c];
    ee_loop[c] = acc;
}

// ================= GAT node transforms: xl, xr =================
__global__ void k_gat0(const float* __restrict__ h2,
                       const float* __restrict__ Wl, const float* __restrict__ bl,
                       const float* __restrict__ Wr, const float* __restrict__ br,
                       float* __restrict__ xl, float* __restrict__ xr) {
    __shared__ float z[2][C_HID];
    int node0 = blockIdx.x * 2;
    int t = threadIdx.x;
    {
        int n = t >> 7, j = t & 127;
        int i = node0 + n;
        if (i < N_NODES) z[n][j] = h2[(size_t)i * C_HID + j];
    }
    __syncthreads();
    int n = t >> 7, c = t & 127;
    int i = node0 + n;
    if (i >= N_NODES) return;
    float al = bl[c], ar = br[c];
#pragma unroll 8
    for (int j = 0; j < C_HID; j++) {
        float zz = z[n][j];
        al += zz * Wl[j * C_HID + c];
        ar += zz * Wr[j * C_HID + c];
    }
    xl[(size_t)i * C_HID + c] = al;
    xr[(size_t)i * C_HID + c] = ar;
}

// ===== GAT fused: scalar metadata, 4-edge batch, batched online softmax =====
__global__ void k_gat_fused(const int* __restrict__ rowp,
                            const int* __restrict__ csr_eid,
                            const int* __restrict__ csr_src,
                            const int* __restrict__ ecat,
                            const float* __restrict__ econt,
                            const float* __restrict__ edge_emb,
                            const float* __restrict__ We,    // [16,128]
                            const float* __restrict__ att,   // [128]
                            const float* __restrict__ ee_loop,
                            const float* __restrict__ xl,
                            const float* __restrict__ xr,
                            const float* __restrict__ bias,  // [64]
                            float* __restrict__ out) {
    int i = blockIdx.x * 4 + (threadIdx.x >> 6);
    int lane = threadIdx.x & 63;
    if (i >= N_NODES) return;
    int c0 = lane, c1 = lane + 64;
    float w0[12], w1[12];
#pragma unroll
    for (int k = 0; k < 12; k++) {
        w0[k] = We[(4 + k) * C_HID + c0];
        w1[k] = We[(4 + k) * C_HID + c1];
    }
    float tb0[4], tb1[4];
#pragma unroll
    for (int q = 0; q < 4; q++) {
        float v0 = 0.f, v1 = 0.f;
#pragma unroll
        for (int k = 0; k < 4; k++) {
            float ev = edge_emb[q * 4 + k];
            v0 += ev * We[k * C_HID + c0];
            v1 += ev * We[k * C_HID + c1];
        }
        tb0[q] = v0; tb1[q] = v1;
    }
    float at0 = att[c0], at1 = att[c1];
    float lp0 = ee_loop[c0], lp1 = ee_loop[c1];

    float xr0 = xr[(size_t)i * C_HID + c0];
    float xr1 = xr[(size_t)i * C_HID + c1];
    float xld0 = xl[(size_t)i * C_HID + c0];
    float xld1 = xl[(size_t)i * C_HID + c1];

    // self-loop alpha
    float m0 = xld0 + xr0 + lp0; m0 = (m0 > 0.f) ? m0 : 0.2f * m0;
    float m1 = xld1 + xr1 + lp1; m1 = (m1 > 0.f) ? m1 : 0.2f * m1;
    float v0 = m0 * at0;
    float v1 = m1 * at1;
#pragma unroll
    for (int off = 32; off > 0; off >>= 1) {
        v0 += __shfl_xor(v0, off);
        v1 += __shfl_xor(v1, off);
    }
    float rm0 = v0, rm1 = v1;
    float den0 = 1.f, den1 = 1.f;
    float acc0 = xld0, acc1 = xld1;

    int beg = rfl(rowp[i]), end = rfl(rowp[i + 1]);
    int p = beg;
    for (; p + 4 <= end; p += 4) {
        int eid[4], src[4], cat[4];
        float4 A[4], B[4], C4[4];
        float xs0[4], xs1[4];
#pragma unroll
        for (int bq = 0; bq < 4; bq++) {
            eid[bq] = rfl(csr_eid[p + bq]);
            src[bq] = rfl(csr_src[p + bq]);
            cat[bq] = rfl(ecat[eid[bq]]);
            const float4* ec4 = (const float4*)(econt + (size_t)eid[bq] * 12);
            A[bq] = ec4[0]; B[bq] = ec4[1]; C4[bq] = ec4[2];
            const float* xls = xl + (size_t)src[bq] * C_HID;
            xs0[bq] = xls[c0]; xs1[bq] = xls[c1];
        }
        float d0[4], d1[4];
#pragma unroll
        for (int bq = 0; bq < 4; bq++) {
            float e0 = sel4(cat[bq], tb0[0], tb0[1], tb0[2], tb0[3]);
            float e1 = sel4(cat[bq], tb1[0], tb1[1], tb1[2], tb1[3]);
            e0 += A[bq].x * w0[0] + A[bq].y * w0[1] + A[bq].z * w0[2] + A[bq].w * w0[3];
            e1 += A[bq].x * w1[0] + A[bq].y * w1[1] + A[bq].z * w1[2] + A[bq].w * w1[3];
            e0 += B[bq].x * w0[4] + B[bq].y * w0[5] + B[bq].z * w0[6] + B[bq].w * w0[7];
            e1 += B[bq].x * w1[4] + B[bq].y * w1[5] + B[bq].z * w1[6] + B[bq].w * w1[7];
            e0 += C4[bq].x * w0[8] + C4[bq].y * w0[9] + C4[bq].z * w0[10] + C4[bq].w * w0[11];
            e1 += C4[bq].x * w1[8] + C4[bq].y * w1[9] + C4[bq].z * w1[10] + C4[bq].w * w1[11];
            float z0 = xs0[bq] + xr0 + e0; z0 = (z0 > 0.f) ? z0 : 0.2f * z0;
            float z1 = xs1[bq] + xr1 + e1; z1 = (z1 > 0.f) ? z1 : 0.2f * z1;
            d0[bq] = z0 * at0;
            d1[bq] = z1 * at1;
        }
        // 8 independent butterfly chains, interleaved
#pragma unroll
        for (int off = 32; off > 0; off >>= 1) {
#pragma unroll
            for (int bq = 0; bq < 4; bq++) {
                d0[bq] += __shfl_xor(d0[bq], off);
                d1[bq] += __shfl_xor(d1[bq], off);
            }
        }
        // batched online-softmax merge (head 0)
        {
            float bm = fmaxf(fmaxf(d0[0], d0[1]), fmaxf(d0[2], d0[3]));
            float nm = fmaxf(rm0, bm);
            float r = __expf(rm0 - nm);
            float p0 = __expf(d0[0] - nm), p1 = __expf(d0[1] - nm);
            float p2 = __expf(d0[2] - nm), p3 = __expf(d0[3] - nm);
            den0 = den0 * r + ((p0 + p1) + (p2 + p3));
            acc0 = acc0 * r + (p0 * xs0[0] + p1 * xs0[1] + p2 * xs0[2] + p3 * xs0[3]);
            rm0 = nm;
        }
        // head 1
        {
            float bm = fmaxf(fmaxf(d1[0], d1[1]), fmaxf(d1[2], d1[3]));
            float nm = fmaxf(rm1, bm);
            float r = __expf(rm1 - nm);
            float p0 = __expf(d1[0] - nm), p1 = __expf(d1[1] - nm);
            float p2 = __expf(d1[2] - nm), p3 = __expf(d1[3] - nm);
            den1 = den1 * r + ((p0 + p1) + (p2 + p3));
            acc1 = acc1 * r + (p0 * xs1[0] + p1 * xs1[1] + p2 * xs1[2] + p3 * xs1[3]);
            rm1 = nm;
        }
    }
    for (; p < end; ++p) {
        int eid = rfl(csr_eid[p]);
        int src = rfl(csr_src[p]);
        int cat = rfl(ecat[eid]);
        const float4* ec4 = (const float4*)(econt + (size_t)eid * 12);
        float4 A = ec4[0], B = ec4[1], C4 = ec4[2];
        float e0 = sel4(cat, tb0[0], tb0[1], tb0[2], tb0[3]);
        float e1 = sel4(cat, tb1[0], tb1[1], tb1[2], tb1[3]);
        e0 += A.x * w0[0] + A.y * w0[1] + A.z * w0[2] + A.w * w0[3];
        e1 += A.x * w1[0] + A.y * w1[1] + A.z * w1[2] + A.w * w1[3];
        e0 += B.x * w0[4] + B.y * w0[5] + B.z * w0[6] + B.w * w0[7];
        e1 += B.x * w1[4] + B.y * w1[5] + B.z * w1[6] + B.w * w1[7];
        e0 += C4.x * w0[8] + C4.y * w0[9] + C4.z * w0[10] + C4.w * w0[11];
        e1 += C4.x * w1[8] + C4.y * w1[9] + C4.z * w1[10] + C4.w * w1[11];
        const float* xls = xl + (size_t)src * C_HID;
        float xs0 = xls[c0], xs1 = xls[c1];
        float z0 = xs0 + xr0 + e0; z0 = (z0 > 0.f) ? z0 : 0.2f * z0;
        float z1 = xs1 + xr1 + e1; z1 = (z1 > 0.f) ? z1 : 0.2f * z1;
        float a0 = z0 * at0;
        float a1 = z1 * at1;
#pragma unroll
        for (int off = 32; off > 0; off >>= 1) {
            a0 += __shfl_xor(a0, off);
            a1 += __shfl_xor(a1, off);
        }
        float nm0 = fmaxf(rm0, a0);
        float so0 = __expf(rm0 - nm0);
        float sn0 = __expf(a0 - nm0);
        den0 = den0 * so0 + sn0;
        acc0 = acc0 * so0 + sn0 * xs0;
        rm0 = nm0;
        float nm1 = fmaxf(rm1, a1);
        float so1 = __expf(rm1 - nm1);
        float sn1 = __expf(a1 - nm1);
        den1 = den1 * so1 + sn1;
        acc1 = acc1 * so1 + sn1 * xs1;
        rm1 = nm1;
    }
    out[(size_t)i * C_OUT + lane] = 0.5f * (acc0 / den0 + acc1 / den1) + bias[lane];
}

extern "C" void kernel_launch(void* const* d_in, const int* in_sizes, int n_in,
                              void* d_out, int out_size, void* d_ws, size_t ws_size,
                              hipStream_t stream) {
    const int*   x_cat    = (const int*)d_in[0];
    const float* x_cont   = (const float*)d_in[1];
    const int*   e_cat    = (const int*)d_in[2];
    const float* e_cont   = (const float*)d_in[3];
    const int*   ei       = (const int*)d_in[4];
    const float* node_emb = (const float*)d_in[5];
    const float* edge_emb = (const float*)d_in[6];
    const float* eps1     = (const float*)d_in[7];
    const float* W1e      = (const float*)d_in[8];
    const float* b1e      = (const float*)d_in[9];
    const float* W1n      = (const float*)d_in[10];
    const float* b1n      = (const float*)d_in[11];
    const float* g1       = (const float*)d_in[12];
    const float* bb1      = (const float*)d_in[13];
    const float* m1       = (const float*)d_in[14];
    const float* v1       = (const float*)d_in[15];
    const float* eps2     = (const float*)d_in[16];
    const float* W2e      = (const float*)d_in[17];
    const float* b2e      = (const float*)d_in[18];
    const float* W2n      = (const float*)d_in[19];
    const float* b2n      = (const float*)d_in[20];
    const float* g2       = (const float*)d_in[21];
    const float* bb2      = (const float*)d_in[22];
    const float* m2       = (const float*)d_in[23];
    const float* v2       = (const float*)d_in[24];
    const float* Wl       = (const float*)d_in[25];
    const float* bl       = (const float*)d_in[26];
    const float* Wr       = (const float*)d_in[27];
    const float* br       = (const float*)d_in[28];
    const float* Weg      = (const float*)d_in[29];
    const float* att      = (const float*)d_in[30];
    const float* gbias    = (const float*)d_in[31];

    const size_t NF36  = (size_t)N_NODES * NODE_IN;
    const size_t NF128 = (size_t)N_NODES * C_HID;

    float* ws = (float*)d_ws;
    float* x      = ws;               // N*36
    float* f1     = x + NF36;         // N*128 : h1, then xl
    float* f2     = f1 + NF128;       // N*128 : h2
    float* f3     = f2 + NF128;       // N*128 : agg36 / agg128 / xr
    float* ea_sum  = f3 + NF128;      // 16
    float* ee_loop = ea_sum + 16;     // 128
    int* ipool   = (int*)(ee_loop + C_HID);
    int* deg     = ipool;                    // N
    int* cursor  = deg + N_NODES;            // N
    int* rowp    = cursor + N_NODES;         // N+1
    int* csr_eid = rowp + N_NODES + 1;       // E
    int* csr_src = csr_eid + N_EDGES;        // E

    float* h1 = f1;  float* xl = f1;
    float* h2 = f2;
    float* agg36 = f3; float* agg128 = f3; float* xr = f3;

    size_t need = (size_t)((char*)(csr_src + N_EDGES) - (char*)d_ws);
    if (ws_size < need) return;

    hipMemsetAsync(deg, 0, N_NODES * sizeof(int), stream);
    hipMemsetAsync(ea_sum, 0, 16 * sizeof(float), stream);

    const int EB = (N_EDGES + 255) / 256;
    const int NB4 = (N_NODES + 3) / 4;

    k_node_feat<<<(N_NODES * NODE_IN + 255) / 256, 256, 0, stream>>>(
        x_cat, x_cont, node_emb, x);
    k_deg<<<EB, 256, 0, stream>>>(ei, deg);
    k_scan<<<1, SCAN_T, 0, stream>>>(deg, rowp, cursor);
    k_fill<<<EB, 256, 0, stream>>>(ei, cursor, csr_eid, csr_src);

    k_gine1_gather<<<NB4, 256, 0, stream>>>(
        rowp, csr_eid, csr_src, e_cat, e_cont, edge_emb, W1e, b1e, x, agg36);
    k_gine1_node<<<N_NODES / 2, 256, 0, stream>>>(
        x, agg36, eps1, W1n, b1n, g1, bb1, m1, v1, h1);
    k_gine2_gather<<<NB4, 256, 0, stream>>>(
        rowp, csr_eid, csr_src, e_cat, e_cont, edge_emb, W2e, b2e, h1, agg128);
    k_gine2_node<<<N_NODES / 2, 256, 0, stream>>>(
        h1, agg128, eps2, W2n, b2n, g2, bb2, m2, v2, h2);

    k_ea_sum<<<256, 256, 0, stream>>>(e_cat, e_cont, edge_emb, ea_sum);
    k_loop_prep<<<1, C_HID, 0, stream>>>(ea_sum, Weg, ee_loop);

    k_gat0<<<N_NODES / 2, 256, 0, stream>>>(h2, Wl, bl, Wr, br, xl, xr);
    k_gat_fused<<<NB4, 256, 0, stream>>>(
        rowp, csr_eid, csr_src, e_cat, e_cont, edge_emb, Weg, att, ee_loop,
        xl, xr, gbias, (float*)d_out);
}

// Round 4
// 981.303 us; speedup vs baseline: 12.3151x; 1.2728x over previous
//
#include <hip/hip_runtime.h>
#include <math.h>

#define N_NODES 50000
#define N_EDGES 800000
#define NODE_IN 36
#define EDGE_IN 16
#define C_HID 128
#define C_OUT 64
#define BN_EPS 1e-5f
#define SCAN_T 1024
#define CHUNK ((N_NODES + SCAN_T - 1) / SCAN_T)   // 49
#define DT_NT 32    // nodes per block in dense tiled kernels

__device__ __forceinline__ int rfl(int v) { return __builtin_amdgcn_readfirstlane(v); }

// select one of 4 per-lane register values by (wave-uniform) cat
__device__ __forceinline__ float sel4(int cat, float a, float b, float c, float d) {
    float r = (cat == 0) ? a : b;
    r = (cat == 2) ? c : r;
    r = (cat == 3) ? d : r;
    return r;
}

// ================= node features =================
__global__ void k_node_feat(const int* __restrict__ xcat,
                            const float* __restrict__ xcont,
                            const float* __restrict__ node_emb,
                            float* __restrict__ x) {
    int idx = blockIdx.x * blockDim.x + threadIdx.x;
    if (idx >= N_NODES * NODE_IN) return;
    int i = idx / NODE_IN;
    int j = idx - i * NODE_IN;
    float v;
    if (j < 20) v = node_emb[xcat[i] * 20 + j];
    else        v = xcont[i * 16 + (j - 20)];
    x[idx] = v;
}

// ================= CSR build =================
__global__ void k_deg(const int* __restrict__ ei, int* __restrict__ deg) {
    int e = blockIdx.x * blockDim.x + threadIdx.x;
    if (e >= N_EDGES) return;
    atomicAdd(deg + ei[N_EDGES + e], 1);
}

__global__ void k_scan(const int* __restrict__ deg, int* __restrict__ rowp,
                       int* __restrict__ cursor) {
    __shared__ int sums[SCAN_T];
    int t = threadIdx.x;
    int lo = t * CHUNK, hi = min(lo + CHUNK, N_NODES);
    int s = 0;
    for (int i = lo; i < hi; i++) s += deg[i];
    sums[t] = s;
    __syncthreads();
    for (int off = 1; off < SCAN_T; off <<= 1) {
        int v = 0;
        if (t >= off) v = sums[t - off];
        __syncthreads();
        if (t >= off) sums[t] += v;
        __syncthreads();
    }
    int run = sums[t] - s;      // exclusive prefix
    for (int i = lo; i < hi; i++) {
        rowp[i] = run;
        cursor[i] = run;
        run += deg[i];
    }
    if (t == SCAN_T - 1) rowp[N_NODES] = sums[SCAN_T - 1];
}

__global__ void k_fill(const int* __restrict__ ei, int* __restrict__ cursor,
                       int* __restrict__ csr_eid, int* __restrict__ csr_src) {
    int e = blockIdx.x * blockDim.x + threadIdx.x;
    if (e >= N_EDGES) return;
    int d = ei[N_EDGES + e];
    int pos = atomicAdd(cursor + d, 1);
    csr_eid[pos] = e;
    csr_src[pos] = ei[e];
}

// ======== GINE1 gather (F=36), scalar metadata + 4-edge batching ========
__global__ void k_gine1_gather(const int* __restrict__ rowp,
                               const int* __restrict__ csr_eid,
                               const int* __restrict__ csr_src,
                               const int* __restrict__ ecat,
                               const float* __restrict__ econt,
                               const float* __restrict__ edge_emb,
                               const float* __restrict__ W,   // [16,36]
                               const float* __restrict__ b,   // [36]
                               const float* __restrict__ x,
                               float* __restrict__ agg) {
    int i = blockIdx.x * 4 + (threadIdx.x >> 6);
    int lane = threadIdx.x & 63;
    if (i >= N_NODES) return;
    int c = (lane < NODE_IN) ? lane : (NODE_IN - 1);
    float w[12];
#pragma unroll
    for (int k = 0; k < 12; k++) w[k] = W[(4 + k) * NODE_IN + c];
    float tb[4];
#pragma unroll
    for (int q = 0; q < 4; q++) {
        float v = b[c];
#pragma unroll
        for (int k = 0; k < 4; k++) v += edge_emb[q * 4 + k] * W[k * NODE_IN + c];
        tb[q] = v;
    }
    int beg = rfl(rowp[i]), end = rfl(rowp[i + 1]);
    float acc = 0.f;
    int p = beg;
    for (; p + 4 <= end; p += 4) {
        int eid[4], src[4], cat[4];
        float4 A[4], B[4], C4[4];
        float xs[4];
#pragma unroll
        for (int bq = 0; bq < 4; bq++) {
            eid[bq] = rfl(csr_eid[p + bq]);
            src[bq] = rfl(csr_src[p + bq]);
            cat[bq] = rfl(ecat[eid[bq]]);
            const float4* ec4 = (const float4*)(econt + (size_t)eid[bq] * 12);
            A[bq] = ec4[0]; B[bq] = ec4[1]; C4[bq] = ec4[2];
            xs[bq] = x[(size_t)src[bq] * NODE_IN + c];
        }
#pragma unroll
        for (int bq = 0; bq < 4; bq++) {
            float t = sel4(cat[bq], tb[0], tb[1], tb[2], tb[3]);
            t += A[bq].x * w[0] + A[bq].y * w[1] + A[bq].z * w[2] + A[bq].w * w[3];
            t += B[bq].x * w[4] + B[bq].y * w[5] + B[bq].z * w[6] + B[bq].w * w[7];
            t += C4[bq].x * w[8] + C4[bq].y * w[9] + C4[bq].z * w[10] + C4[bq].w * w[11];
            acc += fmaxf(xs[bq] + t, 0.f);
        }
    }
    for (; p < end; ++p) {
        int eid = rfl(csr_eid[p]);
        int src = rfl(csr_src[p]);
        int cat = rfl(ecat[eid]);
        const float4* ec4 = (const float4*)(econt + (size_t)eid * 12);
        float4 A = ec4[0], B = ec4[1], C4 = ec4[2];
        float t = sel4(cat, tb[0], tb[1], tb[2], tb[3]);
        t += A.x * w[0] + A.y * w[1] + A.z * w[2] + A.w * w[3];
        t += B.x * w[4] + B.y * w[5] + B.z * w[6] + B.w * w[7];
        t += C4.x * w[8] + C4.y * w[9] + C4.z * w[10] + C4.w * w[11];
        acc += fmaxf(x[(size_t)src * NODE_IN + c] + t, 0.f);
    }
    if (lane < NODE_IN) agg[(size_t)i * NODE_IN + lane] = acc;
}

// ===== GINE1 node MLP + BN, tiled: 32 nodes/block, 4x4 register block =====
__global__ __launch_bounds__(256) void k_gine1_node(
        const float* __restrict__ x, const float* __restrict__ agg,
        const float* __restrict__ eps_p,
        const float* __restrict__ W,   // [36,128]
        const float* __restrict__ b, const float* __restrict__ g,
        const float* __restrict__ bb, const float* __restrict__ m,
        const float* __restrict__ v, float* __restrict__ h) {
    __shared__ float sW[NODE_IN * C_HID];     // 18 KB
    __shared__ float sz[DT_NT * NODE_IN];     // 4.5 KB
    int tid = threadIdx.x;
    int node0 = blockIdx.x * DT_NT;
    float eps = eps_p[0];
    {
        const float4* Wv = (const float4*)W;
        float4* sWv = (float4*)sW;
        for (int t = tid; t < NODE_IN * C_HID / 4; t += 256) sWv[t] = Wv[t];
    }
    {
        int nmax = min(DT_NT, N_NODES - node0);
        int tot = nmax * NODE_IN / 4;
        const float4* xv = (const float4*)(x + (size_t)node0 * NODE_IN);
        const float4* av = (const float4*)(agg + (size_t)node0 * NODE_IN);
        float4* szv = (float4*)sz;
        float s = 1.f + eps;
        for (int t = tid; t < tot; t += 256) {
            float4 a = xv[t], c = av[t];
            float4 r;
            r.x = s * a.x + c.x; r.y = s * a.y + c.y;
            r.z = s * a.z + c.z; r.w = s * a.w + c.w;
            szv[t] = r;
        }
    }
    __syncthreads();
    int cg = tid & 31, c0 = cg * 4;
    int n0 = (tid >> 5) * 4;
    float4 bi = *(const float4*)&b[c0];
    float acc[4][4];
#pragma unroll
    for (int n = 0; n < 4; n++) {
        acc[n][0] = bi.x; acc[n][1] = bi.y; acc[n][2] = bi.z; acc[n][3] = bi.w;
    }
    for (int jb = 0; jb < NODE_IN; jb += 4) {
        float4 w0 = *(const float4*)&sW[(jb + 0) * C_HID + c0];
        float4 w1 = *(const float4*)&sW[(jb + 1) * C_HID + c0];
        float4 w2 = *(const float4*)&sW[(jb + 2) * C_HID + c0];
        float4 w3 = *(const float4*)&sW[(jb + 3) * C_HID + c0];
#pragma unroll
        for (int n = 0; n < 4; n++) {
            float4 zz = *(const float4*)&sz[(n0 + n) * NODE_IN + jb];
            acc[n][0] += zz.x * w0.x + zz.y * w1.x + zz.z * w2.x + zz.w * w3.x;
            acc[n][1] += zz.x * w0.y + zz.y * w1.y + zz.z * w2.y + zz.w * w3.y;
            acc[n][2] += zz.x * w0.z + zz.y * w1.z + zz.z * w2.z + zz.w * w3.z;
            acc[n][3] += zz.x * w0.w + zz.y * w1.w + zz.z * w2.w + zz.w * w3.w;
        }
    }
    float4 gg = *(const float4*)&g[c0];
    float4 mm = *(const float4*)&m[c0];
    float4 vv = *(const float4*)&v[c0];
    float4 bbv = *(const float4*)&bb[c0];
    float4 sc;
    sc.x = gg.x * rsqrtf(vv.x + BN_EPS); sc.y = gg.y * rsqrtf(vv.y + BN_EPS);
    sc.z = gg.z * rsqrtf(vv.z + BN_EPS); sc.w = gg.w * rsqrtf(vv.w + BN_EPS);
#pragma unroll
    for (int n = 0; n < 4; n++) {
        int i = node0 + n0 + n;
        if (i < N_NODES) {
            float4 o;
            o.x = (fmaxf(acc[n][0], 0.f) - mm.x) * sc.x + bbv.x;
            o.y = (fmaxf(acc[n][1], 0.f) - mm.y) * sc.y + bbv.y;
            o.z = (fmaxf(acc[n][2], 0.f) - mm.z) * sc.z + bbv.z;
            o.w = (fmaxf(acc[n][3], 0.f) - mm.w) * sc.w + bbv.w;
            *(float4*)&h[(size_t)i * C_HID + c0] = o;
        }
    }
}

// ======== GINE2 gather (F=128), scalar metadata + 4-edge batching ========
__global__ void k_gine2_gather(const int* __restrict__ rowp,
                               const int* __restrict__ csr_eid,
                               const int* __restrict__ csr_src,
                               const int* __restrict__ ecat,
                               const float* __restrict__ econt,
                               const float* __restrict__ edge_emb,
                               const float* __restrict__ W,   // [16,128]
                               const float* __restrict__ b,   // [128]
                               const float* __restrict__ h1,
                               float* __restrict__ agg) {
    int i = blockIdx.x * 4 + (threadIdx.x >> 6);
    int lane = threadIdx.x & 63;
    if (i >= N_NODES) return;
    int c0 = lane, c1 = lane + 64;
    float w0[12], w1[12];
#pragma unroll
    for (int k = 0; k < 12; k++) {
        w0[k] = W[(4 + k) * C_HID + c0];
        w1[k] = W[(4 + k) * C_HID + c1];
    }
    float tb0[4], tb1[4];
#pragma unroll
    for (int q = 0; q < 4; q++) {
        float v0 = b[c0], v1 = b[c1];
#pragma unroll
        for (int k = 0; k < 4; k++) {
            float ev = edge_emb[q * 4 + k];
            v0 += ev * W[k * C_HID + c0];
            v1 += ev * W[k * C_HID + c1];
        }
        tb0[q] = v0; tb1[q] = v1;
    }
    int beg = rfl(rowp[i]), end = rfl(rowp[i + 1]);
    float acc0 = 0.f, acc1 = 0.f;
    int p = beg;
    for (; p + 4 <= end; p += 4) {
        int eid[4], src[4], cat[4];
        float4 A[4], B[4], C4[4];
        float xs0[4], xs1[4];
#pragma unroll
        for (int bq = 0; bq < 4; bq++) {
            eid[bq] = rfl(csr_eid[p + bq]);
            src[bq] = rfl(csr_src[p + bq]);
            cat[bq] = rfl(ecat[eid[bq]]);
            const float4* ec4 = (const float4*)(econt + (size_t)eid[bq] * 12);
            A[bq] = ec4[0]; B[bq] = ec4[1]; C4[bq] = ec4[2];
            const float* hs = h1 + (size_t)src[bq] * C_HID;
            xs0[bq] = hs[c0]; xs1[bq] = hs[c1];
        }
#pragma unroll
        for (int bq = 0; bq < 4; bq++) {
            float t0 = sel4(cat[bq], tb0[0], tb0[1], tb0[2], tb0[3]);
            float t1 = sel4(cat[bq], tb1[0], tb1[1], tb1[2], tb1[3]);
            t0 += A[bq].x * w0[0] + A[bq].y * w0[1] + A[bq].z * w0[2] + A[bq].w * w0[3];
            t1 += A[bq].x * w1[0] + A[bq].y * w1[1] + A[bq].z * w1[2] + A[bq].w * w1[3];
            t0 += B[bq].x * w0[4] + B[bq].y * w0[5] + B[bq].z * w0[6] + B[bq].w * w0[7];
            t1 += B[bq].x * w1[4] + B[bq].y * w1[5] + B[bq].z * w1[6] + B[bq].w * w1[7];
            t0 += C4[bq].x * w0[8] + C4[bq].y * w0[9] + C4[bq].z * w0[10] + C4[bq].w * w0[11];
            t1 += C4[bq].x * w1[8] + C4[bq].y * w1[9] + C4[bq].z * w1[10] + C4[bq].w * w1[11];
            acc0 += fmaxf(xs0[bq] + t0, 0.f);
            acc1 += fmaxf(xs1[bq] + t1, 0.f);
        }
    }
    for (; p < end; ++p) {
        int eid = rfl(csr_eid[p]);
        int src = rfl(csr_src[p]);
        int cat = rfl(ecat[eid]);
        const float4* ec4 = (const float4*)(econt + (size_t)eid * 12);
        float4 A = ec4[0], B = ec4[1], C4 = ec4[2];
        float t0 = sel4(cat, tb0[0], tb0[1], tb0[2], tb0[3]);
        float t1 = sel4(cat, tb1[0], tb1[1], tb1[2], tb1[3]);
        t0 += A.x * w0[0] + A.y * w0[1] + A.z * w0[2] + A.w * w0[3];
        t1 += A.x * w1[0] + A.y * w1[1] + A.z * w1[2] + A.w * w1[3];
        t0 += B.x * w0[4] + B.y * w0[5] + B.z * w0[6] + B.w * w0[7];
        t1 += B.x * w1[4] + B.y * w1[5] + B.z * w1[6] + B.w * w1[7];
        t0 += C4.x * w0[8] + C4.y * w0[9] + C4.z * w0[10] + C4.w * w0[11];
        t1 += C4.x * w1[8] + C4.y * w1[9] + C4.z * w1[10] + C4.w * w1[11];
        const float* hs = h1 + (size_t)src * C_HID;
        acc0 += fmaxf(hs[c0] + t0, 0.f);
        acc1 += fmaxf(hs[c1] + t1, 0.f);
    }
    agg[(size_t)i * C_HID + c0] = acc0;
    agg[(size_t)i * C_HID + c1] = acc1;
}

// ===== GINE2 node MLP + BN, tiled: 32 nodes/block, W staged in halves =====
__global__ __launch_bounds__(256) void k_gine2_node(
        const float* __restrict__ h1, const float* __restrict__ agg,
        const float* __restrict__ eps_p,
        const float* __restrict__ W,   // [128,128]
        const float* __restrict__ b, const float* __restrict__ g,
        const float* __restrict__ bb, const float* __restrict__ m,
        const float* __restrict__ v, float* __restrict__ h2) {
    __shared__ float sW[64 * C_HID];          // 32 KB (half of W)
    __shared__ float sz[DT_NT * C_HID];       // 16 KB
    int tid = threadIdx.x;
    int node0 = blockIdx.x * DT_NT;
    float eps = eps_p[0];
    {
        int nmax = min(DT_NT, N_NODES - node0);
        int tot = nmax * C_HID / 4;
        const float4* hv = (const float4*)(h1 + (size_t)node0 * C_HID);
        const float4* av = (const float4*)(agg + (size_t)node0 * C_HID);
        float4* szv = (float4*)sz;
        float s = 1.f + eps;
        for (int t = tid; t < tot; t += 256) {
            float4 a = hv[t], c = av[t];
            float4 r;
            r.x = s * a.x + c.x; r.y = s * a.y + c.y;
            r.z = s * a.z + c.z; r.w = s * a.w + c.w;
            szv[t] = r;
        }
    }
    int cg = tid & 31, c0 = cg * 4;
    int n0 = (tid >> 5) * 4;
    float4 bi = *(const float4*)&b[c0];
    float acc[4][4];
#pragma unroll
    for (int n = 0; n < 4; n++) {
        acc[n][0] = bi.x; acc[n][1] = bi.y; acc[n][2] = bi.z; acc[n][3] = bi.w;
    }
    for (int half = 0; half < 2; half++) {
        __syncthreads();
        {
            const float4* Wv = (const float4*)(W + half * 64 * C_HID);
            float4* sWv = (float4*)sW;
            for (int t = tid; t < 64 * C_HID / 4; t += 256) sWv[t] = Wv[t];
        }
        __syncthreads();
        int jbase = half * 64;
        for (int jb = 0; jb < 64; jb += 4) {
            float4 w0 = *(const float4*)&sW[(jb + 0) * C_HID + c0];
            float4 w1 = *(const float4*)&sW[(jb + 1) * C_HID + c0];
            float4 w2 = *(const float4*)&sW[(jb + 2) * C_HID + c0];
            float4 w3 = *(const float4*)&sW[(jb + 3) * C_HID + c0];
#pragma unroll
            for (int n = 0; n < 4; n++) {
                float4 zz = *(const float4*)&sz[(n0 + n) * C_HID + jbase + jb];
                acc[n][0] += zz.x * w0.x + zz.y * w1.x + zz.z * w2.x + zz.w * w3.x;
                acc[n][1] += zz.x * w0.y + zz.y * w1.y + zz.z * w2.y + zz.w * w3.y;
                acc[n][2] += zz.x * w0.z + zz.y * w1.z + zz.z * w2.z + zz.w * w3.z;
                acc[n][3] += zz.x * w0.w + zz.y * w1.w + zz.z * w2.w + zz.w * w3.w;
            }
        }
    }
    float4 gg = *(const float4*)&g[c0];
    float4 mm = *(const float4*)&m[c0];
    float4 vv = *(const float4*)&v[c0];
    float4 bbv = *(const float4*)&bb[c0];
    float4 sc;
    sc.x = gg.x * rsqrtf(vv.x + BN_EPS); sc.y = gg.y * rsqrtf(vv.y + BN_EPS);
    sc.z = gg.z * rsqrtf(vv.z + BN_EPS); sc.w = gg.w * rsqrtf(vv.w + BN_EPS);
#pragma unroll
    for (int n = 0; n < 4; n++) {
        int i = node0 + n0 + n;
        if (i < N_NODES) {
            float4 o;
            o.x = (fmaxf(acc[n][0], 0.f) - mm.x) * sc.x + bbv.x;
            o.y = (fmaxf(acc[n][1], 0.f) - mm.y) * sc.y + bbv.y;
            o.z = (fmaxf(acc[n][2], 0.f) - mm.z) * sc.z + bbv.z;
            o.w = (fmaxf(acc[n][3], 0.f) - mm.w) * sc.w + bbv.w;
            *(float4*)&h2[(size_t)i * C_HID + c0] = o;
        }
    }
}

// ===== mean edge feature: wide grid, float4 loads, category counts =====
__global__ void k_ea_sum(const int* __restrict__ ecat,
                         const float* __restrict__ econt,
                         float* __restrict__ ea_sum) {   // [0..11] cont, [12..15] counts
    float p[12];
#pragma unroll
    for (int k = 0; k < 12; k++) p[k] = 0.f;
    float cnt[4] = {0.f, 0.f, 0.f, 0.f};
    int stride = gridDim.x * blockDim.x;
    for (int e = blockIdx.x * blockDim.x + threadIdx.x; e < N_EDGES; e += stride) {
        int c = ecat[e];
        cnt[0] += (c == 0) ? 1.f : 0.f;
        cnt[1] += (c == 1) ? 1.f : 0.f;
        cnt[2] += (c == 2) ? 1.f : 0.f;
        cnt[3] += (c == 3) ? 1.f : 0.f;
        const float4* v4 = (const float4*)(econt + (size_t)e * 12);
        float4 a = v4[0], bq = v4[1], d = v4[2];
        p[0] += a.x;  p[1] += a.y;  p[2] += a.z;  p[3] += a.w;
        p[4] += bq.x; p[5] += bq.y; p[6] += bq.z; p[7] += bq.w;
        p[8] += d.x;  p[9] += d.y;  p[10] += d.z; p[11] += d.w;
    }
    float vals[16];
#pragma unroll
    for (int k = 0; k < 12; k++) vals[k] = p[k];
#pragma unroll
    for (int k = 0; k < 4; k++) vals[12 + k] = cnt[k];
#pragma unroll
    for (int k = 0; k < 16; k++) {
        float v = vals[k];
#pragma unroll
        for (int off = 32; off > 0; off >>= 1) v += __shfl_xor(v, off);
        vals[k] = v;
    }
    __shared__ float red[4][16];
    int wid = threadIdx.x >> 6, lane = threadIdx.x & 63;
    if (lane == 0) {
#pragma unroll
        for (int k = 0; k < 16; k++) red[wid][k] = vals[k];
    }
    __syncthreads();
    if (threadIdx.x < 16) {
        float s = red[0][threadIdx.x] + red[1][threadIdx.x] +
                  red[2][threadIdx.x] + red[3][threadIdx.x];
        atomicAdd(ea_sum + threadIdx.x, s);
    }
}

__global__ void k_loop_prep(const float* __restrict__ ea_sum,
                            const float* __restrict__ edge_emb,
                            const float* __restrict__ We,
                            float* __restrict__ ee_loop) {
    int c = threadIdx.x;
    const float inv = 1.f / (float)N_EDGES;
    float acc = 0.f;
#pragma unroll
    for (int k = 0; k < 4; k++) {
        float s = 0.f;
#pragma unroll
        for (int q = 0; q < 4; q++) s += ea_sum[12 + q] * edge_emb[q * 4 + k];
        acc += (s * inv) * We[k * C_HID + c];
    }
#pragma unroll
    for (int k = 0; k < 12; k++)
        acc += (ea_sum[k] * inv) * We[(4 + k) * C_HID + c];
    ee_loop[c] = acc;
}

// ===== GAT node transforms xl/xr, tiled: 32 nodes/block, W in halves =====
__global__ __launch_bounds__(256) void k_gat0(
        const float* __restrict__ h2,
        const float* __restrict__ Wl, const float* __restrict__ bl,
        const float* __restrict__ Wr, const float* __restrict__ br,
        float* __restrict__ xl, float* __restrict__ xr) {
    __shared__ float sW[64 * C_HID];          // 32 KB
    __shared__ float sz[DT_NT * C_HID];       // 16 KB
    int tid = threadIdx.x;
    int node0 = blockIdx.x * DT_NT;
    {
        int nmax = min(DT_NT, N_NODES - node0);
        int tot = nmax * C_HID / 4;
        const float4* hv = (const float4*)(h2 + (size_t)node0 * C_HID);
        float4* szv = (float4*)sz;
        for (int t = tid; t < tot; t += 256) szv[t] = hv[t];
    }
    int cg = tid & 31, c0 = cg * 4;
    int n0 = (tid >> 5) * 4;
    for (int wsel = 0; wsel < 2; wsel++) {
        const float* Wm = wsel ? Wr : Wl;
        const float* bm = wsel ? br : bl;
        float4 bi = *(const float4*)&bm[c0];
        float acc[4][4];
#pragma unroll
        for (int n = 0; n < 4; n++) {
            acc[n][0] = bi.x; acc[n][1] = bi.y; acc[n][2] = bi.z; acc[n][3] = bi.w;
        }
        for (int half = 0; half < 2; half++) {
            __syncthreads();
            {
                const float4* Wv = (const float4*)(Wm + half * 64 * C_HID);
                float4* sWv = (float4*)sW;
                for (int t = tid; t < 64 * C_HID / 4; t += 256) sWv[t] = Wv[t];
            }
            __syncthreads();
            int jbase = half * 64;
            for (int jb = 0; jb < 64; jb += 4) {
                float4 w0 = *(const float4*)&sW[(jb + 0) * C_HID + c0];
                float4 w1 = *(const float4*)&sW[(jb + 1) * C_HID + c0];
                float4 w2 = *(const float4*)&sW[(jb + 2) * C_HID + c0];
                float4 w3 = *(const float4*)&sW[(jb + 3) * C_HID + c0];
#pragma unroll
                for (int n = 0; n < 4; n++) {
                    float4 zz = *(const float4*)&sz[(n0 + n) * C_HID + jbase + jb];
                    acc[n][0] += zz.x * w0.x + zz.y * w1.x + zz.z * w2.x + zz.w * w3.x;
                    acc[n][1] += zz.x * w0.y + zz.y * w1.y + zz.z * w2.y + zz.w * w3.y;
                    acc[n][2] += zz.x * w0.z + zz.y * w1.z + zz.z * w2.z + zz.w * w3.z;
                    acc[n][3] += zz.x * w0.w + zz.y * w1.w + zz.z * w2.w + zz.w * w3.w;
                }
            }
        }
        float* dst = wsel ? xr : xl;
#pragma unroll
        for (int n = 0; n < 4; n++) {
            int i = node0 + n0 + n;
            if (i < N_NODES) {
                float4 o;
                o.x = acc[n][0]; o.y = acc[n][1]; o.z = acc[n][2]; o.w = acc[n][3];
                *(float4*)&dst[(size_t)i * C_HID + c0] = o;
            }
        }
    }
}

// ===== GAT fused: scalar metadata, 4-edge batch, batched online softmax =====
__global__ void k_gat_fused(const int* __restrict__ rowp,
                            const int* __restrict__ csr_eid,
                            const int* __restrict__ csr_src,
                            const int* __restrict__ ecat,
                            const float* __restrict__ econt,
                            const float* __restrict__ edge_emb,
                            const float* __restrict__ We,    // [16,128]
                            const float* __restrict__ att,   // [128]
                            const float* __restrict__ ee_loop,
                            const float* __restrict__ xl,
                            const float* __restrict__ xr,
                            const float* __restrict__ bias,  // [64]
                            float* __restrict__ out) {
    int i = blockIdx.x * 4 + (threadIdx.x >> 6);
    int lane = threadIdx.x & 63;
    if (i >= N_NODES) return;
    int c0 = lane, c1 = lane + 64;
    float w0[12], w1[12];
#pragma unroll
    for (int k = 0; k < 12; k++) {
        w0[k] = We[(4 + k) * C_HID + c0];
        w1[k] = We[(4 + k) * C_HID + c1];
    }
    float tb0[4], tb1[4];
#pragma unroll
    for (int q = 0; q < 4; q++) {
        float v0 = 0.f, v1 = 0.f;
#pragma unroll
        for (int k = 0; k < 4; k++) {
            float ev = edge_emb[q * 4 + k];
            v0 += ev * We[k * C_HID + c0];
            v1 += ev * We[k * C_HID + c1];
        }
        tb0[q] = v0; tb1[q] = v1;
    }
    float at0 = att[c0], at1 = att[c1];
    float lp0 = ee_loop[c0], lp1 = ee_loop[c1];

    float xr0 = xr[(size_t)i * C_HID + c0];
    float xr1 = xr[(size_t)i * C_HID + c1];
    float xld0 = xl[(size_t)i * C_HID + c0];
    float xld1 = xl[(size_t)i * C_HID + c1];

    float m0 = xld0 + xr0 + lp0; m0 = (m0 > 0.f) ? m0 : 0.2f * m0;
    float m1 = xld1 + xr1 + lp1; m1 = (m1 > 0.f) ? m1 : 0.2f * m1;
    float v0 = m0 * at0;
    float v1 = m1 * at1;
#pragma unroll
    for (int off = 32; off > 0; off >>= 1) {
        v0 += __shfl_xor(v0, off);
        v1 += __shfl_xor(v1, off);
    }
    float rm0 = v0, rm1 = v1;
    float den0 = 1.f, den1 = 1.f;
    float acc0 = xld0, acc1 = xld1;

    int beg = rfl(rowp[i]), end = rfl(rowp[i + 1]);
    int p = beg;
    for (; p + 4 <= end; p += 4) {
        int eid[4], src[4], cat[4];
        float4 A[4], B[4], C4[4];
        float xs0[4], xs1[4];
#pragma unroll
        for (int bq = 0; bq < 4; bq++) {
            eid[bq] = rfl(csr_eid[p + bq]);
            src[bq] = rfl(csr_src[p + bq]);
            cat[bq] = rfl(ecat[eid[bq]]);
            const float4* ec4 = (const float4*)(econt + (size_t)eid[bq] * 12);
            A[bq] = ec4[0]; B[bq] = ec4[1]; C4[bq] = ec4[2];
            const float* xls = xl + (size_t)src[bq] * C_HID;
            xs0[bq] = xls[c0]; xs1[bq] = xls[c1];
        }
        float d0[4], d1[4];
#pragma unroll
        for (int bq = 0; bq < 4; bq++) {
            float e0 = sel4(cat[bq], tb0[0], tb0[1], tb0[2], tb0[3]);
            float e1 = sel4(cat[bq], tb1[0], tb1[1], tb1[2], tb1[3]);
            e0 += A[bq].x * w0[0] + A[bq].y * w0[1] + A[bq].z * w0[2] + A[bq].w * w0[3];
            e1 += A[bq].x * w1[0] + A[bq].y * w1[1] + A[bq].z * w1[2] + A[bq].w * w1[3];
            e0 += B[bq].x * w0[4] + B[bq].y * w0[5] + B[bq].z * w0[6] + B[bq].w * w0[7];
            e1 += B[bq].x * w1[4] + B[bq].y * w1[5] + B[bq].z * w1[6] + B[bq].w * w1[7];
            e0 += C4[bq].x * w0[8] + C4[bq].y * w0[9] + C4[bq].z * w0[10] + C4[bq].w * w0[11];
            e1 += C4[bq].x * w1[8] + C4[bq].y * w1[9] + C4[bq].z * w1[10] + C4[bq].w * w1[11];
            float z0 = xs0[bq] + xr0 + e0; z0 = (z0 > 0.f) ? z0 : 0.2f * z0;
            float z1 = xs1[bq] + xr1 + e1; z1 = (z1 > 0.f) ? z1 : 0.2f * z1;
            d0[bq] = z0 * at0;
            d1[bq] = z1 * at1;
        }
#pragma unroll
        for (int off = 32; off > 0; off >>= 1) {
#pragma unroll
            for (int bq = 0; bq < 4; bq++) {
                d0[bq] += __shfl_xor(d0[bq], off);
                d1[bq] += __shfl_xor(d1[bq], off);
            }
        }
        {
            float bm = fmaxf(fmaxf(d0[0], d0[1]), fmaxf(d0[2], d0[3]));
            float nm = fmaxf(rm0, bm);
            float r = __expf(rm0 - nm);
            float p0 = __expf(d0[0] - nm), p1 = __expf(d0[1] - nm);
            float p2 = __expf(d0[2] - nm), p3 = __expf(d0[3] - nm);
            den0 = den0 * r + ((p0 + p1) + (p2 + p3));
            acc0 = acc0 * r + (p0 * xs0[0] + p1 * xs0[1] + p2 * xs0[2] + p3 * xs0[3]);
            rm0 = nm;
        }
        {
            float bm = fmaxf(fmaxf(d1[0], d1[1]), fmaxf(d1[2], d1[3]));
            float nm = fmaxf(rm1, bm);
            float r = __expf(rm1 - nm);
            float p0 = __expf(d1[0] - nm), p1 = __expf(d1[1] - nm);
            float p2 = __expf(d1[2] - nm), p3 = __expf(d1[3] - nm);
            den1 = den1 * r + ((p0 + p1) + (p2 + p3));
            acc1 = acc1 * r + (p0 * xs1[0] + p1 * xs1[1] + p2 * xs1[2] + p3 * xs1[3]);
            rm1 = nm;
        }
    }
    for (; p < end; ++p) {
        int eid = rfl(csr_eid[p]);
        int src = rfl(csr_src[p]);
        int cat = rfl(ecat[eid]);
        const float4* ec4 = (const float4*)(econt + (size_t)eid * 12);
        float4 A = ec4[0], B = ec4[1], C4 = ec4[2];
        float e0 = sel4(cat, tb0[0], tb0[1], tb0[2], tb0[3]);
        float e1 = sel4(cat, tb1[0], tb1[1], tb1[2], tb1[3]);
        e0 += A.x * w0[0] + A.y * w0[1] + A.z * w0[2] + A.w * w0[3];
        e1 += A.x * w1[0] + A.y * w1[1] + A.z * w1[2] + A.w * w1[3];
        e0 += B.x * w0[4] + B.y * w0[5] + B.z * w0[6] + B.w * w0[7];
        e1 += B.x * w1[4] + B.y * w1[5] + B.z * w1[6] + B.w * w1[7];
        e0 += C4.x * w0[8] + C4.y * w0[9] + C4.z * w0[10] + C4.w * w0[11];
        e1 += C4.x * w1[8] + C4.y * w1[9] + C4.z * w1[10] + C4.w * w1[11];
        const float* xls = xl + (size_t)src * C_HID;
        float xs0 = xls[c0], xs1 = xls[c1];
        float z0 = xs0 + xr0 + e0; z0 = (z0 > 0.f) ? z0 : 0.2f * z0;
        float z1 = xs1 + xr1 + e1; z1 = (z1 > 0.f) ? z1 : 0.2f * z1;
        float a0 = z0 * at0;
        float a1 = z1 * at1;
#pragma unroll
        for (int off = 32; off > 0; off >>= 1) {
            a0 += __shfl_xor(a0, off);
            a1 += __shfl_xor(a1, off);
        }
        float nm0 = fmaxf(rm0, a0);
        float so0 = __expf(rm0 - nm0);
        float sn0 = __expf(a0 - nm0);
        den0 = den0 * so0 + sn0;
        acc0 = acc0 * so0 + sn0 * xs0;
        rm0 = nm0;
        float nm1 = fmaxf(rm1, a1);
        float so1 = __expf(rm1 - nm1);
        float sn1 = __expf(a1 - nm1);
        den1 = den1 * so1 + sn1;
        acc1 = acc1 * so1 + sn1 * xs1;
        rm1 = nm1;
    }
    out[(size_t)i * C_OUT + lane] = 0.5f * (acc0 / den0 + acc1 / den1) + bias[lane];
}

extern "C" void kernel_launch(void* const* d_in, const int* in_sizes, int n_in,
                              void* d_out, int out_size, void* d_ws, size_t ws_size,
                              hipStream_t stream) {
    const int*   x_cat    = (const int*)d_in[0];
    const float* x_cont   = (const float*)d_in[1];
    const int*   e_cat    = (const int*)d_in[2];
    const float* e_cont   = (const float*)d_in[3];
    const int*   ei       = (const int*)d_in[4];
    const float* node_emb = (const float*)d_in[5];
    const float* edge_emb = (const float*)d_in[6];
    const float* eps1     = (const float*)d_in[7];
    const float* W1e      = (const float*)d_in[8];
    const float* b1e      = (const float*)d_in[9];
    const float* W1n      = (const float*)d_in[10];
    const float* b1n      = (const float*)d_in[11];
    const float* g1       = (const float*)d_in[12];
    const float* bb1      = (const float*)d_in[13];
    const float* m1       = (const float*)d_in[14];
    const float* v1       = (const float*)d_in[15];
    const float* eps2     = (const float*)d_in[16];
    const float* W2e      = (const float*)d_in[17];
    const float* b2e      = (const float*)d_in[18];
    const float* W2n      = (const float*)d_in[19];
    const float* b2n      = (const float*)d_in[20];
    const float* g2       = (const float*)d_in[21];
    const float* bb2      = (const float*)d_in[22];
    const float* m2       = (const float*)d_in[23];
    const float* v2       = (const float*)d_in[24];
    const float* Wl       = (const float*)d_in[25];
    const float* bl       = (const float*)d_in[26];
    const float* Wr       = (const float*)d_in[27];
    const float* br       = (const float*)d_in[28];
    const float* Weg      = (const float*)d_in[29];
    const float* att      = (const float*)d_in[30];
    const float* gbias    = (const float*)d_in[31];

    const size_t NF36  = (size_t)N_NODES * NODE_IN;
    const size_t NF128 = (size_t)N_NODES * C_HID;

    float* ws = (float*)d_ws;
    float* x      = ws;               // N*36
    float* f1     = x + NF36;         // N*128 : h1, then xl
    float* f2     = f1 + NF128;       // N*128 : h2
    float* f3     = f2 + NF128;       // N*128 : agg36 / agg128 / xr
    float* ea_sum  = f3 + NF128;      // 16
    float* ee_loop = ea_sum + 16;     // 128
    int* ipool   = (int*)(ee_loop + C_HID);
    int* deg     = ipool;                    // N
    int* cursor  = deg + N_NODES;            // N
    int* rowp    = cursor + N_NODES;         // N+1
    int* csr_eid = rowp + N_NODES + 1;       // E
    int* csr_src = csr_eid + N_EDGES;        // E

    float* h1 = f1;  float* xl = f1;
    float* h2 = f2;
    float* agg36 = f3; float* agg128 = f3; float* xr = f3;

    size_t need = (size_t)((char*)(csr_src + N_EDGES) - (char*)d_ws);
    if (ws_size < need) return;

    hipMemsetAsync(deg, 0, N_NODES * sizeof(int), stream);
    hipMemsetAsync(ea_sum, 0, 16 * sizeof(float), stream);

    const int EB = (N_EDGES + 255) / 256;
    const int NB4 = (N_NODES + 3) / 4;
    const int NBD = (N_NODES + DT_NT - 1) / DT_NT;

    k_node_feat<<<(N_NODES * NODE_IN + 255) / 256, 256, 0, stream>>>(
        x_cat, x_cont, node_emb, x);
    k_deg<<<EB, 256, 0, stream>>>(ei, deg);
    k_scan<<<1, SCAN_T, 0, stream>>>(deg, rowp, cursor);
    k_fill<<<EB, 256, 0, stream>>>(ei, cursor, csr_eid, csr_src);

    k_gine1_gather<<<NB4, 256, 0, stream>>>(
        rowp, csr_eid, csr_src, e_cat, e_cont, edge_emb, W1e, b1e, x, agg36);
    k_gine1_node<<<NBD, 256, 0, stream>>>(
        x, agg36, eps1, W1n, b1n, g1, bb1, m1, v1, h1);
    k_gine2_gather<<<NB4, 256, 0, stream>>>(
        rowp, csr_eid, csr_src, e_cat, e_cont, edge_emb, W2e, b2e, h1, agg128);
    k_gine2_node<<<NBD, 256, 0, stream>>>(
        h1, agg128, eps2, W2n, b2n, g2, bb2, m2, v2, h2);

    k_ea_sum<<<512, 256, 0, stream>>>(e_cat, e_cont, ea_sum);
    k_loop_prep<<<1, C_HID, 0, stream>>>(ea_sum, edge_emb, Weg, ee_loop);

    k_gat0<<<NBD, 256, 0, stream>>>(h2, Wl, bl, Wr, br, xl, xr);
    k_gat_fused<<<NB4, 256, 0, stream>>>(
        rowp, csr_eid, csr_src, e_cat, e_cont, edge_emb, Weg, att, ee_loop,
        xl, xr, gbias, (float*)d_out);
}

// Round 5
// 840.322 us; speedup vs baseline: 14.3812x; 1.1678x over previous
//
#include <hip/hip_runtime.h>
#include <math.h>

#define N_NODES 50000
#define N_EDGES 800000
#define NODE_IN 36
#define EDGE_IN 16
#define C_HID 128
#define C_OUT 64
#define BN_EPS 1e-5f
#define SCAN_T 1024
#define CHUNK ((N_NODES + SCAN_T - 1) / SCAN_T)   // 49
#define DT_NT 32    // nodes per block in dense tiled kernels

__device__ __forceinline__ int rfl(int v) { return __builtin_amdgcn_readfirstlane(v); }

// select one of 4 per-lane register values by (wave-uniform) cat
__device__ __forceinline__ float sel4(int cat, float a, float b, float c, float d) {
    float r = (cat == 0) ? a : b;
    r = (cat == 2) ? c : r;
    r = (cat == 3) ? d : r;
    return r;
}

// ================= node features =================
__global__ void k_node_feat(const int* __restrict__ xcat,
                            const float* __restrict__ xcont,
                            const float* __restrict__ node_emb,
                            float* __restrict__ x) {
    int idx = blockIdx.x * blockDim.x + threadIdx.x;
    if (idx >= N_NODES * NODE_IN) return;
    int i = idx / NODE_IN;
    int j = idx - i * NODE_IN;
    float v;
    if (j < 20) v = node_emb[xcat[i] * 20 + j];
    else        v = xcont[i * 16 + (j - 20)];
    x[idx] = v;
}

// ================= CSR build =================
__global__ void k_deg(const int* __restrict__ ei, int* __restrict__ deg) {
    int e = blockIdx.x * blockDim.x + threadIdx.x;
    if (e >= N_EDGES) return;
    atomicAdd(deg + ei[N_EDGES + e], 1);
}

__global__ void k_scan(const int* __restrict__ deg, int* __restrict__ rowp,
                       int* __restrict__ cursor) {
    __shared__ int sums[SCAN_T];
    int t = threadIdx.x;
    int lo = t * CHUNK, hi = min(lo + CHUNK, N_NODES);
    int s = 0;
    for (int i = lo; i < hi; i++) s += deg[i];
    sums[t] = s;
    __syncthreads();
    for (int off = 1; off < SCAN_T; off <<= 1) {
        int v = 0;
        if (t >= off) v = sums[t - off];
        __syncthreads();
        if (t >= off) sums[t] += v;
        __syncthreads();
    }
    int run = sums[t] - s;      // exclusive prefix
    for (int i = lo; i < hi; i++) {
        rowp[i] = run;
        cursor[i] = run;
        run += deg[i];
    }
    if (t == SCAN_T - 1) rowp[N_NODES] = sums[SCAN_T - 1];
}

__global__ void k_fill(const int* __restrict__ ei, int* __restrict__ cursor,
                       int* __restrict__ csr_eid, int* __restrict__ csr_src) {
    int e = blockIdx.x * blockDim.x + threadIdx.x;
    if (e >= N_EDGES) return;
    int d = ei[N_EDGES + e];
    int pos = atomicAdd(cursor + d, 1);
    csr_eid[pos] = e;
    csr_src[pos] = ei[e];
}

// ======== GINE1 gather (F=36), scalar metadata + 4-edge batching ========
__global__ void k_gine1_gather(const int* __restrict__ rowp,
                               const int* __restrict__ csr_eid,
                               const int* __restrict__ csr_src,
                               const int* __restrict__ ecat,
                               const float* __restrict__ econt,
                               const float* __restrict__ edge_emb,
                               const float* __restrict__ W,   // [16,36]
                               const float* __restrict__ b,   // [36]
                               const float* __restrict__ x,
                               float* __restrict__ agg) {
    int i = blockIdx.x * 4 + (threadIdx.x >> 6);
    int lane = threadIdx.x & 63;
    if (i >= N_NODES) return;
    int c = (lane < NODE_IN) ? lane : (NODE_IN - 1);
    float w[12];
#pragma unroll
    for (int k = 0; k < 12; k++) w[k] = W[(4 + k) * NODE_IN + c];
    float tb[4];
#pragma unroll
    for (int q = 0; q < 4; q++) {
        float v = b[c];
#pragma unroll
        for (int k = 0; k < 4; k++) v += edge_emb[q * 4 + k] * W[k * NODE_IN + c];
        tb[q] = v;
    }
    int beg = rfl(rowp[i]), end = rfl(rowp[i + 1]);
    float acc = 0.f;
    int p = beg;
    for (; p + 4 <= end; p += 4) {
        int eid[4], src[4], cat[4];
        float4 A[4], B[4], C4[4];
        float xs[4];
#pragma unroll
        for (int bq = 0; bq < 4; bq++) {
            eid[bq] = rfl(csr_eid[p + bq]);
            src[bq] = rfl(csr_src[p + bq]);
            cat[bq] = rfl(ecat[eid[bq]]);
            const float4* ec4 = (const float4*)(econt + (size_t)eid[bq] * 12);
            A[bq] = ec4[0]; B[bq] = ec4[1]; C4[bq] = ec4[2];
            xs[bq] = x[(size_t)src[bq] * NODE_IN + c];
        }
#pragma unroll
        for (int bq = 0; bq < 4; bq++) {
            float t = sel4(cat[bq], tb[0], tb[1], tb[2], tb[3]);
            t += A[bq].x * w[0] + A[bq].y * w[1] + A[bq].z * w[2] + A[bq].w * w[3];
            t += B[bq].x * w[4] + B[bq].y * w[5] + B[bq].z * w[6] + B[bq].w * w[7];
            t += C4[bq].x * w[8] + C4[bq].y * w[9] + C4[bq].z * w[10] + C4[bq].w * w[11];
            acc += fmaxf(xs[bq] + t, 0.f);
        }
    }
    for (; p < end; ++p) {
        int eid = rfl(csr_eid[p]);
        int src = rfl(csr_src[p]);
        int cat = rfl(ecat[eid]);
        const float4* ec4 = (const float4*)(econt + (size_t)eid * 12);
        float4 A = ec4[0], B = ec4[1], C4 = ec4[2];
        float t = sel4(cat, tb[0], tb[1], tb[2], tb[3]);
        t += A.x * w[0] + A.y * w[1] + A.z * w[2] + A.w * w[3];
        t += B.x * w[4] + B.y * w[5] + B.z * w[6] + B.w * w[7];
        t += C4.x * w[8] + C4.y * w[9] + C4.z * w[10] + C4.w * w[11];
        acc += fmaxf(x[(size_t)src * NODE_IN + c] + t, 0.f);
    }
    if (lane < NODE_IN) agg[(size_t)i * NODE_IN + lane] = acc;
}

// ===== GINE1 node MLP + BN, tiled: 32 nodes/block, 4x4 register block =====
__global__ __launch_bounds__(256, 4) void k_gine1_node(
        const float* __restrict__ x, const float* __restrict__ agg,
        const float* __restrict__ eps_p,
        const float* __restrict__ W,   // [36,128]
        const float* __restrict__ b, const float* __restrict__ g,
        const float* __restrict__ bb, const float* __restrict__ m,
        const float* __restrict__ v, float* __restrict__ h) {
    __shared__ float sW[NODE_IN * C_HID];     // 18 KB
    __shared__ float sz[DT_NT * NODE_IN];     // 4.5 KB
    int tid = threadIdx.x;
    int node0 = blockIdx.x * DT_NT;
    float eps = eps_p[0];
    {
        const float4* Wv = (const float4*)W;
        float4* sWv = (float4*)sW;
        for (int t = tid; t < NODE_IN * C_HID / 4; t += 256) sWv[t] = Wv[t];
    }
    {
        int nmax = min(DT_NT, N_NODES - node0);
        int tot = nmax * NODE_IN / 4;
        const float4* xv = (const float4*)(x + (size_t)node0 * NODE_IN);
        const float4* av = (const float4*)(agg + (size_t)node0 * NODE_IN);
        float4* szv = (float4*)sz;
        float s = 1.f + eps;
        for (int t = tid; t < tot; t += 256) {
            float4 a = xv[t], c = av[t];
            float4 r;
            r.x = s * a.x + c.x; r.y = s * a.y + c.y;
            r.z = s * a.z + c.z; r.w = s * a.w + c.w;
            szv[t] = r;
        }
    }
    __syncthreads();
    int cg = tid & 31, c0 = cg * 4;
    int n0 = (tid >> 5) * 4;
    float4 bi = *(const float4*)&b[c0];
    float acc[4][4];
#pragma unroll
    for (int n = 0; n < 4; n++) {
        acc[n][0] = bi.x; acc[n][1] = bi.y; acc[n][2] = bi.z; acc[n][3] = bi.w;
    }
#pragma unroll 2
    for (int jb = 0; jb < NODE_IN; jb += 4) {
        float4 w0 = *(const float4*)&sW[(jb + 0) * C_HID + c0];
        float4 w1 = *(const float4*)&sW[(jb + 1) * C_HID + c0];
        float4 w2 = *(const float4*)&sW[(jb + 2) * C_HID + c0];
        float4 w3 = *(const float4*)&sW[(jb + 3) * C_HID + c0];
#pragma unroll
        for (int n = 0; n < 4; n++) {
            float4 zz = *(const float4*)&sz[(n0 + n) * NODE_IN + jb];
            acc[n][0] += zz.x * w0.x + zz.y * w1.x + zz.z * w2.x + zz.w * w3.x;
            acc[n][1] += zz.x * w0.y + zz.y * w1.y + zz.z * w2.y + zz.w * w3.y;
            acc[n][2] += zz.x * w0.z + zz.y * w1.z + zz.z * w2.z + zz.w * w3.z;
            acc[n][3] += zz.x * w0.w + zz.y * w1.w + zz.z * w2.w + zz.w * w3.w;
        }
    }
    float4 gg = *(const float4*)&g[c0];
    float4 mm = *(const float4*)&m[c0];
    float4 vv = *(const float4*)&v[c0];
    float4 bbv = *(const float4*)&bb[c0];
    float4 sc;
    sc.x = gg.x * rsqrtf(vv.x + BN_EPS); sc.y = gg.y * rsqrtf(vv.y + BN_EPS);
    sc.z = gg.z * rsqrtf(vv.z + BN_EPS); sc.w = gg.w * rsqrtf(vv.w + BN_EPS);
#pragma unroll
    for (int n = 0; n < 4; n++) {
        int i = node0 + n0 + n;
        if (i < N_NODES) {
            float4 o;
            o.x = (fmaxf(acc[n][0], 0.f) - mm.x) * sc.x + bbv.x;
            o.y = (fmaxf(acc[n][1], 0.f) - mm.y) * sc.y + bbv.y;
            o.z = (fmaxf(acc[n][2], 0.f) - mm.z) * sc.z + bbv.z;
            o.w = (fmaxf(acc[n][3], 0.f) - mm.w) * sc.w + bbv.w;
            *(float4*)&h[(size_t)i * C_HID + c0] = o;
        }
    }
}

// ======== GINE2 gather (F=128), scalar metadata + 4-edge batching ========
__global__ void k_gine2_gather(const int* __restrict__ rowp,
                               const int* __restrict__ csr_eid,
                               const int* __restrict__ csr_src,
                               const int* __restrict__ ecat,
                               const float* __restrict__ econt,
                               const float* __restrict__ edge_emb,
                               const float* __restrict__ W,   // [16,128]
                               const float* __restrict__ b,   // [128]
                               const float* __restrict__ h1,
                               float* __restrict__ agg) {
    int i = blockIdx.x * 4 + (threadIdx.x >> 6);
    int lane = threadIdx.x & 63;
    if (i >= N_NODES) return;
    int c0 = lane, c1 = lane + 64;
    float w0[12], w1[12];
#pragma unroll
    for (int k = 0; k < 12; k++) {
        w0[k] = W[(4 + k) * C_HID + c0];
        w1[k] = W[(4 + k) * C_HID + c1];
    }
    float tb0[4], tb1[4];
#pragma unroll
    for (int q = 0; q < 4; q++) {
        float v0 = b[c0], v1 = b[c1];
#pragma unroll
        for (int k = 0; k < 4; k++) {
            float ev = edge_emb[q * 4 + k];
            v0 += ev * W[k * C_HID + c0];
            v1 += ev * W[k * C_HID + c1];
        }
        tb0[q] = v0; tb1[q] = v1;
    }
    int beg = rfl(rowp[i]), end = rfl(rowp[i + 1]);
    float acc0 = 0.f, acc1 = 0.f;
    int p = beg;
    for (; p + 4 <= end; p += 4) {
        int eid[4], src[4], cat[4];
        float4 A[4], B[4], C4[4];
        float xs0[4], xs1[4];
#pragma unroll
        for (int bq = 0; bq < 4; bq++) {
            eid[bq] = rfl(csr_eid[p + bq]);
            src[bq] = rfl(csr_src[p + bq]);
            cat[bq] = rfl(ecat[eid[bq]]);
            const float4* ec4 = (const float4*)(econt + (size_t)eid[bq] * 12);
            A[bq] = ec4[0]; B[bq] = ec4[1]; C4[bq] = ec4[2];
            const float* hs = h1 + (size_t)src[bq] * C_HID;
            xs0[bq] = hs[c0]; xs1[bq] = hs[c1];
        }
#pragma unroll
        for (int bq = 0; bq < 4; bq++) {
            float t0 = sel4(cat[bq], tb0[0], tb0[1], tb0[2], tb0[3]);
            float t1 = sel4(cat[bq], tb1[0], tb1[1], tb1[2], tb1[3]);
            t0 += A[bq].x * w0[0] + A[bq].y * w0[1] + A[bq].z * w0[2] + A[bq].w * w0[3];
            t1 += A[bq].x * w1[0] + A[bq].y * w1[1] + A[bq].z * w1[2] + A[bq].w * w1[3];
            t0 += B[bq].x * w0[4] + B[bq].y * w0[5] + B[bq].z * w0[6] + B[bq].w * w0[7];
            t1 += B[bq].x * w1[4] + B[bq].y * w1[5] + B[bq].z * w1[6] + B[bq].w * w1[7];
            t0 += C4[bq].x * w0[8] + C4[bq].y * w0[9] + C4[bq].z * w0[10] + C4[bq].w * w0[11];
            t1 += C4[bq].x * w1[8] + C4[bq].y * w1[9] + C4[bq].z * w1[10] + C4[bq].w * w1[11];
            acc0 += fmaxf(xs0[bq] + t0, 0.f);
            acc1 += fmaxf(xs1[bq] + t1, 0.f);
        }
    }
    for (; p < end; ++p) {
        int eid = rfl(csr_eid[p]);
        int src = rfl(csr_src[p]);
        int cat = rfl(ecat[eid]);
        const float4* ec4 = (const float4*)(econt + (size_t)eid * 12);
        float4 A = ec4[0], B = ec4[1], C4 = ec4[2];
        float t0 = sel4(cat, tb0[0], tb0[1], tb0[2], tb0[3]);
        float t1 = sel4(cat, tb1[0], tb1[1], tb1[2], tb1[3]);
        t0 += A.x * w0[0] + A.y * w0[1] + A.z * w0[2] + A.w * w0[3];
        t1 += A.x * w1[0] + A.y * w1[1] + A.z * w1[2] + A.w * w1[3];
        t0 += B.x * w0[4] + B.y * w0[5] + B.z * w0[6] + B.w * w0[7];
        t1 += B.x * w1[4] + B.y * w1[5] + B.z * w1[6] + B.w * w1[7];
        t0 += C4.x * w0[8] + C4.y * w0[9] + C4.z * w0[10] + C4.w * w0[11];
        t1 += C4.x * w1[8] + C4.y * w1[9] + C4.z * w1[10] + C4.w * w1[11];
        const float* hs = h1 + (size_t)src * C_HID;
        acc0 += fmaxf(hs[c0] + t0, 0.f);
        acc1 += fmaxf(hs[c1] + t1, 0.f);
    }
    agg[(size_t)i * C_HID + c0] = acc0;
    agg[(size_t)i * C_HID + c1] = acc1;
}

// ===== GINE2 node MLP + BN, tiled: 32 nodes/block, W staged in halves =====
__global__ __launch_bounds__(256, 4) void k_gine2_node(
        const float* __restrict__ h1, const float* __restrict__ agg,
        const float* __restrict__ eps_p,
        const float* __restrict__ W,   // [128,128]
        const float* __restrict__ b, const float* __restrict__ g,
        const float* __restrict__ bb, const float* __restrict__ m,
        const float* __restrict__ v, float* __restrict__ h2) {
    __shared__ float sW[64 * C_HID];          // 32 KB (half of W)
    __shared__ float sz[DT_NT * C_HID];       // 16 KB
    int tid = threadIdx.x;
    int node0 = blockIdx.x * DT_NT;
    float eps = eps_p[0];
    {
        int nmax = min(DT_NT, N_NODES - node0);
        int tot = nmax * C_HID / 4;
        const float4* hv = (const float4*)(h1 + (size_t)node0 * C_HID);
        const float4* av = (const float4*)(agg + (size_t)node0 * C_HID);
        float4* szv = (float4*)sz;
        float s = 1.f + eps;
        for (int t = tid; t < tot; t += 256) {
            float4 a = hv[t], c = av[t];
            float4 r;
            r.x = s * a.x + c.x; r.y = s * a.y + c.y;
            r.z = s * a.z + c.z; r.w = s * a.w + c.w;
            szv[t] = r;
        }
    }
    int cg = tid & 31, c0 = cg * 4;
    int n0 = (tid >> 5) * 4;
    float4 bi = *(const float4*)&b[c0];
    float acc[4][4];
#pragma unroll
    for (int n = 0; n < 4; n++) {
        acc[n][0] = bi.x; acc[n][1] = bi.y; acc[n][2] = bi.z; acc[n][3] = bi.w;
    }
    for (int half = 0; half < 2; half++) {
        __syncthreads();
        {
            const float4* Wv = (const float4*)(W + half * 64 * C_HID);
            float4* sWv = (float4*)sW;
            for (int t = tid; t < 64 * C_HID / 4; t += 256) sWv[t] = Wv[t];
        }
        __syncthreads();
        int jbase = half * 64;
#pragma unroll 2
        for (int jb = 0; jb < 64; jb += 4) {
            float4 w0 = *(const float4*)&sW[(jb + 0) * C_HID + c0];
            float4 w1 = *(const float4*)&sW[(jb + 1) * C_HID + c0];
            float4 w2 = *(const float4*)&sW[(jb + 2) * C_HID + c0];
            float4 w3 = *(const float4*)&sW[(jb + 3) * C_HID + c0];
#pragma unroll
            for (int n = 0; n < 4; n++) {
                float4 zz = *(const float4*)&sz[(n0 + n) * C_HID + jbase + jb];
                acc[n][0] += zz.x * w0.x + zz.y * w1.x + zz.z * w2.x + zz.w * w3.x;
                acc[n][1] += zz.x * w0.y + zz.y * w1.y + zz.z * w2.y + zz.w * w3.y;
                acc[n][2] += zz.x * w0.z + zz.y * w1.z + zz.z * w2.z + zz.w * w3.z;
                acc[n][3] += zz.x * w0.w + zz.y * w1.w + zz.z * w2.w + zz.w * w3.w;
            }
        }
    }
    float4 gg = *(const float4*)&g[c0];
    float4 mm = *(const float4*)&m[c0];
    float4 vv = *(const float4*)&v[c0];
    float4 bbv = *(const float4*)&bb[c0];
    float4 sc;
    sc.x = gg.x * rsqrtf(vv.x + BN_EPS); sc.y = gg.y * rsqrtf(vv.y + BN_EPS);
    sc.z = gg.z * rsqrtf(vv.z + BN_EPS); sc.w = gg.w * rsqrtf(vv.w + BN_EPS);
#pragma unroll
    for (int n = 0; n < 4; n++) {
        int i = node0 + n0 + n;
        if (i < N_NODES) {
            float4 o;
            o.x = (fmaxf(acc[n][0], 0.f) - mm.x) * sc.x + bbv.x;
            o.y = (fmaxf(acc[n][1], 0.f) - mm.y) * sc.y + bbv.y;
            o.z = (fmaxf(acc[n][2], 0.f) - mm.z) * sc.z + bbv.z;
            o.w = (fmaxf(acc[n][3], 0.f) - mm.w) * sc.w + bbv.w;
            *(float4*)&h2[(size_t)i * C_HID + c0] = o;
        }
    }
}

// ===== mean edge feature: wide grid, float4 loads, category counts =====
__global__ void k_ea_sum(const int* __restrict__ ecat,
                         const float* __restrict__ econt,
                         float* __restrict__ ea_sum) {   // [0..11] cont, [12..15] counts
    float p[12];
#pragma unroll
    for (int k = 0; k < 12; k++) p[k] = 0.f;
    float cnt[4] = {0.f, 0.f, 0.f, 0.f};
    int stride = gridDim.x * blockDim.x;
    for (int e = blockIdx.x * blockDim.x + threadIdx.x; e < N_EDGES; e += stride) {
        int c = ecat[e];
        cnt[0] += (c == 0) ? 1.f : 0.f;
        cnt[1] += (c == 1) ? 1.f : 0.f;
        cnt[2] += (c == 2) ? 1.f : 0.f;
        cnt[3] += (c == 3) ? 1.f : 0.f;
        const float4* v4 = (const float4*)(econt + (size_t)e * 12);
        float4 a = v4[0], bq = v4[1], d = v4[2];
        p[0] += a.x;  p[1] += a.y;  p[2] += a.z;  p[3] += a.w;
        p[4] += bq.x; p[5] += bq.y; p[6] += bq.z; p[7] += bq.w;
        p[8] += d.x;  p[9] += d.y;  p[10] += d.z; p[11] += d.w;
    }
    float vals[16];
#pragma unroll
    for (int k = 0; k < 12; k++) vals[k] = p[k];
#pragma unroll
    for (int k = 0; k < 4; k++) vals[12 + k] = cnt[k];
#pragma unroll
    for (int k = 0; k < 16; k++) {
        float v = vals[k];
#pragma unroll
        for (int off = 32; off > 0; off >>= 1) v += __shfl_xor(v, off);
        vals[k] = v;
    }
    __shared__ float red[4][16];
    int wid = threadIdx.x >> 6, lane = threadIdx.x & 63;
    if (lane == 0) {
#pragma unroll
        for (int k = 0; k < 16; k++) red[wid][k] = vals[k];
    }
    __syncthreads();
    if (threadIdx.x < 16) {
        float s = red[0][threadIdx.x] + red[1][threadIdx.x] +
                  red[2][threadIdx.x] + red[3][threadIdx.x];
        atomicAdd(ea_sum + threadIdx.x, s);
    }
}

__global__ void k_loop_prep(const float* __restrict__ ea_sum,
                            const float* __restrict__ edge_emb,
                            const float* __restrict__ We,
                            float* __restrict__ ee_loop) {
    int c = threadIdx.x;
    const float inv = 1.f / (float)N_EDGES;
    float acc = 0.f;
#pragma unroll
    for (int k = 0; k < 4; k++) {
        float s = 0.f;
#pragma unroll
        for (int q = 0; q < 4; q++) s += ea_sum[12 + q] * edge_emb[q * 4 + k];
        acc += (s * inv) * We[k * C_HID + c];
    }
#pragma unroll
    for (int k = 0; k < 12; k++)
        acc += (ea_sum[k] * inv) * We[(4 + k) * C_HID + c];
    ee_loop[c] = acc;
}

// ===== GAT node transforms xl/xr, tiled: 32 nodes/block, W in halves =====
__global__ __launch_bounds__(256, 4) void k_gat0(
        const float* __restrict__ h2,
        const float* __restrict__ Wl, const float* __restrict__ bl,
        const float* __restrict__ Wr, const float* __restrict__ br,
        float* __restrict__ xl, float* __restrict__ xr) {
    __shared__ float sW[64 * C_HID];          // 32 KB
    __shared__ float sz[DT_NT * C_HID];       // 16 KB
    int tid = threadIdx.x;
    int node0 = blockIdx.x * DT_NT;
    {
        int nmax = min(DT_NT, N_NODES - node0);
        int tot = nmax * C_HID / 4;
        const float4* hv = (const float4*)(h2 + (size_t)node0 * C_HID);
        float4* szv = (float4*)sz;
        for (int t = tid; t < tot; t += 256) szv[t] = hv[t];
    }
    int cg = tid & 31, c0 = cg * 4;
    int n0 = (tid >> 5) * 4;
    for (int wsel = 0; wsel < 2; wsel++) {
        const float* Wm = wsel ? Wr : Wl;
        const float* bm = wsel ? br : bl;
        float4 bi = *(const float4*)&bm[c0];
        float acc[4][4];
#pragma unroll
        for (int n = 0; n < 4; n++) {
            acc[n][0] = bi.x; acc[n][1] = bi.y; acc[n][2] = bi.z; acc[n][3] = bi.w;
        }
        for (int half = 0; half < 2; half++) {
            __syncthreads();
            {
                const float4* Wv = (const float4*)(Wm + half * 64 * C_HID);
                float4* sWv = (float4*)sW;
                for (int t = tid; t < 64 * C_HID / 4; t += 256) sWv[t] = Wv[t];
            }
            __syncthreads();
            int jbase = half * 64;
#pragma unroll 2
            for (int jb = 0; jb < 64; jb += 4) {
                float4 w0 = *(const float4*)&sW[(jb + 0) * C_HID + c0];
                float4 w1 = *(const float4*)&sW[(jb + 1) * C_HID + c0];
                float4 w2 = *(const float4*)&sW[(jb + 2) * C_HID + c0];
                float4 w3 = *(const float4*)&sW[(jb + 3) * C_HID + c0];
#pragma unroll
                for (int n = 0; n < 4; n++) {
                    float4 zz = *(const float4*)&sz[(n0 + n) * C_HID + jbase + jb];
                    acc[n][0] += zz.x * w0.x + zz.y * w1.x + zz.z * w2.x + zz.w * w3.x;
                    acc[n][1] += zz.x * w0.y + zz.y * w1.y + zz.z * w2.y + zz.w * w3.y;
                    acc[n][2] += zz.x * w0.z + zz.y * w1.z + zz.z * w2.z + zz.w * w3.z;
                    acc[n][3] += zz.x * w0.w + zz.y * w1.w + zz.z * w2.w + zz.w * w3.w;
                }
            }
        }
        float* dst = wsel ? xr : xl;
#pragma unroll
        for (int n = 0; n < 4; n++) {
            int i = node0 + n0 + n;
            if (i < N_NODES) {
                float4 o;
                o.x = acc[n][0]; o.y = acc[n][1]; o.z = acc[n][2]; o.w = acc[n][3];
                *(float4*)&dst[(size_t)i * C_HID + c0] = o;
            }
        }
    }
}

// ===== GAT fused: scalar metadata, 4-edge batch, batched online softmax =====
__global__ void k_gat_fused(const int* __restrict__ rowp,
                            const int* __restrict__ csr_eid,
                            const int* __restrict__ csr_src,
                            const int* __restrict__ ecat,
                            const float* __restrict__ econt,
                            const float* __restrict__ edge_emb,
                            const float* __restrict__ We,    // [16,128]
                            const float* __restrict__ att,   // [128]
                            const float* __restrict__ ee_loop,
                            const float* __restrict__ xl,
                            const float* __restrict__ xr,
                            const float* __restrict__ bias,  // [64]
                            float* __restrict__ out) {
    int i = blockIdx.x * 4 + (threadIdx.x >> 6);
    int lane = threadIdx.x & 63;
    if (i >= N_NODES) return;
    int c0 = lane, c1 = lane + 64;
    float w0[12], w1[12];
#pragma unroll
    for (int k = 0; k < 12; k++) {
        w0[k] = We[(4 + k) * C_HID + c0];
        w1[k] = We[(4 + k) * C_HID + c1];
    }
    float tb0[4], tb1[4];
#pragma unroll
    for (int q = 0; q < 4; q++) {
        float v0 = 0.f, v1 = 0.f;
#pragma unroll
        for (int k = 0; k < 4; k++) {
            float ev = edge_emb[q * 4 + k];
            v0 += ev * We[k * C_HID + c0];
            v1 += ev * We[k * C_HID + c1];
        }
        tb0[q] = v0; tb1[q] = v1;
    }
    float at0 = att[c0], at1 = att[c1];
    float lp0 = ee_loop[c0], lp1 = ee_loop[c1];

    float xr0 = xr[(size_t)i * C_HID + c0];
    float xr1 = xr[(size_t)i * C_HID + c1];
    float xld0 = xl[(size_t)i * C_HID + c0];
    float xld1 = xl[(size_t)i * C_HID + c1];

    float m0 = xld0 + xr0 + lp0; m0 = (m0 > 0.f) ? m0 : 0.2f * m0;
    float m1 = xld1 + xr1 + lp1; m1 = (m1 > 0.f) ? m1 : 0.2f * m1;
    float v0 = m0 * at0;
    float v1 = m1 * at1;
#pragma unroll
    for (int off = 32; off > 0; off >>= 1) {
        v0 += __shfl_xor(v0, off);
        v1 += __shfl_xor(v1, off);
    }
    float rm0 = v0, rm1 = v1;
    float den0 = 1.f, den1 = 1.f;
    float acc0 = xld0, acc1 = xld1;

    int beg = rfl(rowp[i]), end = rfl(rowp[i + 1]);
    int p = beg;
    for (; p + 4 <= end; p += 4) {
        int eid[4], src[4], cat[4];
        float4 A[4], B[4], C4[4];
        float xs0[4], xs1[4];
#pragma unroll
        for (int bq = 0; bq < 4; bq++) {
            eid[bq] = rfl(csr_eid[p + bq]);
            src[bq] = rfl(csr_src[p + bq]);
            cat[bq] = rfl(ecat[eid[bq]]);
            const float4* ec4 = (const float4*)(econt + (size_t)eid[bq] * 12);
            A[bq] = ec4[0]; B[bq] = ec4[1]; C4[bq] = ec4[2];
            const float* xls = xl + (size_t)src[bq] * C_HID;
            xs0[bq] = xls[c0]; xs1[bq] = xls[c1];
        }
        float d0[4], d1[4];
#pragma unroll
        for (int bq = 0; bq < 4; bq++) {
            float e0 = sel4(cat[bq], tb0[0], tb0[1], tb0[2], tb0[3]);
            float e1 = sel4(cat[bq], tb1[0], tb1[1], tb1[2], tb1[3]);
            e0 += A[bq].x * w0[0] + A[bq].y * w0[1] + A[bq].z * w0[2] + A[bq].w * w0[3];
            e1 += A[bq].x * w1[0] + A[bq].y * w1[1] + A[bq].z * w1[2] + A[bq].w * w1[3];
            e0 += B[bq].x * w0[4] + B[bq].y * w0[5] + B[bq].z * w0[6] + B[bq].w * w0[7];
            e1 += B[bq].x * w1[4] + B[bq].y * w1[5] + B[bq].z * w1[6] + B[bq].w * w1[7];
            e0 += C4[bq].x * w0[8] + C4[bq].y * w0[9] + C4[bq].z * w0[10] + C4[bq].w * w0[11];
            e1 += C4[bq].x * w1[8] + C4[bq].y * w1[9] + C4[bq].z * w1[10] + C4[bq].w * w1[11];
            float z0 = xs0[bq] + xr0 + e0; z0 = (z0 > 0.f) ? z0 : 0.2f * z0;
            float z1 = xs1[bq] + xr1 + e1; z1 = (z1 > 0.f) ? z1 : 0.2f * z1;
            d0[bq] = z0 * at0;
            d1[bq] = z1 * at1;
        }
#pragma unroll
        for (int off = 32; off > 0; off >>= 1) {
#pragma unroll
            for (int bq = 0; bq < 4; bq++) {
                d0[bq] += __shfl_xor(d0[bq], off);
                d1[bq] += __shfl_xor(d1[bq], off);
            }
        }
        {
            float bm = fmaxf(fmaxf(d0[0], d0[1]), fmaxf(d0[2], d0[3]));
            float nm = fmaxf(rm0, bm);
            float r = __expf(rm0 - nm);
            float p0 = __expf(d0[0] - nm), p1 = __expf(d0[1] - nm);
            float p2 = __expf(d0[2] - nm), p3 = __expf(d0[3] - nm);
            den0 = den0 * r + ((p0 + p1) + (p2 + p3));
            acc0 = acc0 * r + (p0 * xs0[0] + p1 * xs0[1] + p2 * xs0[2] + p3 * xs0[3]);
            rm0 = nm;
        }
        {
            float bm = fmaxf(fmaxf(d1[0], d1[1]), fmaxf(d1[2], d1[3]));
            float nm = fmaxf(rm1, bm);
            float r = __expf(rm1 - nm);
            float p0 = __expf(d1[0] - nm), p1 = __expf(d1[1] - nm);
            float p2 = __expf(d1[2] - nm), p3 = __expf(d1[3] - nm);
            den1 = den1 * r + ((p0 + p1) + (p2 + p3));
            acc1 = acc1 * r + (p0 * xs1[0] + p1 * xs1[1] + p2 * xs1[2] + p3 * xs1[3]);
            rm1 = nm;
        }
    }
    for (; p < end; ++p) {
        int eid = rfl(csr_eid[p]);
        int src = rfl(csr_src[p]);
        int cat = rfl(ecat[eid]);
        const float4* ec4 = (const float4*)(econt + (size_t)eid * 12);
        float4 A = ec4[0], B = ec4[1], C4 = ec4[2];
        float e0 = sel4(cat, tb0[0], tb0[1], tb0[2], tb0[3]);
        float e1 = sel4(cat, tb1[0], tb1[1], tb1[2], tb1[3]);
        e0 += A.x * w0[0] + A.y * w0[1] + A.z * w0[2] + A.w * w0[3];
        e1 += A.x * w1[0] + A.y * w1[1] + A.z * w1[2] + A.w * w1[3];
        e0 += B.x * w0[4] + B.y * w0[5] + B.z * w0[6] + B.w * w0[7];
        e1 += B.x * w1[4] + B.y * w1[5] + B.z * w1[6] + B.w * w1[7];
        e0 += C4.x * w0[8] + C4.y * w0[9] + C4.z * w0[10] + C4.w * w0[11];
        e1 += C4.x * w1[8] + C4.y * w1[9] + C4.z * w1[10] + C4.w * w1[11];
        const float* xls = xl + (size_t)src * C_HID;
        float xs0 = xls[c0], xs1 = xls[c1];
        float z0 = xs0 + xr0 + e0; z0 = (z0 > 0.f) ? z0 : 0.2f * z0;
        float z1 = xs1 + xr1 + e1; z1 = (z1 > 0.f) ? z1 : 0.2f * z1;
        float a0 = z0 * at0;
        float a1 = z1 * at1;
#pragma unroll
        for (int off = 32; off > 0; off >>= 1) {
            a0 += __shfl_xor(a0, off);
            a1 += __shfl_xor(a1, off);
        }
        float nm0 = fmaxf(rm0, a0);
        float so0 = __expf(rm0 - nm0);
        float sn0 = __expf(a0 - nm0);
        den0 = den0 * so0 + sn0;
        acc0 = acc0 * so0 + sn0 * xs0;
        rm0 = nm0;
        float nm1 = fmaxf(rm1, a1);
        float so1 = __expf(rm1 - nm1);
        float sn1 = __expf(a1 - nm1);
        den1 = den1 * so1 + sn1;
        acc1 = acc1 * so1 + sn1 * xs1;
        rm1 = nm1;
    }
    out[(size_t)i * C_OUT + lane] = 0.5f * (acc0 / den0 + acc1 / den1) + bias[lane];
}

extern "C" void kernel_launch(void* const* d_in, const int* in_sizes, int n_in,
                              void* d_out, int out_size, void* d_ws, size_t ws_size,
                              hipStream_t stream) {
    const int*   x_cat    = (const int*)d_in[0];
    const float* x_cont   = (const float*)d_in[1];
    const int*   e_cat    = (const int*)d_in[2];
    const float* e_cont   = (const float*)d_in[3];
    const int*   ei       = (const int*)d_in[4];
    const float* node_emb = (const float*)d_in[5];
    const float* edge_emb = (const float*)d_in[6];
    const float* eps1     = (const float*)d_in[7];
    const float* W1e      = (const float*)d_in[8];
    const float* b1e      = (const float*)d_in[9];
    const float* W1n      = (const float*)d_in[10];
    const float* b1n      = (const float*)d_in[11];
    const float* g1       = (const float*)d_in[12];
    const float* bb1      = (const float*)d_in[13];
    const float* m1       = (const float*)d_in[14];
    const float* v1       = (const float*)d_in[15];
    const float* eps2     = (const float*)d_in[16];
    const float* W2e      = (const float*)d_in[17];
    const float* b2e      = (const float*)d_in[18];
    const float* W2n      = (const float*)d_in[19];
    const float* b2n      = (const float*)d_in[20];
    const float* g2       = (const float*)d_in[21];
    const float* bb2      = (const float*)d_in[22];
    const float* m2       = (const float*)d_in[23];
    const float* v2       = (const float*)d_in[24];
    const float* Wl       = (const float*)d_in[25];
    const float* bl       = (const float*)d_in[26];
    const float* Wr       = (const float*)d_in[27];
    const float* br       = (const float*)d_in[28];
    const float* Weg      = (const float*)d_in[29];
    const float* att      = (const float*)d_in[30];
    const float* gbias    = (const float*)d_in[31];

    const size_t NF36  = (size_t)N_NODES * NODE_IN;
    const size_t NF128 = (size_t)N_NODES * C_HID;

    float* ws = (float*)d_ws;
    float* x      = ws;               // N*36
    float* f1     = x + NF36;         // N*128 : h1, then xl
    float* f2     = f1 + NF128;       // N*128 : h2
    float* f3     = f2 + NF128;       // N*128 : agg36 / agg128 / xr
    float* ea_sum  = f3 + NF128;      // 16
    float* ee_loop = ea_sum + 16;     // 128
    int* ipool   = (int*)(ee_loop + C_HID);
    int* deg     = ipool;                    // N
    int* cursor  = deg + N_NODES;            // N
    int* rowp    = cursor + N_NODES;         // N+1
    int* csr_eid = rowp + N_NODES + 1;       // E
    int* csr_src = csr_eid + N_EDGES;        // E

    float* h1 = f1;  float* xl = f1;
    float* h2 = f2;
    float* agg36 = f3; float* agg128 = f3; float* xr = f3;

    size_t need = (size_t)((char*)(csr_src + N_EDGES) - (char*)d_ws);
    if (ws_size < need) return;

    hipMemsetAsync(deg, 0, N_NODES * sizeof(int), stream);
    hipMemsetAsync(ea_sum, 0, 16 * sizeof(float), stream);

    const int EB = (N_EDGES + 255) / 256;
    const int NB4 = (N_NODES + 3) / 4;
    const int NBD = (N_NODES + DT_NT - 1) / DT_NT;

    k_node_feat<<<(N_NODES * NODE_IN + 255) / 256, 256, 0, stream>>>(
        x_cat, x_cont, node_emb, x);
    k_deg<<<EB, 256, 0, stream>>>(ei, deg);
    k_scan<<<1, SCAN_T, 0, stream>>>(deg, rowp, cursor);
    k_fill<<<EB, 256, 0, stream>>>(ei, cursor, csr_eid, csr_src);

    k_gine1_gather<<<NB4, 256, 0, stream>>>(
        rowp, csr_eid, csr_src, e_cat, e_cont, edge_emb, W1e, b1e, x, agg36);
    k_gine1_node<<<NBD, 256, 0, stream>>>(
        x, agg36, eps1, W1n, b1n, g1, bb1, m1, v1, h1);
    k_gine2_gather<<<NB4, 256, 0, stream>>>(
        rowp, csr_eid, csr_src, e_cat, e_cont, edge_emb, W2e, b2e, h1, agg128);
    k_gine2_node<<<NBD, 256, 0, stream>>>(
        h1, agg128, eps2, W2n, b2n, g2, bb2, m2, v2, h2);

    k_ea_sum<<<512, 256, 0, stream>>>(e_cat, e_cont, ea_sum);
    k_loop_prep<<<1, C_HID, 0, stream>>>(ea_sum, edge_emb, Weg, ee_loop);

    k_gat0<<<NBD, 256, 0, stream>>>(h2, Wl, bl, Wr, br, xl, xr);
    k_gat_fused<<<NB4, 256, 0, stream>>>(
        rowp, csr_eid, csr_src, e_cat, e_cont, edge_emb, Weg, att, ee_loop,
        xl, xr, gbias, (float*)d_out);
}

// Round 6
// 740.257 us; speedup vs baseline: 16.3252x; 1.1352x over previous
//
#include <hip/hip_runtime.h>
#include <math.h>

#define N_NODES 50000
#define N_EDGES 800000
#define NODE_IN 36
#define EDGE_IN 16
#define C_HID 128
#define C_OUT 64
#define BN_EPS 1e-5f
#define SCAN_T 1024
#define CHUNK ((N_NODES + SCAN_T - 1) / SCAN_T)   // 49
#define DT_NT 32    // nodes per block in dense tiled kernels

__device__ __forceinline__ int rfl(int v) { return __builtin_amdgcn_readfirstlane(v); }

// bf16 <-> f32 (RNE pack, shift unpack)
__device__ __forceinline__ float bf2f(unsigned short u) {
    return __uint_as_float(((unsigned)u) << 16);
}
__device__ __forceinline__ unsigned short f2bf(float f) {
    unsigned u = __float_as_uint(f);
    u += 0x7FFF + ((u >> 16) & 1);
    return (unsigned short)(u >> 16);
}

// select one of 4 per-lane register values by (wave-uniform) cat
__device__ __forceinline__ float sel4(int cat, float a, float b, float c, float d) {
    float r = (cat == 0) ? a : b;
    r = (cat == 2) ? c : r;
    r = (cat == 3) ? d : r;
    return r;
}

// ================= node features =================
__global__ void k_node_feat(const int* __restrict__ xcat,
                            const float* __restrict__ xcont,
                            const float* __restrict__ node_emb,
                            float* __restrict__ x) {
    int idx = blockIdx.x * blockDim.x + threadIdx.x;
    if (idx >= N_NODES * NODE_IN) return;
    int i = idx / NODE_IN;
    int j = idx - i * NODE_IN;
    float v;
    if (j < 20) v = node_emb[xcat[i] * 20 + j];
    else        v = xcont[i * 16 + (j - 20)];
    x[idx] = v;
}

// ================= CSR build =================
__global__ void k_deg(const int* __restrict__ ei, int* __restrict__ deg) {
    int e = blockIdx.x * blockDim.x + threadIdx.x;
    if (e >= N_EDGES) return;
    atomicAdd(deg + ei[N_EDGES + e], 1);
}

__global__ void k_scan(const int* __restrict__ deg, int* __restrict__ rowp,
                       int* __restrict__ cursor) {
    __shared__ int sums[SCAN_T];
    int t = threadIdx.x;
    int lo = t * CHUNK, hi = min(lo + CHUNK, N_NODES);
    int s = 0;
    for (int i = lo; i < hi; i++) s += deg[i];
    sums[t] = s;
    __syncthreads();
    for (int off = 1; off < SCAN_T; off <<= 1) {
        int v = 0;
        if (t >= off) v = sums[t - off];
        __syncthreads();
        if (t >= off) sums[t] += v;
        __syncthreads();
    }
    int run = sums[t] - s;      // exclusive prefix
    for (int i = lo; i < hi; i++) {
        rowp[i] = run;
        cursor[i] = run;
        run += deg[i];
    }
    if (t == SCAN_T - 1) rowp[N_NODES] = sums[SCAN_T - 1];
}

// fill: csr_eid (for econt indirection) + packed src|cat<<24
__global__ void k_fill(const int* __restrict__ ei, const int* __restrict__ ecat,
                       int* __restrict__ cursor,
                       int* __restrict__ csr_eid, int* __restrict__ csr_ps) {
    int e = blockIdx.x * blockDim.x + threadIdx.x;
    if (e >= N_EDGES) return;
    int d = ei[N_EDGES + e];
    int pos = atomicAdd(cursor + d, 1);
    csr_eid[pos] = e;
    csr_ps[pos] = ei[e] | (ecat[e] << 24);
}

// ======== GINE1 gather (F=36): scalar metadata + 4-edge batching ========
__global__ void k_gine1_gather(const int* __restrict__ rowp,
                               const int* __restrict__ csr_eid,
                               const int* __restrict__ csr_ps,
                               const float* __restrict__ econt,
                               const float* __restrict__ edge_emb,
                               const float* __restrict__ W,   // [16,36]
                               const float* __restrict__ b,   // [36]
                               const float* __restrict__ x,
                               float* __restrict__ agg) {
    int i = blockIdx.x * 4 + (threadIdx.x >> 6);
    int lane = threadIdx.x & 63;
    if (i >= N_NODES) return;
    int c = (lane < NODE_IN) ? lane : (NODE_IN - 1);
    float w[12];
#pragma unroll
    for (int k = 0; k < 12; k++) w[k] = W[(4 + k) * NODE_IN + c];
    float tb[4];
#pragma unroll
    for (int q = 0; q < 4; q++) {
        float v = b[c];
#pragma unroll
        for (int k = 0; k < 4; k++) v += edge_emb[q * 4 + k] * W[k * NODE_IN + c];
        tb[q] = v;
    }
    int beg = rfl(rowp[i]), end = rfl(rowp[i + 1]);
    float acc = 0.f;
    int p = beg;
    for (; p + 4 <= end; p += 4) {
        int eid[4], src[4], cat[4];
        float4 A[4], B[4], C4[4];
        float xs[4];
#pragma unroll
        for (int bq = 0; bq < 4; bq++) {
            eid[bq] = rfl(csr_eid[p + bq]);
            int pc = rfl(csr_ps[p + bq]);
            src[bq] = pc & 0xFFFFFF;
            cat[bq] = pc >> 24;
            const float4* ec4 = (const float4*)(econt + (size_t)eid[bq] * 12);
            A[bq] = ec4[0]; B[bq] = ec4[1]; C4[bq] = ec4[2];
            xs[bq] = x[(size_t)src[bq] * NODE_IN + c];
        }
#pragma unroll
        for (int bq = 0; bq < 4; bq++) {
            float t = sel4(cat[bq], tb[0], tb[1], tb[2], tb[3]);
            t += A[bq].x * w[0] + A[bq].y * w[1] + A[bq].z * w[2] + A[bq].w * w[3];
            t += B[bq].x * w[4] + B[bq].y * w[5] + B[bq].z * w[6] + B[bq].w * w[7];
            t += C4[bq].x * w[8] + C4[bq].y * w[9] + C4[bq].z * w[10] + C4[bq].w * w[11];
            acc += fmaxf(xs[bq] + t, 0.f);
        }
    }
    for (; p < end; ++p) {
        int eid = rfl(csr_eid[p]);
        int pc = rfl(csr_ps[p]);
        int src = pc & 0xFFFFFF;
        int cat = pc >> 24;
        const float4* ec4 = (const float4*)(econt + (size_t)eid * 12);
        float4 A = ec4[0], B = ec4[1], C4 = ec4[2];
        float t = sel4(cat, tb[0], tb[1], tb[2], tb[3]);
        t += A.x * w[0] + A.y * w[1] + A.z * w[2] + A.w * w[3];
        t += B.x * w[4] + B.y * w[5] + B.z * w[6] + B.w * w[7];
        t += C4.x * w[8] + C4.y * w[9] + C4.z * w[10] + C4.w * w[11];
        acc += fmaxf(x[(size_t)src * NODE_IN + c] + t, 0.f);
    }
    if (lane < NODE_IN) agg[(size_t)i * NODE_IN + lane] = acc;
}

// ===== GINE1 node MLP + BN, tiled; OUTPUT h1 in bf16 =====
__global__ __launch_bounds__(256, 4) void k_gine1_node(
        const float* __restrict__ x, const float* __restrict__ agg,
        const float* __restrict__ eps_p,
        const float* __restrict__ W,   // [36,128]
        const float* __restrict__ b, const float* __restrict__ g,
        const float* __restrict__ bb, const float* __restrict__ m,
        const float* __restrict__ v, unsigned short* __restrict__ h) {
    __shared__ float sW[NODE_IN * C_HID];     // 18 KB
    __shared__ float sz[DT_NT * NODE_IN];     // 4.5 KB
    int tid = threadIdx.x;
    int node0 = blockIdx.x * DT_NT;
    float eps = eps_p[0];
    {
        const float4* Wv = (const float4*)W;
        float4* sWv = (float4*)sW;
        for (int t = tid; t < NODE_IN * C_HID / 4; t += 256) sWv[t] = Wv[t];
    }
    {
        int nmax = min(DT_NT, N_NODES - node0);
        int tot = nmax * NODE_IN / 4;
        const float4* xv = (const float4*)(x + (size_t)node0 * NODE_IN);
        const float4* av = (const float4*)(agg + (size_t)node0 * NODE_IN);
        float4* szv = (float4*)sz;
        float s = 1.f + eps;
        for (int t = tid; t < tot; t += 256) {
            float4 a = xv[t], c = av[t];
            float4 r;
            r.x = s * a.x + c.x; r.y = s * a.y + c.y;
            r.z = s * a.z + c.z; r.w = s * a.w + c.w;
            szv[t] = r;
        }
    }
    __syncthreads();
    int cg = tid & 31, c0 = cg * 4;
    int n0 = (tid >> 5) * 4;
    float4 bi = *(const float4*)&b[c0];
    float acc[4][4];
#pragma unroll
    for (int n = 0; n < 4; n++) {
        acc[n][0] = bi.x; acc[n][1] = bi.y; acc[n][2] = bi.z; acc[n][3] = bi.w;
    }
#pragma unroll 2
    for (int jb = 0; jb < NODE_IN; jb += 4) {
        float4 w0 = *(const float4*)&sW[(jb + 0) * C_HID + c0];
        float4 w1 = *(const float4*)&sW[(jb + 1) * C_HID + c0];
        float4 w2 = *(const float4*)&sW[(jb + 2) * C_HID + c0];
        float4 w3 = *(const float4*)&sW[(jb + 3) * C_HID + c0];
#pragma unroll
        for (int n = 0; n < 4; n++) {
            float4 zz = *(const float4*)&sz[(n0 + n) * NODE_IN + jb];
            acc[n][0] += zz.x * w0.x + zz.y * w1.x + zz.z * w2.x + zz.w * w3.x;
            acc[n][1] += zz.x * w0.y + zz.y * w1.y + zz.z * w2.y + zz.w * w3.y;
            acc[n][2] += zz.x * w0.z + zz.y * w1.z + zz.z * w2.z + zz.w * w3.z;
            acc[n][3] += zz.x * w0.w + zz.y * w1.w + zz.z * w2.w + zz.w * w3.w;
        }
    }
    float4 gg = *(const float4*)&g[c0];
    float4 mm = *(const float4*)&m[c0];
    float4 vv = *(const float4*)&v[c0];
    float4 bbv = *(const float4*)&bb[c0];
    float4 sc;
    sc.x = gg.x * rsqrtf(vv.x + BN_EPS); sc.y = gg.y * rsqrtf(vv.y + BN_EPS);
    sc.z = gg.z * rsqrtf(vv.z + BN_EPS); sc.w = gg.w * rsqrtf(vv.w + BN_EPS);
#pragma unroll
    for (int n = 0; n < 4; n++) {
        int i = node0 + n0 + n;
        if (i < N_NODES) {
            ushort4 o;
            o.x = f2bf((fmaxf(acc[n][0], 0.f) - mm.x) * sc.x + bbv.x);
            o.y = f2bf((fmaxf(acc[n][1], 0.f) - mm.y) * sc.y + bbv.y);
            o.z = f2bf((fmaxf(acc[n][2], 0.f) - mm.z) * sc.z + bbv.z);
            o.w = f2bf((fmaxf(acc[n][3], 0.f) - mm.w) * sc.w + bbv.w);
            *(ushort4*)&h[(size_t)i * C_HID + c0] = o;
        }
    }
}

// ======== GINE2 gather (F=128): bf16 h1 reads, scalar metadata ========
__global__ void k_gine2_gather(const int* __restrict__ rowp,
                               const int* __restrict__ csr_eid,
                               const int* __restrict__ csr_ps,
                               const float* __restrict__ econt,
                               const float* __restrict__ edge_emb,
                               const float* __restrict__ W,   // [16,128]
                               const float* __restrict__ b,   // [128]
                               const unsigned short* __restrict__ h1,
                               float* __restrict__ agg) {
    int i = blockIdx.x * 4 + (threadIdx.x >> 6);
    int lane = threadIdx.x & 63;
    if (i >= N_NODES) return;
    int c0 = lane, c1 = lane + 64;
    float w0[12], w1[12];
#pragma unroll
    for (int k = 0; k < 12; k++) {
        w0[k] = W[(4 + k) * C_HID + c0];
        w1[k] = W[(4 + k) * C_HID + c1];
    }
    float tb0[4], tb1[4];
#pragma unroll
    for (int q = 0; q < 4; q++) {
        float v0 = b[c0], v1 = b[c1];
#pragma unroll
        for (int k = 0; k < 4; k++) {
            float ev = edge_emb[q * 4 + k];
            v0 += ev * W[k * C_HID + c0];
            v1 += ev * W[k * C_HID + c1];
        }
        tb0[q] = v0; tb1[q] = v1;
    }
    int beg = rfl(rowp[i]), end = rfl(rowp[i + 1]);
    float acc0 = 0.f, acc1 = 0.f;
    int p = beg;
    for (; p + 4 <= end; p += 4) {
        int eid[4], src[4], cat[4];
        float4 A[4], B[4], C4[4];
        float xs0[4], xs1[4];
#pragma unroll
        for (int bq = 0; bq < 4; bq++) {
            eid[bq] = rfl(csr_eid[p + bq]);
            int pc = rfl(csr_ps[p + bq]);
            src[bq] = pc & 0xFFFFFF;
            cat[bq] = pc >> 24;
            const float4* ec4 = (const float4*)(econt + (size_t)eid[bq] * 12);
            A[bq] = ec4[0]; B[bq] = ec4[1]; C4[bq] = ec4[2];
            const unsigned short* hs = h1 + (size_t)src[bq] * C_HID;
            xs0[bq] = bf2f(hs[c0]); xs1[bq] = bf2f(hs[c1]);
        }
#pragma unroll
        for (int bq = 0; bq < 4; bq++) {
            float t0 = sel4(cat[bq], tb0[0], tb0[1], tb0[2], tb0[3]);
            float t1 = sel4(cat[bq], tb1[0], tb1[1], tb1[2], tb1[3]);
            t0 += A[bq].x * w0[0] + A[bq].y * w0[1] + A[bq].z * w0[2] + A[bq].w * w0[3];
            t1 += A[bq].x * w1[0] + A[bq].y * w1[1] + A[bq].z * w1[2] + A[bq].w * w1[3];
            t0 += B[bq].x * w0[4] + B[bq].y * w0[5] + B[bq].z * w0[6] + B[bq].w * w0[7];
            t1 += B[bq].x * w1[4] + B[bq].y * w1[5] + B[bq].z * w1[6] + B[bq].w * w1[7];
            t0 += C4[bq].x * w0[8] + C4[bq].y * w0[9] + C4[bq].z * w0[10] + C4[bq].w * w0[11];
            t1 += C4[bq].x * w1[8] + C4[bq].y * w1[9] + C4[bq].z * w1[10] + C4[bq].w * w1[11];
            acc0 += fmaxf(xs0[bq] + t0, 0.f);
            acc1 += fmaxf(xs1[bq] + t1, 0.f);
        }
    }
    for (; p < end; ++p) {
        int eid = rfl(csr_eid[p]);
        int pc = rfl(csr_ps[p]);
        int src = pc & 0xFFFFFF;
        int cat = pc >> 24;
        const float4* ec4 = (const float4*)(econt + (size_t)eid * 12);
        float4 A = ec4[0], B = ec4[1], C4 = ec4[2];
        float t0 = sel4(cat, tb0[0], tb0[1], tb0[2], tb0[3]);
        float t1 = sel4(cat, tb1[0], tb1[1], tb1[2], tb1[3]);
        t0 += A.x * w0[0] + A.y * w0[1] + A.z * w0[2] + A.w * w0[3];
        t1 += A.x * w1[0] + A.y * w1[1] + A.z * w1[2] + A.w * w1[3];
        t0 += B.x * w0[4] + B.y * w0[5] + B.z * w0[6] + B.w * w0[7];
        t1 += B.x * w1[4] + B.y * w1[5] + B.z * w1[6] + B.w * w1[7];
        t0 += C4.x * w0[8] + C4.y * w0[9] + C4.z * w0[10] + C4.w * w0[11];
        t1 += C4.x * w1[8] + C4.y * w1[9] + C4.z * w1[10] + C4.w * w1[11];
        const unsigned short* hs = h1 + (size_t)src * C_HID;
        acc0 += fmaxf(bf2f(hs[c0]) + t0, 0.f);
        acc1 += fmaxf(bf2f(hs[c1]) + t1, 0.f);
    }
    agg[(size_t)i * C_HID + c0] = acc0;
    agg[(size_t)i * C_HID + c1] = acc1;
}

// ===== GINE2 node MLP + BN, tiled; h1 input bf16, h2 output fp32 =====
__global__ __launch_bounds__(256, 4) void k_gine2_node(
        const unsigned short* __restrict__ h1, const float* __restrict__ agg,
        const float* __restrict__ eps_p,
        const float* __restrict__ W,   // [128,128]
        const float* __restrict__ b, const float* __restrict__ g,
        const float* __restrict__ bb, const float* __restrict__ m,
        const float* __restrict__ v, float* __restrict__ h2) {
    __shared__ float sW[64 * C_HID];          // 32 KB (half of W)
    __shared__ float sz[DT_NT * C_HID];       // 16 KB
    int tid = threadIdx.x;
    int node0 = blockIdx.x * DT_NT;
    float eps = eps_p[0];
    {
        int nmax = min(DT_NT, N_NODES - node0);
        int tot = nmax * C_HID / 4;
        const ushort4* hv = (const ushort4*)(h1 + (size_t)node0 * C_HID);
        const float4* av = (const float4*)(agg + (size_t)node0 * C_HID);
        float4* szv = (float4*)sz;
        float s = 1.f + eps;
        for (int t = tid; t < tot; t += 256) {
            ushort4 a = hv[t]; float4 c = av[t];
            float4 r;
            r.x = s * bf2f(a.x) + c.x; r.y = s * bf2f(a.y) + c.y;
            r.z = s * bf2f(a.z) + c.z; r.w = s * bf2f(a.w) + c.w;
            szv[t] = r;
        }
    }
    int cg = tid & 31, c0 = cg * 4;
    int n0 = (tid >> 5) * 4;
    float4 bi = *(const float4*)&b[c0];
    float acc[4][4];
#pragma unroll
    for (int n = 0; n < 4; n++) {
        acc[n][0] = bi.x; acc[n][1] = bi.y; acc[n][2] = bi.z; acc[n][3] = bi.w;
    }
    for (int half = 0; half < 2; half++) {
        __syncthreads();
        {
            const float4* Wv = (const float4*)(W + half * 64 * C_HID);
            float4* sWv = (float4*)sW;
            for (int t = tid; t < 64 * C_HID / 4; t += 256) sWv[t] = Wv[t];
        }
        __syncthreads();
        int jbase = half * 64;
#pragma unroll 2
        for (int jb = 0; jb < 64; jb += 4) {
            float4 w0 = *(const float4*)&sW[(jb + 0) * C_HID + c0];
            float4 w1 = *(const float4*)&sW[(jb + 1) * C_HID + c0];
            float4 w2 = *(const float4*)&sW[(jb + 2) * C_HID + c0];
            float4 w3 = *(const float4*)&sW[(jb + 3) * C_HID + c0];
#pragma unroll
            for (int n = 0; n < 4; n++) {
                float4 zz = *(const float4*)&sz[(n0 + n) * C_HID + jbase + jb];
                acc[n][0] += zz.x * w0.x + zz.y * w1.x + zz.z * w2.x + zz.w * w3.x;
                acc[n][1] += zz.x * w0.y + zz.y * w1.y + zz.z * w2.y + zz.w * w3.y;
                acc[n][2] += zz.x * w0.z + zz.y * w1.z + zz.z * w2.z + zz.w * w3.z;
                acc[n][3] += zz.x * w0.w + zz.y * w1.w + zz.z * w2.w + zz.w * w3.w;
            }
        }
    }
    float4 gg = *(const float4*)&g[c0];
    float4 mm = *(const float4*)&m[c0];
    float4 vv = *(const float4*)&v[c0];
    float4 bbv = *(const float4*)&bb[c0];
    float4 sc;
    sc.x = gg.x * rsqrtf(vv.x + BN_EPS); sc.y = gg.y * rsqrtf(vv.y + BN_EPS);
    sc.z = gg.z * rsqrtf(vv.z + BN_EPS); sc.w = gg.w * rsqrtf(vv.w + BN_EPS);
#pragma unroll
    for (int n = 0; n < 4; n++) {
        int i = node0 + n0 + n;
        if (i < N_NODES) {
            float4 o;
            o.x = (fmaxf(acc[n][0], 0.f) - mm.x) * sc.x + bbv.x;
            o.y = (fmaxf(acc[n][1], 0.f) - mm.y) * sc.y + bbv.y;
            o.z = (fmaxf(acc[n][2], 0.f) - mm.z) * sc.z + bbv.z;
            o.w = (fmaxf(acc[n][3], 0.f) - mm.w) * sc.w + bbv.w;
            *(float4*)&h2[(size_t)i * C_HID + c0] = o;
        }
    }
}

// ===== mean edge feature: wide grid, float4 loads, category counts =====
__global__ void k_ea_sum(const int* __restrict__ ecat,
                         const float* __restrict__ econt,
                         float* __restrict__ ea_sum) {   // [0..11] cont, [12..15] counts
    float p[12];
#pragma unroll
    for (int k = 0; k < 12; k++) p[k] = 0.f;
    float cnt[4] = {0.f, 0.f, 0.f, 0.f};
    int stride = gridDim.x * blockDim.x;
    for (int e = blockIdx.x * blockDim.x + threadIdx.x; e < N_EDGES; e += stride) {
        int c = ecat[e];
        cnt[0] += (c == 0) ? 1.f : 0.f;
        cnt[1] += (c == 1) ? 1.f : 0.f;
        cnt[2] += (c == 2) ? 1.f : 0.f;
        cnt[3] += (c == 3) ? 1.f : 0.f;
        const float4* v4 = (const float4*)(econt + (size_t)e * 12);
        float4 a = v4[0], bq = v4[1], d = v4[2];
        p[0] += a.x;  p[1] += a.y;  p[2] += a.z;  p[3] += a.w;
        p[4] += bq.x; p[5] += bq.y; p[6] += bq.z; p[7] += bq.w;
        p[8] += d.x;  p[9] += d.y;  p[10] += d.z; p[11] += d.w;
    }
    float vals[16];
#pragma unroll
    for (int k = 0; k < 12; k++) vals[k] = p[k];
#pragma unroll
    for (int k = 0; k < 4; k++) vals[12 + k] = cnt[k];
#pragma unroll
    for (int k = 0; k < 16; k++) {
        float v = vals[k];
#pragma unroll
        for (int off = 32; off > 0; off >>= 1) v += __shfl_xor(v, off);
        vals[k] = v;
    }
    __shared__ float red[4][16];
    int wid = threadIdx.x >> 6, lane = threadIdx.x & 63;
    if (lane == 0) {
#pragma unroll
        for (int k = 0; k < 16; k++) red[wid][k] = vals[k];
    }
    __syncthreads();
    if (threadIdx.x < 16) {
        float s = red[0][threadIdx.x] + red[1][threadIdx.x] +
                  red[2][threadIdx.x] + red[3][threadIdx.x];
        atomicAdd(ea_sum + threadIdx.x, s);
    }
}

__global__ void k_loop_prep(const float* __restrict__ ea_sum,
                            const float* __restrict__ edge_emb,
                            const float* __restrict__ We,
                            float* __restrict__ ee_loop) {
    int c = threadIdx.x;
    const float inv = 1.f / (float)N_EDGES;
    float acc = 0.f;
#pragma unroll
    for (int k = 0; k < 4; k++) {
        float s = 0.f;
#pragma unroll
        for (int q = 0; q < 4; q++) s += ea_sum[12 + q] * edge_emb[q * 4 + k];
        acc += (s * inv) * We[k * C_HID + c];
    }
#pragma unroll
    for (int k = 0; k < 12; k++)
        acc += (ea_sum[k] * inv) * We[(4 + k) * C_HID + c];
    ee_loop[c] = acc;
}

// ===== GAT node transforms: xl (bf16), xr (fp32), tiled =====
__global__ __launch_bounds__(256, 4) void k_gat0(
        const float* __restrict__ h2,
        const float* __restrict__ Wl, const float* __restrict__ bl,
        const float* __restrict__ Wr, const float* __restrict__ br,
        unsigned short* __restrict__ xl, float* __restrict__ xr) {
    __shared__ float sW[64 * C_HID];          // 32 KB
    __shared__ float sz[DT_NT * C_HID];       // 16 KB
    int tid = threadIdx.x;
    int node0 = blockIdx.x * DT_NT;
    {
        int nmax = min(DT_NT, N_NODES - node0);
        int tot = nmax * C_HID / 4;
        const float4* hv = (const float4*)(h2 + (size_t)node0 * C_HID);
        float4* szv = (float4*)sz;
        for (int t = tid; t < tot; t += 256) szv[t] = hv[t];
    }
    int cg = tid & 31, c0 = cg * 4;
    int n0 = (tid >> 5) * 4;
    for (int wsel = 0; wsel < 2; wsel++) {
        const float* Wm = wsel ? Wr : Wl;
        const float* bm = wsel ? br : bl;
        float4 bi = *(const float4*)&bm[c0];
        float acc[4][4];
#pragma unroll
        for (int n = 0; n < 4; n++) {
            acc[n][0] = bi.x; acc[n][1] = bi.y; acc[n][2] = bi.z; acc[n][3] = bi.w;
        }
        for (int half = 0; half < 2; half++) {
            __syncthreads();
            {
                const float4* Wv = (const float4*)(Wm + half * 64 * C_HID);
                float4* sWv = (float4*)sW;
                for (int t = tid; t < 64 * C_HID / 4; t += 256) sWv[t] = Wv[t];
            }
            __syncthreads();
            int jbase = half * 64;
#pragma unroll 2
            for (int jb = 0; jb < 64; jb += 4) {
                float4 w0 = *(const float4*)&sW[(jb + 0) * C_HID + c0];
                float4 w1 = *(const float4*)&sW[(jb + 1) * C_HID + c0];
                float4 w2 = *(const float4*)&sW[(jb + 2) * C_HID + c0];
                float4 w3 = *(const float4*)&sW[(jb + 3) * C_HID + c0];
#pragma unroll
                for (int n = 0; n < 4; n++) {
                    float4 zz = *(const float4*)&sz[(n0 + n) * C_HID + jbase + jb];
                    acc[n][0] += zz.x * w0.x + zz.y * w1.x + zz.z * w2.x + zz.w * w3.x;
                    acc[n][1] += zz.x * w0.y + zz.y * w1.y + zz.z * w2.y + zz.w * w3.y;
                    acc[n][2] += zz.x * w0.z + zz.y * w1.z + zz.z * w2.z + zz.w * w3.z;
                    acc[n][3] += zz.x * w0.w + zz.y * w1.w + zz.z * w2.w + zz.w * w3.w;
                }
            }
        }
#pragma unroll
        for (int n = 0; n < 4; n++) {
            int i = node0 + n0 + n;
            if (i < N_NODES) {
                if (wsel == 0) {
                    ushort4 o;
                    o.x = f2bf(acc[n][0]); o.y = f2bf(acc[n][1]);
                    o.z = f2bf(acc[n][2]); o.w = f2bf(acc[n][3]);
                    *(ushort4*)&xl[(size_t)i * C_HID + c0] = o;
                } else {
                    float4 o;
                    o.x = acc[n][0]; o.y = acc[n][1]; o.z = acc[n][2]; o.w = acc[n][3];
                    *(float4*)&xr[(size_t)i * C_HID + c0] = o;
                }
            }
        }
    }
}

// ===== GAT fused: bf16 xl reads, scalar metadata, batched online softmax =====
__global__ void k_gat_fused(const int* __restrict__ rowp,
                            const int* __restrict__ csr_eid,
                            const int* __restrict__ csr_ps,
                            const float* __restrict__ econt,
                            const float* __restrict__ edge_emb,
                            const float* __restrict__ We,    // [16,128]
                            const float* __restrict__ att,   // [128]
                            const float* __restrict__ ee_loop,
                            const unsigned short* __restrict__ xl,
                            const float* __restrict__ xr,
                            const float* __restrict__ bias,  // [64]
                            float* __restrict__ out) {
    int i = blockIdx.x * 4 + (threadIdx.x >> 6);
    int lane = threadIdx.x & 63;
    if (i >= N_NODES) return;
    int c0 = lane, c1 = lane + 64;
    float w0[12], w1[12];
#pragma unroll
    for (int k = 0; k < 12; k++) {
        w0[k] = We[(4 + k) * C_HID + c0];
        w1[k] = We[(4 + k) * C_HID + c1];
    }
    float tb0[4], tb1[4];
#pragma unroll
    for (int q = 0; q < 4; q++) {
        float v0 = 0.f, v1 = 0.f;
#pragma unroll
        for (int k = 0; k < 4; k++) {
            float ev = edge_emb[q * 4 + k];
            v0 += ev * We[k * C_HID + c0];
            v1 += ev * We[k * C_HID + c1];
        }
        tb0[q] = v0; tb1[q] = v1;
    }
    float at0 = att[c0], at1 = att[c1];
    float lp0 = ee_loop[c0], lp1 = ee_loop[c1];

    float xr0 = xr[(size_t)i * C_HID + c0];
    float xr1 = xr[(size_t)i * C_HID + c1];
    float xld0 = bf2f(xl[(size_t)i * C_HID + c0]);
    float xld1 = bf2f(xl[(size_t)i * C_HID + c1]);

    float m0 = xld0 + xr0 + lp0; m0 = (m0 > 0.f) ? m0 : 0.2f * m0;
    float m1 = xld1 + xr1 + lp1; m1 = (m1 > 0.f) ? m1 : 0.2f * m1;
    float v0 = m0 * at0;
    float v1 = m1 * at1;
#pragma unroll
    for (int off = 32; off > 0; off >>= 1) {
        v0 += __shfl_xor(v0, off);
        v1 += __shfl_xor(v1, off);
    }
    float rm0 = v0, rm1 = v1;
    float den0 = 1.f, den1 = 1.f;
    float acc0 = xld0, acc1 = xld1;

    int beg = rfl(rowp[i]), end = rfl(rowp[i + 1]);
    int p = beg;
    for (; p + 4 <= end; p += 4) {
        int eid[4], src[4], cat[4];
        float4 A[4], B[4], C4[4];
        float xs0[4], xs1[4];
#pragma unroll
        for (int bq = 0; bq < 4; bq++) {
            eid[bq] = rfl(csr_eid[p + bq]);
            int pc = rfl(csr_ps[p + bq]);
            src[bq] = pc & 0xFFFFFF;
            cat[bq] = pc >> 24;
            const float4* ec4 = (const float4*)(econt + (size_t)eid[bq] * 12);
            A[bq] = ec4[0]; B[bq] = ec4[1]; C4[bq] = ec4[2];
            const unsigned short* xls = xl + (size_t)src[bq] * C_HID;
            xs0[bq] = bf2f(xls[c0]); xs1[bq] = bf2f(xls[c1]);
        }
        float d0[4], d1[4];
#pragma unroll
        for (int bq = 0; bq < 4; bq++) {
            float e0 = sel4(cat[bq], tb0[0], tb0[1], tb0[2], tb0[3]);
            float e1 = sel4(cat[bq], tb1[0], tb1[1], tb1[2], tb1[3]);
            e0 += A[bq].x * w0[0] + A[bq].y * w0[1] + A[bq].z * w0[2] + A[bq].w * w0[3];
            e1 += A[bq].x * w1[0] + A[bq].y * w1[1] + A[bq].z * w1[2] + A[bq].w * w1[3];
            e0 += B[bq].x * w0[4] + B[bq].y * w0[5] + B[bq].z * w0[6] + B[bq].w * w0[7];
            e1 += B[bq].x * w1[4] + B[bq].y * w1[5] + B[bq].z * w1[6] + B[bq].w * w1[7];
            e0 += C4[bq].x * w0[8] + C4[bq].y * w0[9] + C4[bq].z * w0[10] + C4[bq].w * w0[11];
            e1 += C4[bq].x * w1[8] + C4[bq].y * w1[9] + C4[bq].z * w1[10] + C4[bq].w * w1[11];
            float z0 = xs0[bq] + xr0 + e0; z0 = (z0 > 0.f) ? z0 : 0.2f * z0;
            float z1 = xs1[bq] + xr1 + e1; z1 = (z1 > 0.f) ? z1 : 0.2f * z1;
            d0[bq] = z0 * at0;
            d1[bq] = z1 * at1;
        }
#pragma unroll
        for (int off = 32; off > 0; off >>= 1) {
#pragma unroll
            for (int bq = 0; bq < 4; bq++) {
                d0[bq] += __shfl_xor(d0[bq], off);
                d1[bq] += __shfl_xor(d1[bq], off);
            }
        }
        {
            float bm = fmaxf(fmaxf(d0[0], d0[1]), fmaxf(d0[2], d0[3]));
            float nm = fmaxf(rm0, bm);
            float r = __expf(rm0 - nm);
            float p0 = __expf(d0[0] - nm), p1 = __expf(d0[1] - nm);
            float p2 = __expf(d0[2] - nm), p3 = __expf(d0[3] - nm);
            den0 = den0 * r + ((p0 + p1) + (p2 + p3));
            acc0 = acc0 * r + (p0 * xs0[0] + p1 * xs0[1] + p2 * xs0[2] + p3 * xs0[3]);
            rm0 = nm;
        }
        {
            float bm = fmaxf(fmaxf(d1[0], d1[1]), fmaxf(d1[2], d1[3]));
            float nm = fmaxf(rm1, bm);
            float r = __expf(rm1 - nm);
            float p0 = __expf(d1[0] - nm), p1 = __expf(d1[1] - nm);
            float p2 = __expf(d1[2] - nm), p3 = __expf(d1[3] - nm);
            den1 = den1 * r + ((p0 + p1) + (p2 + p3));
            acc1 = acc1 * r + (p0 * xs1[0] + p1 * xs1[1] + p2 * xs1[2] + p3 * xs1[3]);
            rm1 = nm;
        }
    }
    for (; p < end; ++p) {
        int eid = rfl(csr_eid[p]);
        int pc = rfl(csr_ps[p]);
        int src = pc & 0xFFFFFF;
        int cat = pc >> 24;
        const float4* ec4 = (const float4*)(econt + (size_t)eid * 12);
        float4 A = ec4[0], B = ec4[1], C4 = ec4[2];
        float e0 = sel4(cat, tb0[0], tb0[1], tb0[2], tb0[3]);
        float e1 = sel4(cat, tb1[0], tb1[1], tb1[2], tb1[3]);
        e0 += A.x * w0[0] + A.y * w0[1] + A.z * w0[2] + A.w * w0[3];
        e1 += A.x * w1[0] + A.y * w1[1] + A.z * w1[2] + A.w * w1[3];
        e0 += B.x * w0[4] + B.y * w0[5] + B.z * w0[6] + B.w * w0[7];
        e1 += B.x * w1[4] + B.y * w1[5] + B.z * w1[6] + B.w * w1[7];
        e0 += C4.x * w0[8] + C4.y * w0[9] + C4.z * w0[10] + C4.w * w0[11];
        e1 += C4.x * w1[8] + C4.y * w1[9] + C4.z * w1[10] + C4.w * w1[11];
        const unsigned short* xls = xl + (size_t)src * C_HID;
        float xs0 = bf2f(xls[c0]), xs1 = bf2f(xls[c1]);
        float z0 = xs0 + xr0 + e0; z0 = (z0 > 0.f) ? z0 : 0.2f * z0;
        float z1 = xs1 + xr1 + e1; z1 = (z1 > 0.f) ? z1 : 0.2f * z1;
        float a0 = z0 * at0;
        float a1 = z1 * at1;
#pragma unroll
        for (int off = 32; off > 0; off >>= 1) {
            a0 += __shfl_xor(a0, off);
            a1 += __shfl_xor(a1, off);
        }
        float nm0 = fmaxf(rm0, a0);
        float so0 = __expf(rm0 - nm0);
        float sn0 = __expf(a0 - nm0);
        den0 = den0 * so0 + sn0;
        acc0 = acc0 * so0 + sn0 * xs0;
        rm0 = nm0;
        float nm1 = fmaxf(rm1, a1);
        float so1 = __expf(rm1 - nm1);
        float sn1 = __expf(a1 - nm1);
        den1 = den1 * so1 + sn1;
        acc1 = acc1 * so1 + sn1 * xs1;
        rm1 = nm1;
    }
    out[(size_t)i * C_OUT + lane] = 0.5f * (acc0 / den0 + acc1 / den1) + bias[lane];
}

extern "C" void kernel_launch(void* const* d_in, const int* in_sizes, int n_in,
                              void* d_out, int out_size, void* d_ws, size_t ws_size,
                              hipStream_t stream) {
    const int*   x_cat    = (const int*)d_in[0];
    const float* x_cont   = (const float*)d_in[1];
    const int*   e_cat    = (const int*)d_in[2];
    const float* e_cont   = (const float*)d_in[3];
    const int*   ei       = (const int*)d_in[4];
    const float* node_emb = (const float*)d_in[5];
    const float* edge_emb = (const float*)d_in[6];
    const float* eps1     = (const float*)d_in[7];
    const float* W1e      = (const float*)d_in[8];
    const float* b1e      = (const float*)d_in[9];
    const float* W1n      = (const float*)d_in[10];
    const float* b1n      = (const float*)d_in[11];
    const float* g1       = (const float*)d_in[12];
    const float* bb1      = (const float*)d_in[13];
    const float* m1       = (const float*)d_in[14];
    const float* v1       = (const float*)d_in[15];
    const float* eps2     = (const float*)d_in[16];
    const float* W2e      = (const float*)d_in[17];
    const float* b2e      = (const float*)d_in[18];
    const float* W2n      = (const float*)d_in[19];
    const float* b2n      = (const float*)d_in[20];
    const float* g2       = (const float*)d_in[21];
    const float* bb2      = (const float*)d_in[22];
    const float* m2       = (const float*)d_in[23];
    const float* v2       = (const float*)d_in[24];
    const float* Wl       = (const float*)d_in[25];
    const float* bl       = (const float*)d_in[26];
    const float* Wr       = (const float*)d_in[27];
    const float* br       = (const float*)d_in[28];
    const float* Weg      = (const float*)d_in[29];
    const float* att      = (const float*)d_in[30];
    const float* gbias    = (const float*)d_in[31];

    const size_t NF128 = (size_t)N_NODES * C_HID;

    // layout: A (fp32, x -> h2) | B (fp32, agg36/agg128 -> xr) | Hb (bf16, h1 -> xl)
    float* A = (float*)d_ws;                 // 6.4M floats
    float* B = A + NF128;                    // 6.4M floats
    unsigned short* Hb = (unsigned short*)(B + NF128);   // 6.4M ushorts
    float* ea_sum  = (float*)(Hb + NF128);   // 16
    float* ee_loop = ea_sum + 16;            // 128
    int* deg     = (int*)(ee_loop + C_HID);  // N
    int* cursor  = deg + N_NODES;            // N
    int* rowp    = cursor + N_NODES;         // N+1
    int* csr_eid = rowp + N_NODES + 1;       // E
    int* csr_ps  = csr_eid + N_EDGES;        // E

    float* x = A;                 // N*36 (dead before h2 written)
    float* h2 = A;
    float* agg36 = B; float* agg128 = B; float* xr = B;
    unsigned short* h1 = Hb; unsigned short* xl = Hb;

    size_t need = (size_t)((char*)(csr_ps + N_EDGES) - (char*)d_ws);
    if (ws_size < need) return;

    hipMemsetAsync(deg, 0, N_NODES * sizeof(int), stream);
    hipMemsetAsync(ea_sum, 0, 16 * sizeof(float), stream);

    const int EB = (N_EDGES + 255) / 256;
    const int NB4 = (N_NODES + 3) / 4;
    const int NBD = (N_NODES + DT_NT - 1) / DT_NT;

    k_node_feat<<<(N_NODES * NODE_IN + 255) / 256, 256, 0, stream>>>(
        x_cat, x_cont, node_emb, x);
    k_deg<<<EB, 256, 0, stream>>>(ei, deg);
    k_scan<<<1, SCAN_T, 0, stream>>>(deg, rowp, cursor);
    k_fill<<<EB, 256, 0, stream>>>(ei, e_cat, cursor, csr_eid, csr_ps);

    k_gine1_gather<<<NB4, 256, 0, stream>>>(
        rowp, csr_eid, csr_ps, e_cont, edge_emb, W1e, b1e, x, agg36);
    k_gine1_node<<<NBD, 256, 0, stream>>>(
        x, agg36, eps1, W1n, b1n, g1, bb1, m1, v1, h1);
    k_gine2_gather<<<NB4, 256, 0, stream>>>(
        rowp, csr_eid, csr_ps, e_cont, edge_emb, W2e, b2e, h1, agg128);
    k_gine2_node<<<NBD, 256, 0, stream>>>(
        h1, agg128, eps2, W2n, b2n, g2, bb2, m2, v2, h2);

    k_ea_sum<<<512, 256, 0, stream>>>(e_cat, e_cont, ea_sum);
    k_loop_prep<<<1, C_HID, 0, stream>>>(ea_sum, edge_emb, Weg, ee_loop);

    k_gat0<<<NBD, 256, 0, stream>>>(h2, Wl, bl, Wr, br, xl, xr);
    k_gat_fused<<<NB4, 256, 0, stream>>>(
        rowp, csr_eid, csr_ps, e_cont, edge_emb, Weg, att, ee_loop,
        xl, xr, gbias, (float*)d_out);
}

// Round 7
// 719.675 us; speedup vs baseline: 16.7920x; 1.0286x over previous
//
#include <hip/hip_runtime.h>
#include <math.h>

#define N_NODES 50000
#define N_EDGES 800000
#define NODE_IN 36
#define EDGE_IN 16
#define C_HID 128
#define C_OUT 64
#define BN_EPS 1e-5f
#define SCAN_T 1024
#define CHUNK ((N_NODES + SCAN_T - 1) / SCAN_T)   // 49
#define DT_NT 32    // nodes per block in dense tiled kernels

typedef __attribute__((ext_vector_type(2))) float v2f;

__device__ __forceinline__ int rfl(int v) { return __builtin_amdgcn_readfirstlane(v); }

__device__ __forceinline__ v2f v2(float s) { v2f r; r.x = s; r.y = s; return r; }

// paired bf16: u32 = bf16(lo) | bf16(hi)<<16 ; lo = channel c, hi = channel c+64
__device__ __forceinline__ v2f unpack_bf2(unsigned u) {
    v2f r;
    r.x = __uint_as_float(u << 16);
    r.y = __uint_as_float(u & 0xFFFF0000u);
    return r;
}
__device__ __forceinline__ unsigned pack_bf2(float lo, float hi) {
    unsigned ul = __float_as_uint(lo); ul += 0x7FFF + ((ul >> 16) & 1);
    unsigned uh = __float_as_uint(hi); uh += 0x7FFF + ((uh >> 16) & 1);
    return (ul >> 16) | (uh & 0xFFFF0000u);
}

__device__ __forceinline__ v2f sel4v(int cat, v2f a, v2f b, v2f c, v2f d) {
    v2f r = (cat == 0) ? a : b;
    r = (cat == 2) ? c : r;
    r = (cat == 3) ? d : r;
    return r;
}
__device__ __forceinline__ float sel4(int cat, float a, float b, float c, float d) {
    float r = (cat == 0) ? a : b;
    r = (cat == 2) ? c : r;
    r = (cat == 3) ? d : r;
    return r;
}

// ================= node features =================
__global__ void k_node_feat(const int* __restrict__ xcat,
                            const float* __restrict__ xcont,
                            const float* __restrict__ node_emb,
                            float* __restrict__ x) {
    int idx = blockIdx.x * blockDim.x + threadIdx.x;
    if (idx >= N_NODES * NODE_IN) return;
    int i = idx / NODE_IN;
    int j = idx - i * NODE_IN;
    float v;
    if (j < 20) v = node_emb[xcat[i] * 20 + j];
    else        v = xcont[i * 16 + (j - 20)];
    x[idx] = v;
}

// ================= CSR build =================
__global__ void k_deg(const int* __restrict__ ei, int* __restrict__ deg) {
    int e = blockIdx.x * blockDim.x + threadIdx.x;
    if (e >= N_EDGES) return;
    atomicAdd(deg + ei[N_EDGES + e], 1);
}

__global__ void k_scan(const int* __restrict__ deg, int* __restrict__ rowp,
                       int* __restrict__ cursor) {
    __shared__ int sums[SCAN_T];
    int t = threadIdx.x;
    int lo = t * CHUNK, hi = min(lo + CHUNK, N_NODES);
    int s = 0;
    for (int i = lo; i < hi; i++) s += deg[i];
    sums[t] = s;
    __syncthreads();
    for (int off = 1; off < SCAN_T; off <<= 1) {
        int v = 0;
        if (t >= off) v = sums[t - off];
        __syncthreads();
        if (t >= off) sums[t] += v;
        __syncthreads();
    }
    int run = sums[t] - s;      // exclusive prefix
    for (int i = lo; i < hi; i++) {
        rowp[i] = run;
        cursor[i] = run;
        run += deg[i];
    }
    if (t == SCAN_T - 1) rowp[N_NODES] = sums[SCAN_T - 1];
}

__global__ void k_fill(const int* __restrict__ ei, const int* __restrict__ ecat,
                       int* __restrict__ cursor,
                       int* __restrict__ csr_eid, int* __restrict__ csr_ps) {
    int e = blockIdx.x * blockDim.x + threadIdx.x;
    if (e >= N_EDGES) return;
    int d = ei[N_EDGES + e];
    int pos = atomicAdd(cursor + d, 1);
    csr_eid[pos] = e;
    csr_ps[pos] = ei[e] | (ecat[e] << 24);
}

// ======== GINE1 gather (F=36): scalar metadata + 4-edge batching ========
__global__ void k_gine1_gather(const int* __restrict__ rowp,
                               const int* __restrict__ csr_eid,
                               const int* __restrict__ csr_ps,
                               const float* __restrict__ econt,
                               const float* __restrict__ edge_emb,
                               const float* __restrict__ W,   // [16,36]
                               const float* __restrict__ b,   // [36]
                               const float* __restrict__ x,
                               float* __restrict__ agg) {
    int i = blockIdx.x * 4 + (threadIdx.x >> 6);
    int lane = threadIdx.x & 63;
    if (i >= N_NODES) return;
    int c = (lane < NODE_IN) ? lane : (NODE_IN - 1);
    float w[12];
#pragma unroll
    for (int k = 0; k < 12; k++) w[k] = W[(4 + k) * NODE_IN + c];
    float tb[4];
#pragma unroll
    for (int q = 0; q < 4; q++) {
        float v = b[c];
#pragma unroll
        for (int k = 0; k < 4; k++) v += edge_emb[q * 4 + k] * W[k * NODE_IN + c];
        tb[q] = v;
    }
    int beg = rfl(rowp[i]), end = rfl(rowp[i + 1]);
    float acc = 0.f;
    int p = beg;
    for (; p + 4 <= end; p += 4) {
        int eid[4], src[4], cat[4];
        float4 A[4], B[4], C4[4];
        float xs[4];
#pragma unroll
        for (int bq = 0; bq < 4; bq++) {
            eid[bq] = rfl(csr_eid[p + bq]);
            int pc = rfl(csr_ps[p + bq]);
            src[bq] = pc & 0xFFFFFF;
            cat[bq] = pc >> 24;
            const float4* ec4 = (const float4*)(econt + (size_t)eid[bq] * 12);
            A[bq] = ec4[0]; B[bq] = ec4[1]; C4[bq] = ec4[2];
            xs[bq] = x[(size_t)src[bq] * NODE_IN + c];
        }
#pragma unroll
        for (int bq = 0; bq < 4; bq++) {
            float t = sel4(cat[bq], tb[0], tb[1], tb[2], tb[3]);
            t += A[bq].x * w[0] + A[bq].y * w[1] + A[bq].z * w[2] + A[bq].w * w[3];
            t += B[bq].x * w[4] + B[bq].y * w[5] + B[bq].z * w[6] + B[bq].w * w[7];
            t += C4[bq].x * w[8] + C4[bq].y * w[9] + C4[bq].z * w[10] + C4[bq].w * w[11];
            acc += fmaxf(xs[bq] + t, 0.f);
        }
    }
    for (; p < end; ++p) {
        int eid = rfl(csr_eid[p]);
        int pc = rfl(csr_ps[p]);
        int src = pc & 0xFFFFFF;
        int cat = pc >> 24;
        const float4* ec4 = (const float4*)(econt + (size_t)eid * 12);
        float4 A = ec4[0], B = ec4[1], C4 = ec4[2];
        float t = sel4(cat, tb[0], tb[1], tb[2], tb[3]);
        t += A.x * w[0] + A.y * w[1] + A.z * w[2] + A.w * w[3];
        t += B.x * w[4] + B.y * w[5] + B.z * w[6] + B.w * w[7];
        t += C4.x * w[8] + C4.y * w[9] + C4.z * w[10] + C4.w * w[11];
        acc += fmaxf(x[(size_t)src * NODE_IN + c] + t, 0.f);
    }
    if (lane < NODE_IN) agg[(size_t)i * NODE_IN + lane] = acc;
}

// ===== GINE1 node MLP + BN; OUTPUT h1 as paired bf16 (ch c | ch c+64) =====
__global__ __launch_bounds__(256, 4) void k_gine1_node(
        const float* __restrict__ x, const float* __restrict__ agg,
        const float* __restrict__ eps_p,
        const float* __restrict__ W,   // [36,128]
        const float* __restrict__ b, const float* __restrict__ g,
        const float* __restrict__ bb, const float* __restrict__ m,
        const float* __restrict__ v, unsigned* __restrict__ h1p) {
    __shared__ float sW[NODE_IN * C_HID];     // 18 KB
    __shared__ float sz[DT_NT * NODE_IN];     // 4.5 KB
    int tid = threadIdx.x;
    int node0 = blockIdx.x * DT_NT;
    float eps = eps_p[0];
    {
        const float4* Wv = (const float4*)W;
        float4* sWv = (float4*)sW;
        for (int t = tid; t < NODE_IN * C_HID / 4; t += 256) sWv[t] = Wv[t];
    }
    {
        int nmax = min(DT_NT, N_NODES - node0);
        int tot = nmax * NODE_IN / 4;
        const float4* xv = (const float4*)(x + (size_t)node0 * NODE_IN);
        const float4* av = (const float4*)(agg + (size_t)node0 * NODE_IN);
        float4* szv = (float4*)sz;
        float s = 1.f + eps;
        for (int t = tid; t < tot; t += 256) {
            float4 a = xv[t], c = av[t];
            float4 r;
            r.x = s * a.x + c.x; r.y = s * a.y + c.y;
            r.z = s * a.z + c.z; r.w = s * a.w + c.w;
            szv[t] = r;
        }
    }
    __syncthreads();
    int cg = tid & 15, c0 = cg * 4;           // pair base (lo channels c0..c0+3)
    int n0 = (tid >> 4) * 2;                  // 2 nodes per thread
    float4 bL = *(const float4*)&b[c0];
    float4 bH = *(const float4*)&b[c0 + 64];
    float accL[2][4], accH[2][4];
#pragma unroll
    for (int n = 0; n < 2; n++) {
        accL[n][0] = bL.x; accL[n][1] = bL.y; accL[n][2] = bL.z; accL[n][3] = bL.w;
        accH[n][0] = bH.x; accH[n][1] = bH.y; accH[n][2] = bH.z; accH[n][3] = bH.w;
    }
#pragma unroll 2
    for (int jb = 0; jb < NODE_IN; jb += 4) {
#pragma unroll
        for (int r = 0; r < 4; r++) {
            float4 wl = *(const float4*)&sW[(jb + r) * C_HID + c0];
            float4 wh = *(const float4*)&sW[(jb + r) * C_HID + c0 + 64];
#pragma unroll
            for (int n = 0; n < 2; n++) {
                float zz = sz[(n0 + n) * NODE_IN + jb + r];
                accL[n][0] += zz * wl.x; accL[n][1] += zz * wl.y;
                accL[n][2] += zz * wl.z; accL[n][3] += zz * wl.w;
                accH[n][0] += zz * wh.x; accH[n][1] += zz * wh.y;
                accH[n][2] += zz * wh.z; accH[n][3] += zz * wh.w;
            }
        }
    }
    float4 gL = *(const float4*)&g[c0],  gH = *(const float4*)&g[c0 + 64];
    float4 mL = *(const float4*)&m[c0],  mH = *(const float4*)&m[c0 + 64];
    float4 vL = *(const float4*)&v[c0],  vH = *(const float4*)&v[c0 + 64];
    float4 bbL = *(const float4*)&bb[c0], bbH = *(const float4*)&bb[c0 + 64];
    float scL[4] = { gL.x * rsqrtf(vL.x + BN_EPS), gL.y * rsqrtf(vL.y + BN_EPS),
                     gL.z * rsqrtf(vL.z + BN_EPS), gL.w * rsqrtf(vL.w + BN_EPS) };
    float scH[4] = { gH.x * rsqrtf(vH.x + BN_EPS), gH.y * rsqrtf(vH.y + BN_EPS),
                     gH.z * rsqrtf(vH.z + BN_EPS), gH.w * rsqrtf(vH.w + BN_EPS) };
    float mLa[4] = { mL.x, mL.y, mL.z, mL.w }, mHa[4] = { mH.x, mH.y, mH.z, mH.w };
    float bbLa[4] = { bbL.x, bbL.y, bbL.z, bbL.w }, bbHa[4] = { bbH.x, bbH.y, bbH.z, bbH.w };
#pragma unroll
    for (int n = 0; n < 2; n++) {
        int i = node0 + n0 + n;
        if (i < N_NODES) {
            uint4 o;
            unsigned* po = (unsigned*)&o;
#pragma unroll
            for (int k = 0; k < 4; k++) {
                float lo = (fmaxf(accL[n][k], 0.f) - mLa[k]) * scL[k] + bbLa[k];
                float hi = (fmaxf(accH[n][k], 0.f) - mHa[k]) * scH[k] + bbHa[k];
                po[k] = pack_bf2(lo, hi);
            }
            *(uint4*)&h1p[(size_t)i * 64 + c0] = o;
        }
    }
}

// ======== GINE2 gather: paired bf16 h1, packed fp32 math ========
__global__ void k_gine2_gather(const int* __restrict__ rowp,
                               const int* __restrict__ csr_eid,
                               const int* __restrict__ csr_ps,
                               const float* __restrict__ econt,
                               const float* __restrict__ edge_emb,
                               const float* __restrict__ W,   // [16,128]
                               const float* __restrict__ b,   // [128]
                               const unsigned* __restrict__ h1p,
                               float2* __restrict__ aggp) {
    int i = blockIdx.x * 4 + (threadIdx.x >> 6);
    int lane = threadIdx.x & 63;
    if (i >= N_NODES) return;
    v2f w01[12];
#pragma unroll
    for (int k = 0; k < 12; k++) {
        w01[k].x = W[(4 + k) * C_HID + lane];
        w01[k].y = W[(4 + k) * C_HID + lane + 64];
    }
    v2f tb01[4];
#pragma unroll
    for (int q = 0; q < 4; q++) {
        v2f t; t.x = b[lane]; t.y = b[lane + 64];
#pragma unroll
        for (int k = 0; k < 4; k++) {
            float ev = edge_emb[q * 4 + k];
            t.x += ev * W[k * C_HID + lane];
            t.y += ev * W[k * C_HID + lane + 64];
        }
        tb01[q] = t;
    }
    const v2f zero = v2(0.f);
    int beg = rfl(rowp[i]), end = rfl(rowp[i + 1]);
    v2f acc01 = zero;
    int p = beg;
    for (; p + 4 <= end; p += 4) {
        int eid[4], src[4], cat[4];
        float4 A[4], B[4], C4[4];
        v2f xs[4];
#pragma unroll
        for (int bq = 0; bq < 4; bq++) {
            eid[bq] = rfl(csr_eid[p + bq]);
            int pc = rfl(csr_ps[p + bq]);
            src[bq] = pc & 0xFFFFFF;
            cat[bq] = pc >> 24;
            const float4* ec4 = (const float4*)(econt + (size_t)eid[bq] * 12);
            A[bq] = ec4[0]; B[bq] = ec4[1]; C4[bq] = ec4[2];
            xs[bq] = unpack_bf2(h1p[(size_t)src[bq] * 64 + lane]);
        }
#pragma unroll
        for (int bq = 0; bq < 4; bq++) {
            v2f t = sel4v(cat[bq], tb01[0], tb01[1], tb01[2], tb01[3]);
            t = __builtin_elementwise_fma(v2(A[bq].x), w01[0], t);
            t = __builtin_elementwise_fma(v2(A[bq].y), w01[1], t);
            t = __builtin_elementwise_fma(v2(A[bq].z), w01[2], t);
            t = __builtin_elementwise_fma(v2(A[bq].w), w01[3], t);
            t = __builtin_elementwise_fma(v2(B[bq].x), w01[4], t);
            t = __builtin_elementwise_fma(v2(B[bq].y), w01[5], t);
            t = __builtin_elementwise_fma(v2(B[bq].z), w01[6], t);
            t = __builtin_elementwise_fma(v2(B[bq].w), w01[7], t);
            t = __builtin_elementwise_fma(v2(C4[bq].x), w01[8], t);
            t = __builtin_elementwise_fma(v2(C4[bq].y), w01[9], t);
            t = __builtin_elementwise_fma(v2(C4[bq].z), w01[10], t);
            t = __builtin_elementwise_fma(v2(C4[bq].w), w01[11], t);
            acc01 += __builtin_elementwise_max(xs[bq] + t, zero);
        }
    }
    for (; p < end; ++p) {
        int eid = rfl(csr_eid[p]);
        int pc = rfl(csr_ps[p]);
        int src = pc & 0xFFFFFF;
        int cat = pc >> 24;
        const float4* ec4 = (const float4*)(econt + (size_t)eid * 12);
        float4 A = ec4[0], B = ec4[1], C4 = ec4[2];
        v2f xs = unpack_bf2(h1p[(size_t)src * 64 + lane]);
        v2f t = sel4v(cat, tb01[0], tb01[1], tb01[2], tb01[3]);
        t = __builtin_elementwise_fma(v2(A.x), w01[0], t);
        t = __builtin_elementwise_fma(v2(A.y), w01[1], t);
        t = __builtin_elementwise_fma(v2(A.z), w01[2], t);
        t = __builtin_elementwise_fma(v2(A.w), w01[3], t);
        t = __builtin_elementwise_fma(v2(B.x), w01[4], t);
        t = __builtin_elementwise_fma(v2(B.y), w01[5], t);
        t = __builtin_elementwise_fma(v2(B.z), w01[6], t);
        t = __builtin_elementwise_fma(v2(B.w), w01[7], t);
        t = __builtin_elementwise_fma(v2(C4.x), w01[8], t);
        t = __builtin_elementwise_fma(v2(C4.y), w01[9], t);
        t = __builtin_elementwise_fma(v2(C4.z), w01[10], t);
        t = __builtin_elementwise_fma(v2(C4.w), w01[11], t);
        acc01 += __builtin_elementwise_max(xs + t, zero);
    }
    float2 o; o.x = acc01.x; o.y = acc01.y;
    aggp[(size_t)i * 64 + lane] = o;
}

// ===== GINE2 node MLP + BN; h1 paired bf16 + agg paired fp32 in, h2 standard out =====
__global__ __launch_bounds__(256, 4) void k_gine2_node(
        const unsigned* __restrict__ h1p, const float2* __restrict__ aggp,
        const float* __restrict__ eps_p,
        const float* __restrict__ W,   // [128,128]
        const float* __restrict__ b, const float* __restrict__ g,
        const float* __restrict__ bb, const float* __restrict__ m,
        const float* __restrict__ v, float* __restrict__ h2) {
    __shared__ float sW[64 * C_HID];          // 32 KB (half of W)
    __shared__ float sz[DT_NT * C_HID];       // 16 KB
    int tid = threadIdx.x;
    int node0 = blockIdx.x * DT_NT;
    float eps = eps_p[0];
    {
        int nmax = min(DT_NT, N_NODES - node0);
        int tot = nmax * 64;                  // pairs
        float s = 1.f + eps;
        for (int t = tid; t < tot; t += 256) {
            int n = t >> 6, pp = t & 63;
            v2f h = unpack_bf2(h1p[(size_t)(node0 + n) * 64 + pp]);
            float2 a = aggp[(size_t)(node0 + n) * 64 + pp];
            sz[n * C_HID + pp]      = s * h.x + a.x;
            sz[n * C_HID + pp + 64] = s * h.y + a.y;
        }
    }
    int cg = tid & 31, c0 = cg * 4;
    int n0 = (tid >> 5) * 4;
    float4 bi = *(const float4*)&b[c0];
    float acc[4][4];
#pragma unroll
    for (int n = 0; n < 4; n++) {
        acc[n][0] = bi.x; acc[n][1] = bi.y; acc[n][2] = bi.z; acc[n][3] = bi.w;
    }
    for (int half = 0; half < 2; half++) {
        __syncthreads();
        {
            const float4* Wv = (const float4*)(W + half * 64 * C_HID);
            float4* sWv = (float4*)sW;
            for (int t = tid; t < 64 * C_HID / 4; t += 256) sWv[t] = Wv[t];
        }
        __syncthreads();
        int jbase = half * 64;
#pragma unroll 2
        for (int jb = 0; jb < 64; jb += 4) {
            float4 w0 = *(const float4*)&sW[(jb + 0) * C_HID + c0];
            float4 w1 = *(const float4*)&sW[(jb + 1) * C_HID + c0];
            float4 w2 = *(const float4*)&sW[(jb + 2) * C_HID + c0];
            float4 w3 = *(const float4*)&sW[(jb + 3) * C_HID + c0];
#pragma unroll
            for (int n = 0; n < 4; n++) {
                float4 zz = *(const float4*)&sz[(n0 + n) * C_HID + jbase + jb];
                acc[n][0] += zz.x * w0.x + zz.y * w1.x + zz.z * w2.x + zz.w * w3.x;
                acc[n][1] += zz.x * w0.y + zz.y * w1.y + zz.z * w2.y + zz.w * w3.y;
                acc[n][2] += zz.x * w0.z + zz.y * w1.z + zz.z * w2.z + zz.w * w3.z;
                acc[n][3] += zz.x * w0.w + zz.y * w1.w + zz.z * w2.w + zz.w * w3.w;
            }
        }
    }
    float4 gg = *(const float4*)&g[c0];
    float4 mm = *(const float4*)&m[c0];
    float4 vv = *(const float4*)&v[c0];
    float4 bbv = *(const float4*)&bb[c0];
    float4 sc;
    sc.x = gg.x * rsqrtf(vv.x + BN_EPS); sc.y = gg.y * rsqrtf(vv.y + BN_EPS);
    sc.z = gg.z * rsqrtf(vv.z + BN_EPS); sc.w = gg.w * rsqrtf(vv.w + BN_EPS);
#pragma unroll
    for (int n = 0; n < 4; n++) {
        int i = node0 + n0 + n;
        if (i < N_NODES) {
            float4 o;
            o.x = (fmaxf(acc[n][0], 0.f) - mm.x) * sc.x + bbv.x;
            o.y = (fmaxf(acc[n][1], 0.f) - mm.y) * sc.y + bbv.y;
            o.z = (fmaxf(acc[n][2], 0.f) - mm.z) * sc.z + bbv.z;
            o.w = (fmaxf(acc[n][3], 0.f) - mm.w) * sc.w + bbv.w;
            *(float4*)&h2[(size_t)i * C_HID + c0] = o;
        }
    }
}

// ===== mean edge feature =====
__global__ void k_ea_sum(const int* __restrict__ ecat,
                         const float* __restrict__ econt,
                         float* __restrict__ ea_sum) {   // [0..11] cont, [12..15] counts
    float p[12];
#pragma unroll
    for (int k = 0; k < 12; k++) p[k] = 0.f;
    float cnt[4] = {0.f, 0.f, 0.f, 0.f};
    int stride = gridDim.x * blockDim.x;
    for (int e = blockIdx.x * blockDim.x + threadIdx.x; e < N_EDGES; e += stride) {
        int c = ecat[e];
        cnt[0] += (c == 0) ? 1.f : 0.f;
        cnt[1] += (c == 1) ? 1.f : 0.f;
        cnt[2] += (c == 2) ? 1.f : 0.f;
        cnt[3] += (c == 3) ? 1.f : 0.f;
        const float4* v4 = (const float4*)(econt + (size_t)e * 12);
        float4 a = v4[0], bq = v4[1], d = v4[2];
        p[0] += a.x;  p[1] += a.y;  p[2] += a.z;  p[3] += a.w;
        p[4] += bq.x; p[5] += bq.y; p[6] += bq.z; p[7] += bq.w;
        p[8] += d.x;  p[9] += d.y;  p[10] += d.z; p[11] += d.w;
    }
    float vals[16];
#pragma unroll
    for (int k = 0; k < 12; k++) vals[k] = p[k];
#pragma unroll
    for (int k = 0; k < 4; k++) vals[12 + k] = cnt[k];
#pragma unroll
    for (int k = 0; k < 16; k++) {
        float v = vals[k];
#pragma unroll
        for (int off = 32; off > 0; off >>= 1) v += __shfl_xor(v, off);
        vals[k] = v;
    }
    __shared__ float red[4][16];
    int wid = threadIdx.x >> 6, lane = threadIdx.x & 63;
    if (lane == 0) {
#pragma unroll
        for (int k = 0; k < 16; k++) red[wid][k] = vals[k];
    }
    __syncthreads();
    if (threadIdx.x < 16) {
        float s = red[0][threadIdx.x] + red[1][threadIdx.x] +
                  red[2][threadIdx.x] + red[3][threadIdx.x];
        atomicAdd(ea_sum + threadIdx.x, s);
    }
}

__global__ void k_loop_prep(const float* __restrict__ ea_sum,
                            const float* __restrict__ edge_emb,
                            const float* __restrict__ We,
                            float* __restrict__ ee_loop) {
    int c = threadIdx.x;
    const float inv = 1.f / (float)N_EDGES;
    float acc = 0.f;
#pragma unroll
    for (int k = 0; k < 4; k++) {
        float s = 0.f;
#pragma unroll
        for (int q = 0; q < 4; q++) s += ea_sum[12 + q] * edge_emb[q * 4 + k];
        acc += (s * inv) * We[k * C_HID + c];
    }
#pragma unroll
    for (int k = 0; k < 12; k++)
        acc += (ea_sum[k] * inv) * We[(4 + k) * C_HID + c];
    ee_loop[c] = acc;
}

// ===== GAT node transforms: xl paired bf16, xr paired fp32 =====
__global__ __launch_bounds__(256, 4) void k_gat0(
        const float* __restrict__ h2,
        const float* __restrict__ Wl, const float* __restrict__ bl,
        const float* __restrict__ Wr, const float* __restrict__ br,
        unsigned* __restrict__ xlp, float2* __restrict__ xrp) {
    __shared__ float sW[64 * C_HID];          // 32 KB
    __shared__ float sz[DT_NT * C_HID];       // 16 KB
    int tid = threadIdx.x;
    int node0 = blockIdx.x * DT_NT;
    {
        int nmax = min(DT_NT, N_NODES - node0);
        int tot = nmax * C_HID / 4;
        const float4* hv = (const float4*)(h2 + (size_t)node0 * C_HID);
        float4* szv = (float4*)sz;
        for (int t = tid; t < tot; t += 256) szv[t] = hv[t];
    }
    int cg = tid & 15, c0 = cg * 4;           // pair base
    int n0 = (tid >> 4) * 2;                  // 2 nodes
    for (int wsel = 0; wsel < 2; wsel++) {
        const float* Wm = wsel ? Wr : Wl;
        const float* bm = wsel ? br : bl;
        float4 bL = *(const float4*)&bm[c0];
        float4 bH = *(const float4*)&bm[c0 + 64];
        float accL[2][4], accH[2][4];
#pragma unroll
        for (int n = 0; n < 2; n++) {
            accL[n][0] = bL.x; accL[n][1] = bL.y; accL[n][2] = bL.z; accL[n][3] = bL.w;
            accH[n][0] = bH.x; accH[n][1] = bH.y; accH[n][2] = bH.z; accH[n][3] = bH.w;
        }
        for (int half = 0; half < 2; half++) {
            __syncthreads();
            {
                const float4* Wv = (const float4*)(Wm + half * 64 * C_HID);
                float4* sWv = (float4*)sW;
                for (int t = tid; t < 64 * C_HID / 4; t += 256) sWv[t] = Wv[t];
            }
            __syncthreads();
            int jbase = half * 64;
#pragma unroll 2
            for (int jb = 0; jb < 64; jb += 4) {
#pragma unroll
                for (int r = 0; r < 4; r++) {
                    float4 wl = *(const float4*)&sW[(jb + r) * C_HID + c0];
                    float4 wh = *(const float4*)&sW[(jb + r) * C_HID + c0 + 64];
#pragma unroll
                    for (int n = 0; n < 2; n++) {
                        float zz = sz[(n0 + n) * C_HID + jbase + jb + r];
                        accL[n][0] += zz * wl.x; accL[n][1] += zz * wl.y;
                        accL[n][2] += zz * wl.z; accL[n][3] += zz * wl.w;
                        accH[n][0] += zz * wh.x; accH[n][1] += zz * wh.y;
                        accH[n][2] += zz * wh.z; accH[n][3] += zz * wh.w;
                    }
                }
            }
        }
#pragma unroll
        for (int n = 0; n < 2; n++) {
            int i = node0 + n0 + n;
            if (i < N_NODES) {
                if (wsel == 0) {
                    uint4 o;
                    unsigned* po = (unsigned*)&o;
#pragma unroll
                    for (int k = 0; k < 4; k++) po[k] = pack_bf2(accL[n][k], accH[n][k]);
                    *(uint4*)&xlp[(size_t)i * 64 + c0] = o;
                } else {
                    float4 o1, o2;
                    o1.x = accL[n][0]; o1.y = accH[n][0]; o1.z = accL[n][1]; o1.w = accH[n][1];
                    o2.x = accL[n][2]; o2.y = accH[n][2]; o2.z = accL[n][3]; o2.w = accH[n][3];
                    *(float4*)&xrp[(size_t)i * 64 + c0] = o1;
                    *(float4*)&xrp[(size_t)i * 64 + c0 + 2] = o2;
                }
            }
        }
    }
}

// ===== GAT fused: paired bf16 xl, packed fp32 math, batched online softmax =====
__global__ void k_gat_fused(const int* __restrict__ rowp,
                            const int* __restrict__ csr_eid,
                            const int* __restrict__ csr_ps,
                            const float* __restrict__ econt,
                            const float* __restrict__ edge_emb,
                            const float* __restrict__ We,    // [16,128]
                            const float* __restrict__ att,   // [128]
                            const float* __restrict__ ee_loop,
                            const unsigned* __restrict__ xlp,
                            const float2* __restrict__ xrp,
                            const float* __restrict__ bias,  // [64]
                            float* __restrict__ out) {
    int i = blockIdx.x * 4 + (threadIdx.x >> 6);
    int lane = threadIdx.x & 63;
    if (i >= N_NODES) return;
    v2f w01[12];
#pragma unroll
    for (int k = 0; k < 12; k++) {
        w01[k].x = We[(4 + k) * C_HID + lane];
        w01[k].y = We[(4 + k) * C_HID + lane + 64];
    }
    v2f tb01[4];
#pragma unroll
    for (int q = 0; q < 4; q++) {
        v2f t = v2(0.f);
#pragma unroll
        for (int k = 0; k < 4; k++) {
            float ev = edge_emb[q * 4 + k];
            t.x += ev * We[k * C_HID + lane];
            t.y += ev * We[k * C_HID + lane + 64];
        }
        tb01[q] = t;
    }
    v2f at01; at01.x = att[lane]; at01.y = att[lane + 64];
    v2f lp01; lp01.x = ee_loop[lane]; lp01.y = ee_loop[lane + 64];
    const v2f zero = v2(0.f);
    const v2f fifth = v2(0.2f);

    float2 xr2 = xrp[(size_t)i * 64 + lane];
    v2f xr01; xr01.x = xr2.x; xr01.y = xr2.y;
    v2f xld01 = unpack_bf2(xlp[(size_t)i * 64 + lane]);

    // self-loop alpha
    v2f z01 = xld01 + xr01 + lp01;
    z01 = __builtin_elementwise_max(z01, zero) +
          fifth * __builtin_elementwise_min(z01, zero);
    v2f d01 = z01 * at01;
#pragma unroll
    for (int off = 32; off > 0; off >>= 1) {
        v2f t;
        t.x = __shfl_xor(d01.x, off);
        t.y = __shfl_xor(d01.y, off);
        d01 += t;
    }
    v2f rm01 = d01;
    v2f den01 = v2(1.f);
    v2f acc01 = xld01;

    int beg = rfl(rowp[i]), end = rfl(rowp[i + 1]);
    int p = beg;
    for (; p + 4 <= end; p += 4) {
        int eid[4], src[4], cat[4];
        float4 A[4], B[4], C4[4];
        v2f xs[4];
#pragma unroll
        for (int bq = 0; bq < 4; bq++) {
            eid[bq] = rfl(csr_eid[p + bq]);
            int pc = rfl(csr_ps[p + bq]);
            src[bq] = pc & 0xFFFFFF;
            cat[bq] = pc >> 24;
            const float4* ec4 = (const float4*)(econt + (size_t)eid[bq] * 12);
            A[bq] = ec4[0]; B[bq] = ec4[1]; C4[bq] = ec4[2];
            xs[bq] = unpack_bf2(xlp[(size_t)src[bq] * 64 + lane]);
        }
        v2f dd[4];
#pragma unroll
        for (int bq = 0; bq < 4; bq++) {
            v2f e = sel4v(cat[bq], tb01[0], tb01[1], tb01[2], tb01[3]);
            e = __builtin_elementwise_fma(v2(A[bq].x), w01[0], e);
            e = __builtin_elementwise_fma(v2(A[bq].y), w01[1], e);
            e = __builtin_elementwise_fma(v2(A[bq].z), w01[2], e);
            e = __builtin_elementwise_fma(v2(A[bq].w), w01[3], e);
            e = __builtin_elementwise_fma(v2(B[bq].x), w01[4], e);
            e = __builtin_elementwise_fma(v2(B[bq].y), w01[5], e);
            e = __builtin_elementwise_fma(v2(B[bq].z), w01[6], e);
            e = __builtin_elementwise_fma(v2(B[bq].w), w01[7], e);
            e = __builtin_elementwise_fma(v2(C4[bq].x), w01[8], e);
            e = __builtin_elementwise_fma(v2(C4[bq].y), w01[9], e);
            e = __builtin_elementwise_fma(v2(C4[bq].z), w01[10], e);
            e = __builtin_elementwise_fma(v2(C4[bq].w), w01[11], e);
            v2f z = xs[bq] + xr01 + e;
            z = __builtin_elementwise_max(z, zero) +
                fifth * __builtin_elementwise_min(z, zero);
            dd[bq] = z * at01;
        }
#pragma unroll
        for (int off = 32; off > 0; off >>= 1) {
#pragma unroll
            for (int bq = 0; bq < 4; bq++) {
                v2f t;
                t.x = __shfl_xor(dd[bq].x, off);
                t.y = __shfl_xor(dd[bq].y, off);
                dd[bq] += t;
            }
        }
        // batched online-softmax merge (both heads packed)
        v2f bm = __builtin_elementwise_max(
                     __builtin_elementwise_max(dd[0], dd[1]),
                     __builtin_elementwise_max(dd[2], dd[3]));
        v2f nm = __builtin_elementwise_max(rm01, bm);
        v2f r01; r01.x = __expf(rm01.x - nm.x); r01.y = __expf(rm01.y - nm.y);
        v2f p0; p0.x = __expf(dd[0].x - nm.x); p0.y = __expf(dd[0].y - nm.y);
        v2f p1; p1.x = __expf(dd[1].x - nm.x); p1.y = __expf(dd[1].y - nm.y);
        v2f p2; p2.x = __expf(dd[2].x - nm.x); p2.y = __expf(dd[2].y - nm.y);
        v2f p3; p3.x = __expf(dd[3].x - nm.x); p3.y = __expf(dd[3].y - nm.y);
        den01 = __builtin_elementwise_fma(den01, r01, (p0 + p1) + (p2 + p3));
        acc01 = acc01 * r01;
        acc01 = __builtin_elementwise_fma(p0, xs[0], acc01);
        acc01 = __builtin_elementwise_fma(p1, xs[1], acc01);
        acc01 = __builtin_elementwise_fma(p2, xs[2], acc01);
        acc01 = __builtin_elementwise_fma(p3, xs[3], acc01);
        rm01 = nm;
    }
    for (; p < end; ++p) {
        int eid = rfl(csr_eid[p]);
        int pc = rfl(csr_ps[p]);
        int src = pc & 0xFFFFFF;
        int cat = pc >> 24;
        const float4* ec4 = (const float4*)(econt + (size_t)eid * 12);
        float4 A = ec4[0], B = ec4[1], C4 = ec4[2];
        v2f xs = unpack_bf2(xlp[(size_t)src * 64 + lane]);
        v2f e = sel4v(cat, tb01[0], tb01[1], tb01[2], tb01[3]);
        e = __builtin_elementwise_fma(v2(A.x), w01[0], e);
        e = __builtin_elementwise_fma(v2(A.y), w01[1], e);
        e = __builtin_elementwise_fma(v2(A.z), w01[2], e);
        e = __builtin_elementwise_fma(v2(A.w), w01[3], e);
        e = __builtin_elementwise_fma(v2(B.x), w01[4], e);
        e = __builtin_elementwise_fma(v2(B.y), w01[5], e);
        e = __builtin_elementwise_fma(v2(B.z), w01[6], e);
        e = __builtin_elementwise_fma(v2(B.w), w01[7], e);
        e = __builtin_elementwise_fma(v2(C4.x), w01[8], e);
        e = __builtin_elementwise_fma(v2(C4.y), w01[9], e);
        e = __builtin_elementwise_fma(v2(C4.z), w01[10], e);
        e = __builtin_elementwise_fma(v2(C4.w), w01[11], e);
        v2f z = xs + xr01 + e;
        z = __builtin_elementwise_max(z, zero) +
            fifth * __builtin_elementwise_min(z, zero);
        v2f a = z * at01;
#pragma unroll
        for (int off = 32; off > 0; off >>= 1) {
            v2f t;
            t.x = __shfl_xor(a.x, off);
            t.y = __shfl_xor(a.y, off);
            a += t;
        }
        v2f nm = __builtin_elementwise_max(rm01, a);
        v2f so; so.x = __expf(rm01.x - nm.x); so.y = __expf(rm01.y - nm.y);
        v2f sn; sn.x = __expf(a.x - nm.x); sn.y = __expf(a.y - nm.y);
        den01 = __builtin_elementwise_fma(den01, so, sn);
        acc01 = acc01 * so;
        acc01 = __builtin_elementwise_fma(sn, xs, acc01);
        rm01 = nm;
    }
    out[(size_t)i * C_OUT + lane] =
        0.5f * (acc01.x / den01.x + acc01.y / den01.y) + bias[lane];
}

extern "C" void kernel_launch(void* const* d_in, const int* in_sizes, int n_in,
                              void* d_out, int out_size, void* d_ws, size_t ws_size,
                              hipStream_t stream) {
    const int*   x_cat    = (const int*)d_in[0];
    const float* x_cont   = (const float*)d_in[1];
    const int*   e_cat    = (const int*)d_in[2];
    const float* e_cont   = (const float*)d_in[3];
    const int*   ei       = (const int*)d_in[4];
    const float* node_emb = (const float*)d_in[5];
    const float* edge_emb = (const float*)d_in[6];
    const float* eps1     = (const float*)d_in[7];
    const float* W1e      = (const float*)d_in[8];
    const float* b1e      = (const float*)d_in[9];
    const float* W1n      = (const float*)d_in[10];
    const float* b1n      = (const float*)d_in[11];
    const float* g1       = (const float*)d_in[12];
    const float* bb1      = (const float*)d_in[13];
    const float* m1       = (const float*)d_in[14];
    const float* v1       = (const float*)d_in[15];
    const float* eps2     = (const float*)d_in[16];
    const float* W2e      = (const float*)d_in[17];
    const float* b2e      = (const float*)d_in[18];
    const float* W2n      = (const float*)d_in[19];
    const float* b2n      = (const float*)d_in[20];
    const float* g2       = (const float*)d_in[21];
    const float* bb2      = (const float*)d_in[22];
    const float* m2       = (const float*)d_in[23];
    const float* v2p      = (const float*)d_in[24];
    const float* Wl       = (const float*)d_in[25];
    const float* bl       = (const float*)d_in[26];
    const float* Wr       = (const float*)d_in[27];
    const float* br       = (const float*)d_in[28];
    const float* Weg      = (const float*)d_in[29];
    const float* att      = (const float*)d_in[30];
    const float* gbias    = (const float*)d_in[31];

    const size_t NF128 = (size_t)N_NODES * C_HID;

    // layout: A (fp32, x -> h2) | B (fp32, agg36 / agg-pairs / xr-pairs) | Hb (bf16 pairs, h1 -> xl)
    float* A = (float*)d_ws;                 // N*128 floats
    float* B = A + NF128;                    // N*128 floats
    unsigned* Hb = (unsigned*)(B + NF128);   // N*64 u32
    float* ea_sum  = (float*)(Hb + (size_t)N_NODES * 64);   // 16
    float* ee_loop = ea_sum + 16;            // 128
    int* deg     = (int*)(ee_loop + C_HID);  // N
    int* cursor  = deg + N_NODES;            // N
    int* rowp    = cursor + N_NODES;         // N+1
    int* csr_eid = rowp + N_NODES + 1;       // E
    int* csr_ps  = csr_eid + N_EDGES;        // E

    float* x = A;                 // N*36 (dead before h2 written)
    float* h2 = A;
    float* agg36 = B;
    float2* aggp = (float2*)B;    // N*64 float2
    float2* xrp  = (float2*)B;
    unsigned* h1p = Hb; unsigned* xlp = Hb;

    size_t need = (size_t)((char*)(csr_ps + N_EDGES) - (char*)d_ws);
    if (ws_size < need) return;

    hipMemsetAsync(deg, 0, N_NODES * sizeof(int), stream);
    hipMemsetAsync(ea_sum, 0, 16 * sizeof(float), stream);

    const int EB = (N_EDGES + 255) / 256;
    const int NB4 = (N_NODES + 3) / 4;
    const int NBD = (N_NODES + DT_NT - 1) / DT_NT;

    k_node_feat<<<(N_NODES * NODE_IN + 255) / 256, 256, 0, stream>>>(
        x_cat, x_cont, node_emb, x);
    k_deg<<<EB, 256, 0, stream>>>(ei, deg);
    k_scan<<<1, SCAN_T, 0, stream>>>(deg, rowp, cursor);
    k_fill<<<EB, 256, 0, stream>>>(ei, e_cat, cursor, csr_eid, csr_ps);

    k_gine1_gather<<<NB4, 256, 0, stream>>>(
        rowp, csr_eid, csr_ps, e_cont, edge_emb, W1e, b1e, x, agg36);
    k_gine1_node<<<NBD, 256, 0, stream>>>(
        x, agg36, eps1, W1n, b1n, g1, bb1, m1, v1, h1p);
    k_gine2_gather<<<NB4, 256, 0, stream>>>(
        rowp, csr_eid, csr_ps, e_cont, edge_emb, W2e, b2e, h1p, aggp);
    k_gine2_node<<<NBD, 256, 0, stream>>>(
        h1p, aggp, eps2, W2n, b2n, g2, bb2, m2, v2p, h2);

    k_ea_sum<<<512, 256, 0, stream>>>(e_cat, e_cont, ea_sum);
    k_loop_prep<<<1, C_HID, 0, stream>>>(ea_sum, edge_emb, Weg, ee_loop);

    k_gat0<<<NBD, 256, 0, stream>>>(h2, Wl, bl, Wr, br, xlp, xrp);
    k_gat_fused<<<NB4, 256, 0, stream>>>(
        rowp, csr_eid, csr_ps, e_cont, edge_emb, Weg, att, ee_loop,
        xlp, xrp, gbias, (float*)d_out);
}